// Round 3
// baseline (532.770 us; speedup 1.0000x reference)
//
#include <hip/hip_runtime.h>
#include <hip/hip_bf16.h>
#include <hip/hip_cooperative_groups.h>

namespace cg = cooperative_groups;

#define NN 4096
#define NFEAT 512
#define NHID 64
#define NHEAD 8
#define NCLASS 16
#define CAP 192
#define LALPHA 0.2f

#define SZ2 (NHEAD*2*NHID)   // a_heads
#define SZ3 (NHEAD*NHID)     // b_heads
#define SZ4 (NFEAT*NCLASS)   // W_out
#define SZ5 (2*NCLASS)       // a_out
#define SZ6 (NCLASS)         // b_out
#define NSMALL (SZ2+SZ3+SZ4+SZ5+SZ6)
#define NZERO (NN*NN/32 + NN + NHEAD*NHID + NCLASS)   // bits+deg+cm1+cm2

typedef __attribute__((ext_vector_type(8))) short bf16x8;
typedef __attribute__((ext_vector_type(4))) float f32x4;
typedef __attribute__((ext_vector_type(8))) unsigned short u16x8;

__device__ __forceinline__ float b2f(unsigned short h) {
    return __uint_as_float(((unsigned int)h) << 16);
}
__device__ __forceinline__ unsigned short f2b(float f) {
    unsigned int u = __float_as_uint(f);
    unsigned int r = (u + 0x7fffu + ((u >> 16) & 1u)) >> 16;
    return (unsigned short)r;
}
__device__ __forceinline__ float waveMax(float v) {
#pragma unroll
    for (int m = 32; m >= 1; m >>= 1) v = fmaxf(v, __shfl_xor(v, m, 64));
    return v;
}
__device__ __forceinline__ float waveSum(float v) {
#pragma unroll
    for (int m = 32; m >= 1; m >>= 1) v += __shfl_xor(v, m, 64);
    return v;
}
__device__ __forceinline__ float lrelu(float e) {
    return e >= 0.f ? e : LALPHA * e;
}

// =====================================================================
// Fused cooperative kernel. Grid-stride in every phase -> ANY grid size
// is correct; host sizes the grid from the occupancy query.
// LDS: Bc 27712 B -> 4-5 blocks/CU.
// =====================================================================
__global__ void __launch_bounds__(256, 4)
k_fused(const void* __restrict__ f, const void* __restrict__ Wh_,
        const void* __restrict__ ah_, const void* __restrict__ bh_,
        const void* __restrict__ Wo_, const void* __restrict__ ao_,
        const void* __restrict__ bo_, const int* __restrict__ e32,
        int E, int csb,
        unsigned short* __restrict__ featb, unsigned short* __restrict__ Wtb,
        float* __restrict__ smallf, unsigned int* __restrict__ bits,
        int* __restrict__ deg, int* __restrict__ csr,
        float* __restrict__ cm1, float* __restrict__ cm2,
        float* __restrict__ s1, float* __restrict__ s2,
        float* __restrict__ out2, float* __restrict__ s1o, float* __restrict__ s2o,
        unsigned short* __restrict__ Hb, float* __restrict__ outp)
{
    cg::grid_group grid = cg::this_grid();
    __shared__ __align__(16) char Bc[27712];
    __shared__ int sbf, s64f;
    int t = threadIdx.x, bid = blockIdx.x, nblk = gridDim.x;
    int wid = t >> 6, lane = t & 63;

    // ---- Z: zero bits+deg+cm1+cm2 (contiguous); dtype detects ----
    for (int i = bid * 256 + t; i < NZERO; i += nblk * 256) bits[i] = 0u;
    if (t < 64) {
        unsigned int w = ((const unsigned int*)f)[t];
        unsigned int lo = w & 0xffffu, e = (lo >> 7) & 0xffu;
        unsigned long long bal = __ballot(lo == 0u || (e >= 100u && e <= 140u));
        if (t == 0) sbf = (__popcll(bal) >= 40);
        unsigned long long bal2 = __ballot(e32[2 * t + 1] == 0);
        if (t == 0) s64f = (__popcll(bal2) >= 48);
    }
    __threadfence();
    grid.sync();
    bool bf = (sbf != 0);

    // ---- P0: prep (W transpose | edge bitmap | feature/small cast) ----
    int NVB0 = 128 + csb + 896;
    for (int vb = bid; vb < NVB0; vb += nblk) {
        if (vb < 128) {
            float (*tile)[33] = (float(*)[33])Bc;
            int h = vb >> 4, k0 = (vb & 15) * 32;
            int nn = t & 63, kh = t >> 6;
#pragma unroll
            for (int i = 0; i < 8; ++i) {
                int kk = kh * 8 + i;
                int si = (h << 15) + (k0 + kk) * NHID + nn;
                float v = bf ? b2f(((const unsigned short*)Wh_)[si])
                             : ((const float*)Wh_)[si];
                tile[nn][kk] = v;
            }
            __syncthreads();
            int n2 = t >> 2, kk0 = (t & 3) * 8;
            u16x8 o;
#pragma unroll
            for (int i = 0; i < 8; ++i) o[i] = f2b(tile[n2][kk0 + i]);
            *(u16x8*)&Wtb[(size_t)((h << 6) + n2) * NFEAT + k0 + kk0] = o;
            __syncthreads();
        } else if (vb < 128 + csb) {
            int i = (vb - 128) * 256 + t;
            if (i < E) {
                int s, tt;
                if (s64f) { s = e32[2 * i]; tt = e32[2 * (E + i)]; }
                else      { s = e32[i];     tt = e32[E + i]; }
                s &= (NN - 1); tt &= (NN - 1);
                unsigned int pos = (unsigned int)s * NN + (unsigned int)tt;
                atomicOr(&bits[pos >> 5], 1u << (pos & 31u));
            }
        } else {
            const int NF8 = NN * NFEAT / 8;
            const int TOT = NF8 + NSMALL;
            for (int i = (vb - 128 - csb) * 256 + t; i < TOT; i += 896 * 256) {
                if (i < NF8) {
                    if (bf) {
                        *(u16x8*)&featb[i * 8] = ((const u16x8*)f)[i];
                    } else {
                        float4 lo = ((const float4*)f)[i * 2];
                        float4 hi = ((const float4*)f)[i * 2 + 1];
                        u16x8 o;
                        o[0] = f2b(lo.x); o[1] = f2b(lo.y); o[2] = f2b(lo.z); o[3] = f2b(lo.w);
                        o[4] = f2b(hi.x); o[5] = f2b(hi.y); o[6] = f2b(hi.z); o[7] = f2b(hi.w);
                        *(u16x8*)&featb[i * 8] = o;
                    }
                } else {
                    int r = i - NF8;
                    const void* sp; int off;
                    if (r < SZ2)                        { sp = ah_; off = r; }
                    else if (r < SZ2 + SZ3)             { sp = bh_; off = r - SZ2; }
                    else if (r < SZ2 + SZ3 + SZ4)       { sp = Wo_; off = r - SZ2 - SZ3; }
                    else if (r < SZ2 + SZ3 + SZ4 + SZ5) { sp = ao_; off = r - SZ2 - SZ3 - SZ4; }
                    else                                { sp = bo_; off = r - SZ2 - SZ3 - SZ4 - SZ5; }
                    smallf[r] = bf ? b2f(((const unsigned short*)sp)[off])
                                   : ((const float*)sp)[off];
                }
            }
        }
    }
    __threadfence();
    grid.sync();

    // ---- P1: extract (bitmap -> global csr/deg) + gemm1 ----
    for (int vb = bid; vb < 1024; vb += nblk) {
        {   // extract: registers/shuffles only, no LDS
            int n = vb * 4 + wid;
            uint2 w2 = *(const uint2*)&bits[n * 128 + lane * 2];
            int c = __popc(w2.x) + __popc(w2.y);
            int incl = c;
#pragma unroll
            for (int off = 1; off < 64; off <<= 1) {
                int u = __shfl_up(incl, off, 64);
                if (lane >= off) incl += u;
            }
            int excl = incl - c;
            int total = __shfl(incl, 63, 64);
            if (lane == 0) deg[n] = total;
            int base = n * CAP;
            int tbase = lane * 64;
            unsigned int x = w2.x;
            while (x) {
                int b = __ffs(x) - 1; x &= x - 1;
                if (excl < CAP) csr[base + excl] = tbase + b;
                ++excl;
            }
            unsigned int y = w2.y;
            while (y) {
                int b = __ffs(y) - 1; y &= y - 1;
                if (excl < CAP) csr[base + excl] = tbase + 32 + b;
                ++excl;
            }
        }
        {   // gemm1 tile: h = vb>>7, rows m0..m0+31, wave owns 16 cols
            float* sp1   = (float*)Bc;        // [32]
            float* sp2   = sp1 + 32;          // [32]
            float* cms64 = sp2 + 32;          // [64]
            if (t < 32) sp1[t] = 0.f;
            else if (t < 64) sp2[t - 32] = 0.f;
            __syncthreads();
            int h = vb >> 7, m0 = (vb & 127) << 5;
            int quad = lane >> 4, l16 = lane & 15;
            f32x4 acc0 = {}, acc1 = {};
            const unsigned short* a0p = featb + (size_t)(m0 + l16) * NFEAT + quad * 8;
            const unsigned short* a1p = a0p + 16 * NFEAT;
            const unsigned short* bp  = Wtb + ((size_t)h << 15) + (size_t)(wid * 16 + l16) * NFEAT + quad * 8;
#pragma unroll 4
            for (int k0 = 0; k0 < NFEAT; k0 += 32) {
                bf16x8 a0 = *(const bf16x8*)(a0p + k0);
                bf16x8 a1 = *(const bf16x8*)(a1p + k0);
                bf16x8 b  = *(const bf16x8*)(bp + k0);
                acc0 = __builtin_amdgcn_mfma_f32_16x16x32_bf16(a0, b, acc0, 0, 0, 0);
                acc1 = __builtin_amdgcn_mfma_f32_16x16x32_bf16(a1, b, acc1, 0, 0, 0);
            }
            const float* av = smallf + h * 2 * NHID;
            int col = wid * 16 + l16;
            float av1 = av[col], av2 = av[NHID + col];
            float p1v[2][4], p2v[2][4];
            float csum = 0.f;
#pragma unroll
            for (int rh = 0; rh < 2; ++rh)
#pragma unroll
                for (int r = 0; r < 4; ++r) {
                    float v = rh ? acc1[r] : acc0[r];
                    int row = m0 + rh * 16 + quad * 4 + r;
                    Hb[((size_t)row << 9) + (h << 6) + col] = f2b(v);
                    p1v[rh][r] = v * av1;
                    p2v[rh][r] = v * av2;
                    csum += v;
                }
#pragma unroll
            for (int m = 8; m >= 1; m >>= 1)
#pragma unroll
                for (int rh = 0; rh < 2; ++rh)
#pragma unroll
                    for (int r = 0; r < 4; ++r) {
                        p1v[rh][r] += __shfl_xor(p1v[rh][r], m, 64);
                        p2v[rh][r] += __shfl_xor(p2v[rh][r], m, 64);
                    }
            if (l16 == 0) {
#pragma unroll
                for (int rh = 0; rh < 2; ++rh)
#pragma unroll
                    for (int r = 0; r < 4; ++r) {
                        atomicAdd(&sp1[rh * 16 + quad * 4 + r], p1v[rh][r]);
                        atomicAdd(&sp2[rh * 16 + quad * 4 + r], p2v[rh][r]);
                    }
            }
            csum += __shfl_xor(csum, 16, 64);
            csum += __shfl_xor(csum, 32, 64);
            if (lane < 16) cms64[wid * 16 + lane] = csum;
            __syncthreads();
            if (t < 32) {
                s1[(h << 12) + m0 + t] = sp1[t];
                s2[(h << 12) + m0 + t] = sp2[t];
            }
            if (t < 64) atomicAdd(&cm1[h * NHID + t], cms64[t]);
        }
    }
    __threadfence();
    grid.sync();

    // ---- P2: attn1 (all heads per wave) + bias + ELU + fused gemm2/scores2 ----
    {
        float* sW   = (float*)Bc;               // [4][CAP*8], reused as X row after gather
        int*   sTl  = (int*)(Bc + 24576);       // [4][CAP]
        float* cmsL = (float*)(Bc + 27648);     // [16]
        if (t < NCLASS) cmsL[t] = 0.f;
        __syncthreads();
        const float* bhf = smallf + SZ2;
        const float* Wof = smallf + SZ2 + SZ3;
        const float* aof = Wof + SZ4;
        for (int vb = bid; vb < 1024; vb += nblk) {
            int n = vb * 4 + wid;
            int h = lane >> 3, jslot = lane & 7;
            int d = min(deg[n], CAP);
            float* sWw = sW + wid * (CAP * 8);
            int*   sTw = sTl + wid * CAP;
            const int* row = csr + (size_t)n * CAP;
            float acc[8] = {};
            float rden = 1.f;
            if (d > 0) {
                const float* s2h = s2 + ((size_t)h << 12);
                float s1n = s1[(h << 12) + n];
                float mx = -1e30f;
                for (int jb = 0; jb < d; jb += 8) {
                    int j = jb + jslot;
                    int tt = (j < d) ? row[j] : 0;
                    float e = (j < d) ? lrelu(s1n + s2h[tt]) : -1e30f;
                    sWw[(j << 3) + h] = e;
                    if (h == 0) sTw[j] = tt;
                    mx = fmaxf(mx, e);
                }
                mx = fmaxf(mx, __shfl_xor(mx, 1, 64));
                mx = fmaxf(mx, __shfl_xor(mx, 2, 64));
                mx = fmaxf(mx, __shfl_xor(mx, 4, 64));
                float den = 0.f;
                for (int jb = 0; jb < d; jb += 8) {
                    int j = jb + jslot;
                    float e = sWw[(j << 3) + h];
                    float w = __expf(e - mx);
                    sWw[(j << 3) + h] = w;
                    den += w;
                }
                den += __shfl_xor(den, 1, 64);
                den += __shfl_xor(den, 2, 64);
                den += __shfl_xor(den, 4, 64);
                rden = 1.f / den;
                const unsigned short* Hp = Hb + lane * 8;
                int j = 0;
#pragma unroll 2
                for (; j + 2 <= d; j += 2) {
                    int t0 = sTw[j], t1 = sTw[j + 1];
                    float w0 = sWw[(j << 3) + h];
                    float w1 = sWw[((j + 1) << 3) + h];
                    u16x8 v0 = *(const u16x8*)(Hp + ((size_t)t0 << 9));
                    u16x8 v1 = *(const u16x8*)(Hp + ((size_t)t1 << 9));
#pragma unroll
                    for (int i = 0; i < 8; ++i)
                        acc[i] += w0 * b2f(v0[i]) + w1 * b2f(v1[i]);
                }
                if (j < d) {
                    int t0 = sTw[j];
                    float w0 = sWw[(j << 3) + h];
                    u16x8 v0 = *(const u16x8*)(Hp + ((size_t)t0 << 9));
#pragma unroll
                    for (int i = 0; i < 8; ++i) acc[i] += w0 * b2f(v0[i]);
                }
            }
            float o[8];
            if (d == 0) {
#pragma unroll
                for (int i = 0; i < 8; ++i) o[i] = cm1[lane * 8 + i] * (1.0f / NN);
            } else {
#pragma unroll
                for (int i = 0; i < 8; ++i) o[i] = acc[i] * rden;
            }
#pragma unroll
            for (int i = 0; i < 8; ++i) {
                float v = o[i] + bhf[lane * 8 + i];
                o[i] = v > 0.f ? v : __expf(v) - 1.f;     // ELU
            }
            // reuse this wave's weight region as its X row (same-wave ordering)
            float* xw = sWw;
            *(float4*)&xw[lane * 8]     = make_float4(o[0], o[1], o[2], o[3]);
            *(float4*)&xw[lane * 8 + 4] = make_float4(o[4], o[5], o[6], o[7]);
            int c = lane & 15, sub = lane >> 4;
            const float* xp = xw + sub * 128;
            const float* wp = Wof + sub * 128 * NCLASS + c;
            float a2 = 0.f;
#pragma unroll 8
            for (int kk = 0; kk < 128; ++kk) a2 += xp[kk] * wp[kk * NCLASS];
            a2 += __shfl_xor(a2, 16, 64);
            a2 += __shfl_xor(a2, 32, 64);
            if (lane < 16) out2[n * NCLASS + c] = a2;
            float r1 = a2 * aof[c], r2 = a2 * aof[NCLASS + c];
#pragma unroll
            for (int m = 8; m >= 1; m >>= 1) {
                r1 += __shfl_xor(r1, m, 16);
                r2 += __shfl_xor(r2, m, 16);
            }
            if (lane == 0) { s1o[n] = r1; s2o[n] = r2; }
            if (lane < 16) atomicAdd(&cmsL[c], a2);
        }
        __syncthreads();
        if (t < NCLASS) atomicAdd(&cm2[t], cmsL[t]);
    }
    __threadfence();
    grid.sync();

    // ---- P3: attn2 + bias + log_softmax ----
    {
        float* wv  = (float*)Bc;            // [4][CAP]
        float* o2s = (float*)(Bc + 3072);   // [4][16]
        const float* bof = smallf + SZ2 + SZ3 + SZ4 + SZ5;
        for (int vb = bid; vb < 1024; vb += nblk) {
            int n = vb * 4 + wid;
            int c = lane & 15;
            int d = min(deg[n], CAP);
            float val;
            if (d == 0) {
                val = cm2[c] * (1.0f / NN);
            } else {
                float s1n = s1o[n];
                const int* rowp = csr + (size_t)n * CAP;
                float* wvw = wv + wid * CAP;
                int t0 = (lane < d)       ? rowp[lane]       : 0;
                int t1 = (lane + 64 < d)  ? rowp[lane + 64]  : 0;
                int t2 = (lane + 128 < d) ? rowp[lane + 128] : 0;
                float e0 = (lane < d)       ? lrelu(s1n + s2o[t0]) : -1e30f;
                float e1 = (lane + 64 < d)  ? lrelu(s1n + s2o[t1]) : -1e30f;
                float e2 = (lane + 128 < d) ? lrelu(s1n + s2o[t2]) : -1e30f;
                float m = waveMax(fmaxf(e0, fmaxf(e1, e2)));
                float w0 = (lane < d)       ? __expf(e0 - m) : 0.f;
                float w1 = (lane + 64 < d)  ? __expf(e1 - m) : 0.f;
                float w2 = (lane + 128 < d) ? __expf(e2 - m) : 0.f;
                float den = waveSum(w0 + w1 + w2);
                wvw[lane]       = w0;
                wvw[lane + 64]  = w1;
                wvw[lane + 128] = w2;
                int g2 = lane >> 2, q = lane & 3;
                float a4[4] = {};
                for (int j = g2; j < d; j += 16) {
                    float w = wvw[j];
                    int tt = rowp[j];
                    float4 v = *(const float4*)(out2 + tt * NCLASS + q * 4);
                    a4[0] += w * v.x; a4[1] += w * v.y;
                    a4[2] += w * v.z; a4[3] += w * v.w;
                }
#pragma unroll
                for (int m2 = 4; m2 <= 32; m2 <<= 1)
#pragma unroll
                    for (int i = 0; i < 4; ++i) a4[i] += __shfl_xor(a4[i], m2, 64);
                if (lane < 4)
                    *(float4*)&o2s[wid * 16 + lane * 4] = make_float4(a4[0], a4[1], a4[2], a4[3]);
                val = o2s[wid * 16 + c] / den;
            }
            val += bof[c];
            float mx = val;
#pragma unroll
            for (int m = 8; m >= 1; m >>= 1) mx = fmaxf(mx, __shfl_xor(mx, m, 16));
            float se = __expf(val - mx);
#pragma unroll
            for (int m = 8; m >= 1; m >>= 1) se += __shfl_xor(se, m, 16);
            float res = val - mx - __logf(se);
            if (lane < 16) outp[n * NCLASS + lane] = res;
        }
    }
}

// =====================================================================
// Fallback kernels (verbatim round-1, known-correct at 147 us)
// =====================================================================
__global__ void __launch_bounds__(256)
k_prep(const void* __restrict__ f, const void* __restrict__ Wh_,
       const void* __restrict__ ah_, const void* __restrict__ bh_,
       const void* __restrict__ Wo_, const void* __restrict__ ao_,
       const void* __restrict__ bo_, const int* __restrict__ e32,
       int E, int csb,
       unsigned short* __restrict__ featb,
       unsigned short* __restrict__ Wtb,
       float* __restrict__ smallf,
       unsigned int* __restrict__ bits) {
    __shared__ int sbf;
    int t = threadIdx.x;
    if (t < 64) {
        unsigned int w = ((const unsigned int*)f)[t];
        unsigned int lo = w & 0xffffu, e = (lo >> 7) & 0xffu;
        unsigned long long bal = __ballot(lo == 0u || (e >= 100u && e <= 140u));
        if (t == 0) sbf = (__popcll(bal) >= 40);
    }
    __syncthreads();
    bool bf = (sbf != 0);
    if (blockIdx.x < 128) {
        __shared__ float tile[64][33];
        int h = blockIdx.x >> 4, k0 = (blockIdx.x & 15) * 32;
        int n = t & 63, kh = t >> 6;
#pragma unroll
        for (int i = 0; i < 8; ++i) {
            int kk = kh * 8 + i;
            int si = (h << 15) + (k0 + kk) * NHID + n;
            float v = bf ? b2f(((const unsigned short*)Wh_)[si])
                         : ((const float*)Wh_)[si];
            tile[n][kk] = v;
        }
        __syncthreads();
        int n2 = t >> 2, kk0 = (t & 3) * 8;
        u16x8 o;
#pragma unroll
        for (int i = 0; i < 8; ++i) o[i] = f2b(tile[n2][kk0 + i]);
        *(u16x8*)&Wtb[(size_t)((h << 6) + n2) * NFEAT + k0 + kk0] = o;
    } else if ((int)blockIdx.x < 128 + csb) {
        __shared__ int s64f;
        if (t < 64) {
            unsigned long long bal = __ballot(e32[2 * t + 1] == 0);
            if (t == 0) s64f = (__popcll(bal) >= 48);
        }
        __syncthreads();
        int i = (blockIdx.x - 128) * 256 + t;
        if (i < E) {
            int s, tt;
            if (s64f) { s = e32[2 * i]; tt = e32[2 * (E + i)]; }
            else      { s = e32[i];     tt = e32[E + i]; }
            s &= (NN - 1); tt &= (NN - 1);
            unsigned int pos = (unsigned int)s * NN + (unsigned int)tt;
            atomicOr(&bits[pos >> 5], 1u << (pos & 31u));
        }
    } else {
        const int NF8 = NN * NFEAT / 8;
        int i = (blockIdx.x - 128 - csb) * 256 + t;
        int stride = (gridDim.x - 128 - csb) * 256;
        const int TOT = NF8 + NSMALL;
        for (; i < TOT; i += stride) {
            if (i < NF8) {
                if (bf) {
                    *(u16x8*)&featb[i * 8] = ((const u16x8*)f)[i];
                } else {
                    float4 lo = ((const float4*)f)[i * 2];
                    float4 hi = ((const float4*)f)[i * 2 + 1];
                    u16x8 o;
                    o[0] = f2b(lo.x); o[1] = f2b(lo.y); o[2] = f2b(lo.z); o[3] = f2b(lo.w);
                    o[4] = f2b(hi.x); o[5] = f2b(hi.y); o[6] = f2b(hi.z); o[7] = f2b(hi.w);
                    *(u16x8*)&featb[i * 8] = o;
                }
            } else {
                int r = i - NF8;
                const void* sp; int off;
                if (r < SZ2)                        { sp = ah_; off = r; }
                else if (r < SZ2 + SZ3)             { sp = bh_; off = r - SZ2; }
                else if (r < SZ2 + SZ3 + SZ4)       { sp = Wo_; off = r - SZ2 - SZ3; }
                else if (r < SZ2 + SZ3 + SZ4 + SZ5) { sp = ao_; off = r - SZ2 - SZ3 - SZ4; }
                else                                { sp = bo_; off = r - SZ2 - SZ3 - SZ4 - SZ5; }
                smallf[r] = bf ? b2f(((const unsigned short*)sp)[off])
                               : ((const float*)sp)[off];
            }
        }
    }
}

__global__ void __launch_bounds__(256)
k_gemm_ext(const unsigned short* __restrict__ Ab,
           const unsigned short* __restrict__ Wtb,
           const float* __restrict__ ah,
           unsigned short* __restrict__ Hb,
           float* __restrict__ s1, float* __restrict__ s2,
           float* __restrict__ cm1,
           const unsigned int* __restrict__ bits,
           int* __restrict__ deg, int* __restrict__ csr) {
    int t = threadIdx.x;
    if (blockIdx.x >= 256) {
        int wid = t >> 6, lane = t & 63;
        int n = (blockIdx.x - 256) * 4 + wid;
        uint2 w = *(const uint2*)&bits[n * 128 + lane * 2];
        int c = __popc(w.x) + __popc(w.y);
        int incl = c;
#pragma unroll
        for (int off = 1; off < 64; off <<= 1) {
            int u = __shfl_up(incl, off, 64);
            if (lane >= off) incl += u;
        }
        int excl = incl - c;
        int total = __shfl(incl, 63, 64);
        if (lane == 0) deg[n] = total;
        int base = n * CAP;
        int tbase = lane * 64;
        unsigned int x = w.x;
        while (x) {
            int b = __ffs(x) - 1; x &= x - 1;
            if (excl < CAP) csr[base + excl] = tbase + b;
            ++excl;
        }
        unsigned int y = w.y;
        while (y) {
            int b = __ffs(y) - 1; y &= y - 1;
            if (excl < CAP) csr[base + excl] = tbase + 32 + b;
            ++excl;
        }
        return;
    }
    __shared__ float cms[64];
    if (t < 64) cms[t] = 0.f;
    __syncthreads();
    int w = t >> 6, l = t & 63;
    int quad = l >> 4, l16 = l & 15;
    int h = blockIdx.x >> 5;
    int m0 = (blockIdx.x & 31) * 128 + w * 32;
    f32x4 acc[2][4] = {};
    const unsigned short* a0p = Ab + (size_t)(m0 + l16) * NFEAT + quad * 8;
    const unsigned short* a1p = a0p + 16 * NFEAT;
    const unsigned short* bp  = Wtb + ((size_t)h << 15) + (size_t)l16 * NFEAT + quad * 8;
#pragma unroll 4
    for (int k0 = 0; k0 < NFEAT; k0 += 32) {
        bf16x8 a0 = *(const bf16x8*)(a0p + k0);
        bf16x8 a1 = *(const bf16x8*)(a1p + k0);
#pragma unroll
        for (int nt = 0; nt < 4; ++nt) {
            bf16x8 b = *(const bf16x8*)(bp + (size_t)nt * 16 * NFEAT + k0);
            acc[0][nt] = __builtin_amdgcn_mfma_f32_16x16x32_bf16(a0, b, acc[0][nt], 0, 0, 0);
            acc[1][nt] = __builtin_amdgcn_mfma_f32_16x16x32_bf16(a1, b, acc[1][nt], 0, 0, 0);
        }
    }
    const float* av = ah + h * 2 * NHID;
    float p1[2][4] = {}, p2[2][4] = {};
#pragma unroll
    for (int rh = 0; rh < 2; ++rh) {
#pragma unroll
        for (int nt = 0; nt < 4; ++nt) {
            int col = nt * 16 + l16;
            float av1 = av[col], av2 = av[NHID + col];
            float csum = 0.f;
#pragma unroll
            for (int r = 0; r < 4; ++r) {
                float v = acc[rh][nt][r];
                int row = m0 + rh * 16 + quad * 4 + r;
                Hb[((size_t)row << 9) + (h << 6) + col] = f2b(v);
                p1[rh][r] += v * av1;
                p2[rh][r] += v * av2;
                csum += v;
            }
            atomicAdd(&cms[col], csum);
        }
    }
#pragma unroll
    for (int m = 8; m >= 1; m >>= 1)
#pragma unroll
        for (int rh = 0; rh < 2; ++rh)
#pragma unroll
            for (int r = 0; r < 4; ++r) {
                p1[rh][r] += __shfl_xor(p1[rh][r], m, 64);
                p2[rh][r] += __shfl_xor(p2[rh][r], m, 64);
            }
    if (l16 == 0) {
#pragma unroll
        for (int rh = 0; rh < 2; ++rh)
#pragma unroll
            for (int r = 0; r < 4; ++r) {
                int row = m0 + rh * 16 + quad * 4 + r;
                s1[(h << 12) + row] = p1[rh][r];
                s2[(h << 12) + row] = p2[rh][r];
            }
    }
    __syncthreads();
    if (t < 64) atomicAdd(&cm1[h * NHID + t], cms[t]);
}

__global__ void __launch_bounds__(256)
k_attn1f(const int* __restrict__ deg, const int* __restrict__ csr,
         const float* __restrict__ s1, const float* __restrict__ s2,
         const unsigned short* __restrict__ Hb,
         const float* __restrict__ bh, const float* __restrict__ cm1,
         const float* __restrict__ Wo, const float* __restrict__ ao,
         float* __restrict__ out2, float* __restrict__ s1o,
         float* __restrict__ s2o, float* __restrict__ cm2) {
    __shared__ float sW[4][CAP * 8];
    __shared__ int   sT[4][CAP];
    __shared__ float xr[4][NFEAT];
    __shared__ float cms[NCLASS];
    int t = threadIdx.x;
    if (t < NCLASS) cms[t] = 0.f;
    __syncthreads();
    int wid = t >> 6, lane = t & 63;
    int n = blockIdx.x * 4 + wid;
    int h = lane >> 3, jslot = lane & 7;
    int d = min(deg[n], CAP);
    float acc[8] = {};
    float rden = 1.f;
    if (d > 0) {
        const int* row = csr + (size_t)n * CAP;
        const float* s2h = s2 + ((size_t)h << 12);
        float s1n = s1[(h << 12) + n];
        float mx = -1e30f;
        for (int jb = 0; jb < d; jb += 8) {
            int j = jb + jslot;
            int tt = (j < d) ? row[j] : 0;
            float e = (j < d) ? lrelu(s1n + s2h[tt]) : -1e30f;
            sW[wid][(j << 3) + h] = e;
            if (h == 0) sT[wid][j] = tt;
            mx = fmaxf(mx, e);
        }
        mx = fmaxf(mx, __shfl_xor(mx, 1, 64));
        mx = fmaxf(mx, __shfl_xor(mx, 2, 64));
        mx = fmaxf(mx, __shfl_xor(mx, 4, 64));
        float den = 0.f;
        for (int jb = 0; jb < d; jb += 8) {
            int j = jb + jslot;
            float e = sW[wid][(j << 3) + h];
            float w = __expf(e - mx);
            sW[wid][(j << 3) + h] = w;
            den += w;
        }
        den += __shfl_xor(den, 1, 64);
        den += __shfl_xor(den, 2, 64);
        den += __shfl_xor(den, 4, 64);
        rden = 1.f / den;
        const unsigned short* Hp = Hb + lane * 8;
        int j = 0;
#pragma unroll 2
        for (; j + 2 <= d; j += 2) {
            int t0 = sT[wid][j], t1 = sT[wid][j + 1];
            float w0 = sW[wid][(j << 3) + h];
            float w1 = sW[wid][((j + 1) << 3) + h];
            u16x8 v0 = *(const u16x8*)(Hp + ((size_t)t0 << 9));
            u16x8 v1 = *(const u16x8*)(Hp + ((size_t)t1 << 9));
#pragma unroll
            for (int i = 0; i < 8; ++i)
                acc[i] += w0 * b2f(v0[i]) + w1 * b2f(v1[i]);
        }
        if (j < d) {
            int t0 = sT[wid][j];
            float w0 = sW[wid][(j << 3) + h];
            u16x8 v0 = *(const u16x8*)(Hp + ((size_t)t0 << 9));
#pragma unroll
            for (int i = 0; i < 8; ++i) acc[i] += w0 * b2f(v0[i]);
        }
    }
    float o[8];
    if (d == 0) {
#pragma unroll
        for (int i = 0; i < 8; ++i) o[i] = cm1[lane * 8 + i] * (1.0f / NN);
    } else {
#pragma unroll
        for (int i = 0; i < 8; ++i) o[i] = acc[i] * rden;
    }
#pragma unroll
    for (int i = 0; i < 8; ++i) {
        float v = o[i] + bh[lane * 8 + i];
        o[i] = v > 0.f ? v : __expf(v) - 1.f;
    }
    float* xw = xr[wid];
    *(float4*)&xw[lane * 8]     = make_float4(o[0], o[1], o[2], o[3]);
    *(float4*)&xw[lane * 8 + 4] = make_float4(o[4], o[5], o[6], o[7]);
    int c = lane & 15, sub = lane >> 4;
    const float* xp = xw + sub * 128;
    const float* wp = Wo + sub * 128 * NCLASS + c;
    float a2 = 0.f;
#pragma unroll 8
    for (int kk = 0; kk < 128; ++kk) a2 += xp[kk] * wp[kk * NCLASS];
    a2 += __shfl_xor(a2, 16, 64);
    a2 += __shfl_xor(a2, 32, 64);
    if (lane < 16) out2[n * NCLASS + c] = a2;
    float r1 = a2 * ao[c], r2 = a2 * ao[NCLASS + c];
#pragma unroll
    for (int m = 8; m >= 1; m >>= 1) {
        r1 += __shfl_xor(r1, m, 16);
        r2 += __shfl_xor(r2, m, 16);
    }
    if (lane == 0) { s1o[n] = r1; s2o[n] = r2; }
    if (lane < 16) atomicAdd(&cms[c], a2);
    __syncthreads();
    if (t < NCLASS) atomicAdd(&cm2[t], cms[t]);
}

__global__ void __launch_bounds__(256)
k_attn2(const int* __restrict__ deg, const int* __restrict__ csr,
        const float* __restrict__ s1o, const float* __restrict__ s2o,
        const float* __restrict__ out2, const float* __restrict__ bo,
        const float* __restrict__ cm2, float* __restrict__ outp) {
    __shared__ float wv[4][CAP];
    __shared__ float o2s[4][16];
    int wid = threadIdx.x >> 6, lane = threadIdx.x & 63;
    int n = blockIdx.x * 4 + wid;
    int c = lane & 15;
    int d = min(deg[n], CAP);
    float val;
    if (d == 0) {
        val = cm2[c] * (1.0f / NN);
    } else {
        float s1n = s1o[n];
        const int* rowp = csr + (size_t)n * CAP;
        int t0 = (lane < d)       ? rowp[lane]       : 0;
        int t1 = (lane + 64 < d)  ? rowp[lane + 64]  : 0;
        int t2 = (lane + 128 < d) ? rowp[lane + 128] : 0;
        float e0 = (lane < d)       ? lrelu(s1n + s2o[t0]) : -1e30f;
        float e1 = (lane + 64 < d)  ? lrelu(s1n + s2o[t1]) : -1e30f;
        float e2 = (lane + 128 < d) ? lrelu(s1n + s2o[t2]) : -1e30f;
        float m = waveMax(fmaxf(e0, fmaxf(e1, e2)));
        float w0 = (lane < d)       ? __expf(e0 - m) : 0.f;
        float w1 = (lane + 64 < d)  ? __expf(e1 - m) : 0.f;
        float w2 = (lane + 128 < d) ? __expf(e2 - m) : 0.f;
        float den = waveSum(w0 + w1 + w2);
        wv[wid][lane]       = w0;
        wv[wid][lane + 64]  = w1;
        wv[wid][lane + 128] = w2;
        int g2 = lane >> 2, q = lane & 3;
        float a4[4] = {};
        for (int j = g2; j < d; j += 16) {
            float w = wv[wid][j];
            int tt = rowp[j];
            float4 v = *(const float4*)(out2 + tt * NCLASS + q * 4);
            a4[0] += w * v.x; a4[1] += w * v.y;
            a4[2] += w * v.z; a4[3] += w * v.w;
        }
#pragma unroll
        for (int m2 = 4; m2 <= 32; m2 <<= 1)
#pragma unroll
            for (int i = 0; i < 4; ++i) a4[i] += __shfl_xor(a4[i], m2, 64);
        if (lane < 4)
            *(float4*)&o2s[wid][lane * 4] = make_float4(a4[0], a4[1], a4[2], a4[3]);
        val = o2s[wid][c] / den;
    }
    val += bo[c];
    float mx = val;
#pragma unroll
    for (int m = 8; m >= 1; m >>= 1) mx = fmaxf(mx, __shfl_xor(mx, m, 16));
    float se = __expf(val - mx);
#pragma unroll
    for (int m = 8; m >= 1; m >>= 1) se += __shfl_xor(se, m, 16);
    float res = val - mx - __logf(se);
    if (lane < 16) outp[n * NCLASS + lane] = res;
}

extern "C" void kernel_launch(void* const* d_in, const int* in_sizes, int n_in,
                              void* d_out, int out_size, void* d_ws, size_t ws_size,
                              hipStream_t stream) {
    const void* features = d_in[0];
    const int*  edges    = (const int*)d_in[1];
    const void* W_heads  = d_in[2];
    const void* a_heads  = d_in[3];
    const void* b_heads  = d_in[4];
    const void* W_out    = d_in[5];
    const void* a_out    = d_in[6];
    const void* b_out    = d_in[7];
    int E = in_sizes[1] / 2;
    int csb = (E + 255) / 256;

    // ---- unified workspace layout (4B units); bits,deg,cm1,cm2 contiguous ----
    unsigned int* bits = (unsigned int*)d_ws;                  // NN*NN/32
    int*   deg  = (int*)(bits + (NN * NN / 32));               // NN
    float* cm1  = (float*)(deg + NN);                          // NHEAD*NHID
    float* cm2  = cm1 + NHEAD * NHID;                          // NCLASS  (zero region ends)
    int*   csr  = (int*)(cm2 + NCLASS);                        // NN*CAP
    float* s1   = (float*)(csr + NN * CAP);                    // NHEAD*NN
    float* s2   = s1 + NHEAD * NN;                             // NHEAD*NN
    float* out2 = s2 + NHEAD * NN;                             // NN*NCLASS
    float* s1o  = out2 + NN * NCLASS;                          // NN
    float* s2o  = s1o + NN;                                    // NN
    float* smallf = s2o + NN;                                  // NSMALL fp32
    unsigned short* Hb    = (unsigned short*)(smallf + NSMALL);// NN*512 bf16 (node-major)
    unsigned short* featb = Hb + (size_t)NN * NHEAD * NHID;    // NN*NFEAT bf16
    unsigned short* Wtb   = featb + (size_t)NN * NFEAT;        // NHEAD*NHID*NFEAT bf16
    float* outp = (float*)d_out;

    // ---- cooperative grid sizing from the runtime's own occupancy math ----
    static int coop_blocks = -2;
    if (coop_blocks == -2) {
        int maxB = 0, ncu = 0, dev = 0;
        if (hipOccupancyMaxActiveBlocksPerMultiprocessor(
                &maxB, reinterpret_cast<const void*>(&k_fused), 256, 0) != hipSuccess)
            maxB = 0;
        (void)hipGetDevice(&dev);
        if (hipDeviceGetAttribute(&ncu, hipDeviceAttributeMultiprocessorCount, dev)
                != hipSuccess)
            ncu = 0;
        coop_blocks = (maxB > 0 && ncu > 0) ? maxB * ncu : 0;
    }
    int nblk = coop_blocks > 1024 ? 1024 : coop_blocks;

    bool done = false;
    if (nblk >= 256) {
        void* args[] = {
            (void*)&features, (void*)&W_heads, (void*)&a_heads, (void*)&b_heads,
            (void*)&W_out, (void*)&a_out, (void*)&b_out, (void*)&edges,
            (void*)&E, (void*)&csb,
            (void*)&featb, (void*)&Wtb, (void*)&smallf, (void*)&bits,
            (void*)&deg, (void*)&csr, (void*)&cm1, (void*)&cm2,
            (void*)&s1, (void*)&s2, (void*)&out2, (void*)&s1o, (void*)&s2o,
            (void*)&Hb, (void*)&outp
        };
        hipError_t err = hipLaunchCooperativeKernel((const void*)k_fused,
                                                    dim3(nblk), dim3(256),
                                                    args, 0, stream);
        if (err == hipSuccess) done = true;
        else (void)hipGetLastError();   // clear sticky error, use fallback
    }
    if (!done) {
        hipMemsetAsync(d_ws, 0, (size_t)NZERO * 4, stream);
        hipLaunchKernelGGL(k_prep, dim3(128 + csb + 896), dim3(256), 0, stream,
                           features, W_heads, a_heads, b_heads, W_out, a_out, b_out,
                           edges, E, csb, featb, Wtb, smallf, bits);
        hipLaunchKernelGGL(k_gemm_ext, dim3(256 + NN / 4), dim3(256), 0, stream,
                           featb, Wtb, smallf, Hb, s1, s2, cm1, bits, deg, csr);
        hipLaunchKernelGGL(k_attn1f, dim3(NN / 4), dim3(256), 0, stream,
                           deg, csr, s1, s2, Hb, smallf + SZ2, cm1,
                           smallf + SZ2 + SZ3, smallf + SZ2 + SZ3 + SZ4,
                           out2, s1o, s2o, cm2);
        hipLaunchKernelGGL(k_attn2, dim3(NN / 4), dim3(256), 0, stream,
                           deg, csr, s1o, s2o, out2,
                           smallf + SZ2 + SZ3 + SZ4 + SZ5, cm2, outp);
    }
}

// Round 4
// 409.111 us; speedup vs baseline: 1.3023x; 1.3023x over previous
//
#include <hip/hip_runtime.h>
#include <hip/hip_bf16.h>

#define NN 4096
#define NFEAT 512
#define NHID 64
#define NHEAD 8
#define NCLASS 16
#define CAP 192
#define LALPHA 0.2f

#define SZ2 (NHEAD*2*NHID)   // a_heads
#define SZ3 (NHEAD*NHID)     // b_heads
#define SZ4 (NFEAT*NCLASS)   // W_out
#define SZ5 (2*NCLASS)       // a_out
#define SZ6 (NCLASS)         // b_out
#define NSMALL (SZ2+SZ3+SZ4+SZ5+SZ6)
#define NGB 64               // grid-barrier words (3 barriers, 64B-spaced)
#define NZERO (NN*NN/32 + NN + NHEAD*NHID + NCLASS + NGB)   // bits+deg+cm1+cm2+gb

typedef __attribute__((ext_vector_type(8))) short bf16x8;
typedef __attribute__((ext_vector_type(4))) float f32x4;
typedef __attribute__((ext_vector_type(8))) unsigned short u16x8;

__device__ __forceinline__ float b2f(unsigned short h) {
    return __uint_as_float(((unsigned int)h) << 16);
}
__device__ __forceinline__ unsigned short f2b(float f) {
    unsigned int u = __float_as_uint(f);
    unsigned int r = (u + 0x7fffu + ((u >> 16) & 1u)) >> 16;
    return (unsigned short)r;
}
__device__ __forceinline__ float waveMax(float v) {
#pragma unroll
    for (int m = 32; m >= 1; m >>= 1) v = fmaxf(v, __shfl_xor(v, m, 64));
    return v;
}
__device__ __forceinline__ float waveSum(float v) {
#pragma unroll
    for (int m = 32; m >= 1; m >>= 1) v += __shfl_xor(v, m, 64);
    return v;
}
__device__ __forceinline__ float lrelu(float e) {
    return e >= 0.f ? e : LALPHA * e;
}

// Hand-rolled grid barrier: lane-0 arrive (agent-scope atomic), last block
// releases flag, others spin with s_sleep. Pre-zeroed by host memset.
// Co-residency of all blocks is guaranteed by hipLaunchCooperativeKernel.
__device__ __forceinline__ void gbar(int* gb, int idx, int nblk) {
    __syncthreads();
    if (threadIdx.x == 0) {
        __threadfence();                       // release (wb L2 for cross-XCD)
        int* ctr  = gb + idx * 16;
        int* flag = gb + idx * 16 + 8;
        int prev = __hip_atomic_fetch_add(ctr, 1, __ATOMIC_ACQ_REL,
                                          __HIP_MEMORY_SCOPE_AGENT);
        if (prev == nblk - 1) {
            __hip_atomic_store(flag, 1, __ATOMIC_RELEASE,
                               __HIP_MEMORY_SCOPE_AGENT);
        } else {
            while (!__hip_atomic_load(flag, __ATOMIC_ACQUIRE,
                                      __HIP_MEMORY_SCOPE_AGENT))
                __builtin_amdgcn_s_sleep(16);
        }
        __threadfence();                       // acquire (inv L1/L2)
    }
    __syncthreads();
}

// =====================================================================
// Fused kernel (phase code verbatim from the verified round-3 version;
// only the sync mechanism changed: cg::grid.sync -> gbar, Z -> memset).
// =====================================================================
__global__ void __launch_bounds__(256, 4)
k_fused(const void* __restrict__ f, const void* __restrict__ Wh_,
        const void* __restrict__ ah_, const void* __restrict__ bh_,
        const void* __restrict__ Wo_, const void* __restrict__ ao_,
        const void* __restrict__ bo_, const int* __restrict__ e32,
        int E, int csb,
        unsigned short* __restrict__ featb, unsigned short* __restrict__ Wtb,
        float* __restrict__ smallf, unsigned int* __restrict__ bits,
        int* __restrict__ deg, int* __restrict__ csr,
        float* __restrict__ cm1, float* __restrict__ cm2,
        float* __restrict__ s1, float* __restrict__ s2,
        float* __restrict__ out2, float* __restrict__ s1o, float* __restrict__ s2o,
        unsigned short* __restrict__ Hb, float* __restrict__ outp,
        int* __restrict__ gb)
{
    __shared__ __align__(16) char Bc[27712];
    __shared__ int sbf, s64f;
    int t = threadIdx.x, bid = blockIdx.x, nblk = gridDim.x;
    int wid = t >> 6, lane = t & 63;

    // dtype detection (block-local, no sync needed)
    if (t < 64) {
        unsigned int w = ((const unsigned int*)f)[t];
        unsigned int lo = w & 0xffffu, e = (lo >> 7) & 0xffu;
        unsigned long long bal = __ballot(lo == 0u || (e >= 100u && e <= 140u));
        if (t == 0) sbf = (__popcll(bal) >= 40);
        unsigned long long bal2 = __ballot(e32[2 * t + 1] == 0);
        if (t == 0) s64f = (__popcll(bal2) >= 48);
    }
    __syncthreads();
    bool bf = (sbf != 0);

    // ---- P0: prep (W transpose | edge bitmap | feature/small cast) ----
    int NVB0 = 128 + csb + 896;
    for (int vb = bid; vb < NVB0; vb += nblk) {
        if (vb < 128) {
            float (*tile)[33] = (float(*)[33])Bc;
            int h = vb >> 4, k0 = (vb & 15) * 32;
            int nn = t & 63, kh = t >> 6;
#pragma unroll
            for (int i = 0; i < 8; ++i) {
                int kk = kh * 8 + i;
                int si = (h << 15) + (k0 + kk) * NHID + nn;
                float v = bf ? b2f(((const unsigned short*)Wh_)[si])
                             : ((const float*)Wh_)[si];
                tile[nn][kk] = v;
            }
            __syncthreads();
            int n2 = t >> 2, kk0 = (t & 3) * 8;
            u16x8 o;
#pragma unroll
            for (int i = 0; i < 8; ++i) o[i] = f2b(tile[n2][kk0 + i]);
            *(u16x8*)&Wtb[(size_t)((h << 6) + n2) * NFEAT + k0 + kk0] = o;
            __syncthreads();
        } else if (vb < 128 + csb) {
            int i = (vb - 128) * 256 + t;
            if (i < E) {
                int s, tt;
                if (s64f) { s = e32[2 * i]; tt = e32[2 * (E + i)]; }
                else      { s = e32[i];     tt = e32[E + i]; }
                s &= (NN - 1); tt &= (NN - 1);
                unsigned int pos = (unsigned int)s * NN + (unsigned int)tt;
                atomicOr(&bits[pos >> 5], 1u << (pos & 31u));
            }
        } else {
            const int NF8 = NN * NFEAT / 8;
            const int TOT = NF8 + NSMALL;
            for (int i = (vb - 128 - csb) * 256 + t; i < TOT; i += 896 * 256) {
                if (i < NF8) {
                    if (bf) {
                        *(u16x8*)&featb[i * 8] = ((const u16x8*)f)[i];
                    } else {
                        float4 lo = ((const float4*)f)[i * 2];
                        float4 hi = ((const float4*)f)[i * 2 + 1];
                        u16x8 o;
                        o[0] = f2b(lo.x); o[1] = f2b(lo.y); o[2] = f2b(lo.z); o[3] = f2b(lo.w);
                        o[4] = f2b(hi.x); o[5] = f2b(hi.y); o[6] = f2b(hi.z); o[7] = f2b(hi.w);
                        *(u16x8*)&featb[i * 8] = o;
                    }
                } else {
                    int r = i - NF8;
                    const void* sp; int off;
                    if (r < SZ2)                        { sp = ah_; off = r; }
                    else if (r < SZ2 + SZ3)             { sp = bh_; off = r - SZ2; }
                    else if (r < SZ2 + SZ3 + SZ4)       { sp = Wo_; off = r - SZ2 - SZ3; }
                    else if (r < SZ2 + SZ3 + SZ4 + SZ5) { sp = ao_; off = r - SZ2 - SZ3 - SZ4; }
                    else                                { sp = bo_; off = r - SZ2 - SZ3 - SZ4 - SZ5; }
                    smallf[r] = bf ? b2f(((const unsigned short*)sp)[off])
                                   : ((const float*)sp)[off];
                }
            }
        }
    }
    gbar(gb, 0, nblk);

    // ---- P1: extract (bitmap -> global csr/deg) + gemm1 ----
    for (int vb = bid; vb < 1024; vb += nblk) {
        {   // extract: registers/shuffles only, no LDS
            int n = vb * 4 + wid;
            uint2 w2 = *(const uint2*)&bits[n * 128 + lane * 2];
            int c = __popc(w2.x) + __popc(w2.y);
            int incl = c;
#pragma unroll
            for (int off = 1; off < 64; off <<= 1) {
                int u = __shfl_up(incl, off, 64);
                if (lane >= off) incl += u;
            }
            int excl = incl - c;
            int total = __shfl(incl, 63, 64);
            if (lane == 0) deg[n] = total;
            int base = n * CAP;
            int tbase = lane * 64;
            unsigned int x = w2.x;
            while (x) {
                int b = __ffs(x) - 1; x &= x - 1;
                if (excl < CAP) csr[base + excl] = tbase + b;
                ++excl;
            }
            unsigned int y = w2.y;
            while (y) {
                int b = __ffs(y) - 1; y &= y - 1;
                if (excl < CAP) csr[base + excl] = tbase + 32 + b;
                ++excl;
            }
        }
        {   // gemm1 tile: h = vb>>7, rows m0..m0+31, wave owns 16 cols
            float* sp1   = (float*)Bc;        // [32]
            float* sp2   = sp1 + 32;          // [32]
            float* cms64 = sp2 + 32;          // [64]
            if (t < 32) sp1[t] = 0.f;
            else if (t < 64) sp2[t - 32] = 0.f;
            __syncthreads();
            int h = vb >> 7, m0 = (vb & 127) << 5;
            int quad = lane >> 4, l16 = lane & 15;
            f32x4 acc0 = {}, acc1 = {};
            const unsigned short* a0p = featb + (size_t)(m0 + l16) * NFEAT + quad * 8;
            const unsigned short* a1p = a0p + 16 * NFEAT;
            const unsigned short* bp  = Wtb + ((size_t)h << 15) + (size_t)(wid * 16 + l16) * NFEAT + quad * 8;
#pragma unroll 4
            for (int k0 = 0; k0 < NFEAT; k0 += 32) {
                bf16x8 a0 = *(const bf16x8*)(a0p + k0);
                bf16x8 a1 = *(const bf16x8*)(a1p + k0);
                bf16x8 b  = *(const bf16x8*)(bp + k0);
                acc0 = __builtin_amdgcn_mfma_f32_16x16x32_bf16(a0, b, acc0, 0, 0, 0);
                acc1 = __builtin_amdgcn_mfma_f32_16x16x32_bf16(a1, b, acc1, 0, 0, 0);
            }
            const float* av = smallf + h * 2 * NHID;
            int col = wid * 16 + l16;
            float av1 = av[col], av2 = av[NHID + col];
            float p1v[2][4], p2v[2][4];
            float csum = 0.f;
#pragma unroll
            for (int rh = 0; rh < 2; ++rh)
#pragma unroll
                for (int r = 0; r < 4; ++r) {
                    float v = rh ? acc1[r] : acc0[r];
                    int row = m0 + rh * 16 + quad * 4 + r;
                    Hb[((size_t)row << 9) + (h << 6) + col] = f2b(v);
                    p1v[rh][r] = v * av1;
                    p2v[rh][r] = v * av2;
                    csum += v;
                }
#pragma unroll
            for (int m = 8; m >= 1; m >>= 1)
#pragma unroll
                for (int rh = 0; rh < 2; ++rh)
#pragma unroll
                    for (int r = 0; r < 4; ++r) {
                        p1v[rh][r] += __shfl_xor(p1v[rh][r], m, 64);
                        p2v[rh][r] += __shfl_xor(p2v[rh][r], m, 64);
                    }
            if (l16 == 0) {
#pragma unroll
                for (int rh = 0; rh < 2; ++rh)
#pragma unroll
                    for (int r = 0; r < 4; ++r) {
                        atomicAdd(&sp1[rh * 16 + quad * 4 + r], p1v[rh][r]);
                        atomicAdd(&sp2[rh * 16 + quad * 4 + r], p2v[rh][r]);
                    }
            }
            csum += __shfl_xor(csum, 16, 64);
            csum += __shfl_xor(csum, 32, 64);
            if (lane < 16) cms64[wid * 16 + lane] = csum;
            __syncthreads();
            if (t < 32) {
                s1[(h << 12) + m0 + t] = sp1[t];
                s2[(h << 12) + m0 + t] = sp2[t];
            }
            if (t < 64) atomicAdd(&cm1[h * NHID + t], cms64[t]);
        }
    }
    gbar(gb, 1, nblk);

    // ---- P2: attn1 (all heads per wave) + bias + ELU + fused gemm2/scores2 ----
    {
        float* sW   = (float*)Bc;               // [4][CAP*8], reused as X row
        int*   sTl  = (int*)(Bc + 24576);       // [4][CAP]
        float* cmsL = (float*)(Bc + 27648);     // [16]
        if (t < NCLASS) cmsL[t] = 0.f;
        __syncthreads();
        const float* bhf = smallf + SZ2;
        const float* Wof = smallf + SZ2 + SZ3;
        const float* aof = Wof + SZ4;
        for (int vb = bid; vb < 1024; vb += nblk) {
            int n = vb * 4 + wid;
            int h = lane >> 3, jslot = lane & 7;
            int d = min(deg[n], CAP);
            float* sWw = sW + wid * (CAP * 8);
            int*   sTw = sTl + wid * CAP;
            const int* row = csr + (size_t)n * CAP;
            float acc[8] = {};
            float rden = 1.f;
            if (d > 0) {
                const float* s2h = s2 + ((size_t)h << 12);
                float s1n = s1[(h << 12) + n];
                float mx = -1e30f;
                for (int jb = 0; jb < d; jb += 8) {
                    int j = jb + jslot;
                    int tt = (j < d) ? row[j] : 0;
                    float e = (j < d) ? lrelu(s1n + s2h[tt]) : -1e30f;
                    sWw[(j << 3) + h] = e;
                    if (h == 0) sTw[j] = tt;
                    mx = fmaxf(mx, e);
                }
                mx = fmaxf(mx, __shfl_xor(mx, 1, 64));
                mx = fmaxf(mx, __shfl_xor(mx, 2, 64));
                mx = fmaxf(mx, __shfl_xor(mx, 4, 64));
                float den = 0.f;
                for (int jb = 0; jb < d; jb += 8) {
                    int j = jb + jslot;
                    float e = sWw[(j << 3) + h];
                    float w = __expf(e - mx);
                    sWw[(j << 3) + h] = w;
                    den += w;
                }
                den += __shfl_xor(den, 1, 64);
                den += __shfl_xor(den, 2, 64);
                den += __shfl_xor(den, 4, 64);
                rden = 1.f / den;
                const unsigned short* Hp = Hb + lane * 8;
                int j = 0;
#pragma unroll 2
                for (; j + 2 <= d; j += 2) {
                    int t0 = sTw[j], t1 = sTw[j + 1];
                    float w0 = sWw[(j << 3) + h];
                    float w1 = sWw[((j + 1) << 3) + h];
                    u16x8 v0 = *(const u16x8*)(Hp + ((size_t)t0 << 9));
                    u16x8 v1 = *(const u16x8*)(Hp + ((size_t)t1 << 9));
#pragma unroll
                    for (int i = 0; i < 8; ++i)
                        acc[i] += w0 * b2f(v0[i]) + w1 * b2f(v1[i]);
                }
                if (j < d) {
                    int t0 = sTw[j];
                    float w0 = sWw[(j << 3) + h];
                    u16x8 v0 = *(const u16x8*)(Hp + ((size_t)t0 << 9));
#pragma unroll
                    for (int i = 0; i < 8; ++i) acc[i] += w0 * b2f(v0[i]);
                }
            }
            float o[8];
            if (d == 0) {
#pragma unroll
                for (int i = 0; i < 8; ++i) o[i] = cm1[lane * 8 + i] * (1.0f / NN);
            } else {
#pragma unroll
                for (int i = 0; i < 8; ++i) o[i] = acc[i] * rden;
            }
#pragma unroll
            for (int i = 0; i < 8; ++i) {
                float v = o[i] + bhf[lane * 8 + i];
                o[i] = v > 0.f ? v : __expf(v) - 1.f;     // ELU
            }
            float* xw = sWw;
            *(float4*)&xw[lane * 8]     = make_float4(o[0], o[1], o[2], o[3]);
            *(float4*)&xw[lane * 8 + 4] = make_float4(o[4], o[5], o[6], o[7]);
            int c = lane & 15, sub = lane >> 4;
            const float* xp = xw + sub * 128;
            const float* wp = Wof + sub * 128 * NCLASS + c;
            float a2 = 0.f;
#pragma unroll 8
            for (int kk = 0; kk < 128; ++kk) a2 += xp[kk] * wp[kk * NCLASS];
            a2 += __shfl_xor(a2, 16, 64);
            a2 += __shfl_xor(a2, 32, 64);
            if (lane < 16) out2[n * NCLASS + c] = a2;
            float r1 = a2 * aof[c], r2 = a2 * aof[NCLASS + c];
#pragma unroll
            for (int m = 8; m >= 1; m >>= 1) {
                r1 += __shfl_xor(r1, m, 16);
                r2 += __shfl_xor(r2, m, 16);
            }
            if (lane == 0) { s1o[n] = r1; s2o[n] = r2; }
            if (lane < 16) atomicAdd(&cmsL[c], a2);
        }
        __syncthreads();
        if (t < NCLASS) atomicAdd(&cm2[t], cmsL[t]);
    }
    gbar(gb, 2, nblk);

    // ---- P3: attn2 + bias + log_softmax ----
    {
        float* wv  = (float*)Bc;            // [4][CAP]
        float* o2s = (float*)(Bc + 3072);   // [4][16]
        const float* bof = smallf + SZ2 + SZ3 + SZ4 + SZ5;
        for (int vb = bid; vb < 1024; vb += nblk) {
            int n = vb * 4 + wid;
            int c = lane & 15;
            int d = min(deg[n], CAP);
            float val;
            if (d == 0) {
                val = cm2[c] * (1.0f / NN);
            } else {
                float s1n = s1o[n];
                const int* rowp = csr + (size_t)n * CAP;
                float* wvw = wv + wid * CAP;
                int t0 = (lane < d)       ? rowp[lane]       : 0;
                int t1 = (lane + 64 < d)  ? rowp[lane + 64]  : 0;
                int t2 = (lane + 128 < d) ? rowp[lane + 128] : 0;
                float e0 = (lane < d)       ? lrelu(s1n + s2o[t0]) : -1e30f;
                float e1 = (lane + 64 < d)  ? lrelu(s1n + s2o[t1]) : -1e30f;
                float e2 = (lane + 128 < d) ? lrelu(s1n + s2o[t2]) : -1e30f;
                float m = waveMax(fmaxf(e0, fmaxf(e1, e2)));
                float w0 = (lane < d)       ? __expf(e0 - m) : 0.f;
                float w1 = (lane + 64 < d)  ? __expf(e1 - m) : 0.f;
                float w2 = (lane + 128 < d) ? __expf(e2 - m) : 0.f;
                float den = waveSum(w0 + w1 + w2);
                wvw[lane]       = w0;
                wvw[lane + 64]  = w1;
                wvw[lane + 128] = w2;
                int g2 = lane >> 2, q = lane & 3;
                float a4[4] = {};
                for (int j = g2; j < d; j += 16) {
                    float w = wvw[j];
                    int tt = rowp[j];
                    float4 v = *(const float4*)(out2 + tt * NCLASS + q * 4);
                    a4[0] += w * v.x; a4[1] += w * v.y;
                    a4[2] += w * v.z; a4[3] += w * v.w;
                }
#pragma unroll
                for (int m2 = 4; m2 <= 32; m2 <<= 1)
#pragma unroll
                    for (int i = 0; i < 4; ++i) a4[i] += __shfl_xor(a4[i], m2, 64);
                if (lane < 4)
                    *(float4*)&o2s[wid * 16 + lane * 4] = make_float4(a4[0], a4[1], a4[2], a4[3]);
                val = o2s[wid * 16 + c] / den;
            }
            val += bof[c];
            float mx = val;
#pragma unroll
            for (int m = 8; m >= 1; m >>= 1) mx = fmaxf(mx, __shfl_xor(mx, m, 16));
            float se = __expf(val - mx);
#pragma unroll
            for (int m = 8; m >= 1; m >>= 1) se += __shfl_xor(se, m, 16);
            float res = val - mx - __logf(se);
            if (lane < 16) outp[n * NCLASS + lane] = res;
        }
    }
}

// =====================================================================
// Fallback kernels (verbatim round-1, known-correct at 147 us)
// =====================================================================
__global__ void __launch_bounds__(256)
k_prep(const void* __restrict__ f, const void* __restrict__ Wh_,
       const void* __restrict__ ah_, const void* __restrict__ bh_,
       const void* __restrict__ Wo_, const void* __restrict__ ao_,
       const void* __restrict__ bo_, const int* __restrict__ e32,
       int E, int csb,
       unsigned short* __restrict__ featb,
       unsigned short* __restrict__ Wtb,
       float* __restrict__ smallf,
       unsigned int* __restrict__ bits) {
    __shared__ int sbf;
    int t = threadIdx.x;
    if (t < 64) {
        unsigned int w = ((const unsigned int*)f)[t];
        unsigned int lo = w & 0xffffu, e = (lo >> 7) & 0xffu;
        unsigned long long bal = __ballot(lo == 0u || (e >= 100u && e <= 140u));
        if (t == 0) sbf = (__popcll(bal) >= 40);
    }
    __syncthreads();
    bool bf = (sbf != 0);
    if (blockIdx.x < 128) {
        __shared__ float tile[64][33];
        int h = blockIdx.x >> 4, k0 = (blockIdx.x & 15) * 32;
        int n = t & 63, kh = t >> 6;
#pragma unroll
        for (int i = 0; i < 8; ++i) {
            int kk = kh * 8 + i;
            int si = (h << 15) + (k0 + kk) * NHID + n;
            float v = bf ? b2f(((const unsigned short*)Wh_)[si])
                         : ((const float*)Wh_)[si];
            tile[n][kk] = v;
        }
        __syncthreads();
        int n2 = t >> 2, kk0 = (t & 3) * 8;
        u16x8 o;
#pragma unroll
        for (int i = 0; i < 8; ++i) o[i] = f2b(tile[n2][kk0 + i]);
        *(u16x8*)&Wtb[(size_t)((h << 6) + n2) * NFEAT + k0 + kk0] = o;
    } else if ((int)blockIdx.x < 128 + csb) {
        __shared__ int s64f;
        if (t < 64) {
            unsigned long long bal = __ballot(e32[2 * t + 1] == 0);
            if (t == 0) s64f = (__popcll(bal) >= 48);
        }
        __syncthreads();
        int i = (blockIdx.x - 128) * 256 + t;
        if (i < E) {
            int s, tt;
            if (s64f) { s = e32[2 * i]; tt = e32[2 * (E + i)]; }
            else      { s = e32[i];     tt = e32[E + i]; }
            s &= (NN - 1); tt &= (NN - 1);
            unsigned int pos = (unsigned int)s * NN + (unsigned int)tt;
            atomicOr(&bits[pos >> 5], 1u << (pos & 31u));
        }
    } else {
        const int NF8 = NN * NFEAT / 8;
        int i = (blockIdx.x - 128 - csb) * 256 + t;
        int stride = (gridDim.x - 128 - csb) * 256;
        const int TOT = NF8 + NSMALL;
        for (; i < TOT; i += stride) {
            if (i < NF8) {
                if (bf) {
                    *(u16x8*)&featb[i * 8] = ((const u16x8*)f)[i];
                } else {
                    float4 lo = ((const float4*)f)[i * 2];
                    float4 hi = ((const float4*)f)[i * 2 + 1];
                    u16x8 o;
                    o[0] = f2b(lo.x); o[1] = f2b(lo.y); o[2] = f2b(lo.z); o[3] = f2b(lo.w);
                    o[4] = f2b(hi.x); o[5] = f2b(hi.y); o[6] = f2b(hi.z); o[7] = f2b(hi.w);
                    *(u16x8*)&featb[i * 8] = o;
                }
            } else {
                int r = i - NF8;
                const void* sp; int off;
                if (r < SZ2)                        { sp = ah_; off = r; }
                else if (r < SZ2 + SZ3)             { sp = bh_; off = r - SZ2; }
                else if (r < SZ2 + SZ3 + SZ4)       { sp = Wo_; off = r - SZ2 - SZ3; }
                else if (r < SZ2 + SZ3 + SZ4 + SZ5) { sp = ao_; off = r - SZ2 - SZ3 - SZ4; }
                else                                { sp = bo_; off = r - SZ2 - SZ3 - SZ4 - SZ5; }
                smallf[r] = bf ? b2f(((const unsigned short*)sp)[off])
                               : ((const float*)sp)[off];
            }
        }
    }
}

__global__ void __launch_bounds__(256)
k_gemm_ext(const unsigned short* __restrict__ Ab,
           const unsigned short* __restrict__ Wtb,
           const float* __restrict__ ah,
           unsigned short* __restrict__ Hb,
           float* __restrict__ s1, float* __restrict__ s2,
           float* __restrict__ cm1,
           const unsigned int* __restrict__ bits,
           int* __restrict__ deg, int* __restrict__ csr) {
    int t = threadIdx.x;
    if (blockIdx.x >= 256) {
        int wid = t >> 6, lane = t & 63;
        int n = (blockIdx.x - 256) * 4 + wid;
        uint2 w = *(const uint2*)&bits[n * 128 + lane * 2];
        int c = __popc(w.x) + __popc(w.y);
        int incl = c;
#pragma unroll
        for (int off = 1; off < 64; off <<= 1) {
            int u = __shfl_up(incl, off, 64);
            if (lane >= off) incl += u;
        }
        int excl = incl - c;
        int total = __shfl(incl, 63, 64);
        if (lane == 0) deg[n] = total;
        int base = n * CAP;
        int tbase = lane * 64;
        unsigned int x = w.x;
        while (x) {
            int b = __ffs(x) - 1; x &= x - 1;
            if (excl < CAP) csr[base + excl] = tbase + b;
            ++excl;
        }
        unsigned int y = w.y;
        while (y) {
            int b = __ffs(y) - 1; y &= y - 1;
            if (excl < CAP) csr[base + excl] = tbase + 32 + b;
            ++excl;
        }
        return;
    }
    __shared__ float cms[64];
    if (t < 64) cms[t] = 0.f;
    __syncthreads();
    int w = t >> 6, l = t & 63;
    int quad = l >> 4, l16 = l & 15;
    int h = blockIdx.x >> 5;
    int m0 = (blockIdx.x & 31) * 128 + w * 32;
    f32x4 acc[2][4] = {};
    const unsigned short* a0p = Ab + (size_t)(m0 + l16) * NFEAT + quad * 8;
    const unsigned short* a1p = a0p + 16 * NFEAT;
    const unsigned short* bp  = Wtb + ((size_t)h << 15) + (size_t)l16 * NFEAT + quad * 8;
#pragma unroll 4
    for (int k0 = 0; k0 < NFEAT; k0 += 32) {
        bf16x8 a0 = *(const bf16x8*)(a0p + k0);
        bf16x8 a1 = *(const bf16x8*)(a1p + k0);
#pragma unroll
        for (int nt = 0; nt < 4; ++nt) {
            bf16x8 b = *(const bf16x8*)(bp + (size_t)nt * 16 * NFEAT + k0);
            acc[0][nt] = __builtin_amdgcn_mfma_f32_16x16x32_bf16(a0, b, acc[0][nt], 0, 0, 0);
            acc[1][nt] = __builtin_amdgcn_mfma_f32_16x16x32_bf16(a1, b, acc[1][nt], 0, 0, 0);
        }
    }
    const float* av = ah + h * 2 * NHID;
    float p1[2][4] = {}, p2[2][4] = {};
#pragma unroll
    for (int rh = 0; rh < 2; ++rh) {
#pragma unroll
        for (int nt = 0; nt < 4; ++nt) {
            int col = nt * 16 + l16;
            float av1 = av[col], av2 = av[NHID + col];
            float csum = 0.f;
#pragma unroll
            for (int r = 0; r < 4; ++r) {
                float v = acc[rh][nt][r];
                int row = m0 + rh * 16 + quad * 4 + r;
                Hb[((size_t)row << 9) + (h << 6) + col] = f2b(v);
                p1[rh][r] += v * av1;
                p2[rh][r] += v * av2;
                csum += v;
            }
            atomicAdd(&cms[col], csum);
        }
    }
#pragma unroll
    for (int m = 8; m >= 1; m >>= 1)
#pragma unroll
        for (int rh = 0; rh < 2; ++rh)
#pragma unroll
            for (int r = 0; r < 4; ++r) {
                p1[rh][r] += __shfl_xor(p1[rh][r], m, 64);
                p2[rh][r] += __shfl_xor(p2[rh][r], m, 64);
            }
    if (l16 == 0) {
#pragma unroll
        for (int rh = 0; rh < 2; ++rh)
#pragma unroll
            for (int r = 0; r < 4; ++r) {
                int row = m0 + rh * 16 + quad * 4 + r;
                s1[(h << 12) + row] = p1[rh][r];
                s2[(h << 12) + row] = p2[rh][r];
            }
    }
    __syncthreads();
    if (t < 64) atomicAdd(&cm1[h * NHID + t], cms[t]);
}

__global__ void __launch_bounds__(256)
k_attn1f(const int* __restrict__ deg, const int* __restrict__ csr,
         const float* __restrict__ s1, const float* __restrict__ s2,
         const unsigned short* __restrict__ Hb,
         const float* __restrict__ bh, const float* __restrict__ cm1,
         const float* __restrict__ Wo, const float* __restrict__ ao,
         float* __restrict__ out2, float* __restrict__ s1o,
         float* __restrict__ s2o, float* __restrict__ cm2) {
    __shared__ float sW[4][CAP * 8];
    __shared__ int   sT[4][CAP];
    __shared__ float xr[4][NFEAT];
    __shared__ float cms[NCLASS];
    int t = threadIdx.x;
    if (t < NCLASS) cms[t] = 0.f;
    __syncthreads();
    int wid = t >> 6, lane = t & 63;
    int n = blockIdx.x * 4 + wid;
    int h = lane >> 3, jslot = lane & 7;
    int d = min(deg[n], CAP);
    float acc[8] = {};
    float rden = 1.f;
    if (d > 0) {
        const int* row = csr + (size_t)n * CAP;
        const float* s2h = s2 + ((size_t)h << 12);
        float s1n = s1[(h << 12) + n];
        float mx = -1e30f;
        for (int jb = 0; jb < d; jb += 8) {
            int j = jb + jslot;
            int tt = (j < d) ? row[j] : 0;
            float e = (j < d) ? lrelu(s1n + s2h[tt]) : -1e30f;
            sW[wid][(j << 3) + h] = e;
            if (h == 0) sT[wid][j] = tt;
            mx = fmaxf(mx, e);
        }
        mx = fmaxf(mx, __shfl_xor(mx, 1, 64));
        mx = fmaxf(mx, __shfl_xor(mx, 2, 64));
        mx = fmaxf(mx, __shfl_xor(mx, 4, 64));
        float den = 0.f;
        for (int jb = 0; jb < d; jb += 8) {
            int j = jb + jslot;
            float e = sW[wid][(j << 3) + h];
            float w = __expf(e - mx);
            sW[wid][(j << 3) + h] = w;
            den += w;
        }
        den += __shfl_xor(den, 1, 64);
        den += __shfl_xor(den, 2, 64);
        den += __shfl_xor(den, 4, 64);
        rden = 1.f / den;
        const unsigned short* Hp = Hb + lane * 8;
        int j = 0;
#pragma unroll 2
        for (; j + 2 <= d; j += 2) {
            int t0 = sT[wid][j], t1 = sT[wid][j + 1];
            float w0 = sW[wid][(j << 3) + h];
            float w1 = sW[wid][((j + 1) << 3) + h];
            u16x8 v0 = *(const u16x8*)(Hp + ((size_t)t0 << 9));
            u16x8 v1 = *(const u16x8*)(Hp + ((size_t)t1 << 9));
#pragma unroll
            for (int i = 0; i < 8; ++i)
                acc[i] += w0 * b2f(v0[i]) + w1 * b2f(v1[i]);
        }
        if (j < d) {
            int t0 = sT[wid][j];
            float w0 = sW[wid][(j << 3) + h];
            u16x8 v0 = *(const u16x8*)(Hp + ((size_t)t0 << 9));
#pragma unroll
            for (int i = 0; i < 8; ++i) acc[i] += w0 * b2f(v0[i]);
        }
    }
    float o[8];
    if (d == 0) {
#pragma unroll
        for (int i = 0; i < 8; ++i) o[i] = cm1[lane * 8 + i] * (1.0f / NN);
    } else {
#pragma unroll
        for (int i = 0; i < 8; ++i) o[i] = acc[i] * rden;
    }
#pragma unroll
    for (int i = 0; i < 8; ++i) {
        float v = o[i] + bh[lane * 8 + i];
        o[i] = v > 0.f ? v : __expf(v) - 1.f;
    }
    float* xw = xr[wid];
    *(float4*)&xw[lane * 8]     = make_float4(o[0], o[1], o[2], o[3]);
    *(float4*)&xw[lane * 8 + 4] = make_float4(o[4], o[5], o[6], o[7]);
    int c = lane & 15, sub = lane >> 4;
    const float* xp = xw + sub * 128;
    const float* wp = Wo + sub * 128 * NCLASS + c;
    float a2 = 0.f;
#pragma unroll 8
    for (int kk = 0; kk < 128; ++kk) a2 += xp[kk] * wp[kk * NCLASS];
    a2 += __shfl_xor(a2, 16, 64);
    a2 += __shfl_xor(a2, 32, 64);
    if (lane < 16) out2[n * NCLASS + c] = a2;
    float r1 = a2 * ao[c], r2 = a2 * ao[NCLASS + c];
#pragma unroll
    for (int m = 8; m >= 1; m >>= 1) {
        r1 += __shfl_xor(r1, m, 16);
        r2 += __shfl_xor(r2, m, 16);
    }
    if (lane == 0) { s1o[n] = r1; s2o[n] = r2; }
    if (lane < 16) atomicAdd(&cms[c], a2);
    __syncthreads();
    if (t < NCLASS) atomicAdd(&cm2[t], cms[t]);
}

__global__ void __launch_bounds__(256)
k_attn2(const int* __restrict__ deg, const int* __restrict__ csr,
        const float* __restrict__ s1o, const float* __restrict__ s2o,
        const float* __restrict__ out2, const float* __restrict__ bo,
        const float* __restrict__ cm2, float* __restrict__ outp) {
    __shared__ float wv[4][CAP];
    __shared__ float o2s[4][16];
    int wid = threadIdx.x >> 6, lane = threadIdx.x & 63;
    int n = blockIdx.x * 4 + wid;
    int c = lane & 15;
    int d = min(deg[n], CAP);
    float val;
    if (d == 0) {
        val = cm2[c] * (1.0f / NN);
    } else {
        float s1n = s1o[n];
        const int* rowp = csr + (size_t)n * CAP;
        int t0 = (lane < d)       ? rowp[lane]       : 0;
        int t1 = (lane + 64 < d)  ? rowp[lane + 64]  : 0;
        int t2 = (lane + 128 < d) ? rowp[lane + 128] : 0;
        float e0 = (lane < d)       ? lrelu(s1n + s2o[t0]) : -1e30f;
        float e1 = (lane + 64 < d)  ? lrelu(s1n + s2o[t1]) : -1e30f;
        float e2 = (lane + 128 < d) ? lrelu(s1n + s2o[t2]) : -1e30f;
        float m = waveMax(fmaxf(e0, fmaxf(e1, e2)));
        float w0 = (lane < d)       ? __expf(e0 - m) : 0.f;
        float w1 = (lane + 64 < d)  ? __expf(e1 - m) : 0.f;
        float w2 = (lane + 128 < d) ? __expf(e2 - m) : 0.f;
        float den = waveSum(w0 + w1 + w2);
        wv[wid][lane]       = w0;
        wv[wid][lane + 64]  = w1;
        wv[wid][lane + 128] = w2;
        int g2 = lane >> 2, q = lane & 3;
        float a4[4] = {};
        for (int j = g2; j < d; j += 16) {
            float w = wv[wid][j];
            int tt = rowp[j];
            float4 v = *(const float4*)(out2 + tt * NCLASS + q * 4);
            a4[0] += w * v.x; a4[1] += w * v.y;
            a4[2] += w * v.z; a4[3] += w * v.w;
        }
#pragma unroll
        for (int m2 = 4; m2 <= 32; m2 <<= 1)
#pragma unroll
            for (int i = 0; i < 4; ++i) a4[i] += __shfl_xor(a4[i], m2, 64);
        if (lane < 4)
            *(float4*)&o2s[wid][lane * 4] = make_float4(a4[0], a4[1], a4[2], a4[3]);
        val = o2s[wid][c] / den;
    }
    val += bo[c];
    float mx = val;
#pragma unroll
    for (int m = 8; m >= 1; m >>= 1) mx = fmaxf(mx, __shfl_xor(mx, m, 16));
    float se = __expf(val - mx);
#pragma unroll
    for (int m = 8; m >= 1; m >>= 1) se += __shfl_xor(se, m, 16);
    float res = val - mx - __logf(se);
    if (lane < 16) outp[n * NCLASS + lane] = res;
}

extern "C" void kernel_launch(void* const* d_in, const int* in_sizes, int n_in,
                              void* d_out, int out_size, void* d_ws, size_t ws_size,
                              hipStream_t stream) {
    const void* features = d_in[0];
    const int*  edges    = (const int*)d_in[1];
    const void* W_heads  = d_in[2];
    const void* a_heads  = d_in[3];
    const void* b_heads  = d_in[4];
    const void* W_out    = d_in[5];
    const void* a_out    = d_in[6];
    const void* b_out    = d_in[7];
    int E = in_sizes[1] / 2;
    int csb = (E + 255) / 256;

    // ---- workspace layout (4B units); bits,deg,cm1,cm2,gb contiguous zero region ----
    unsigned int* bits = (unsigned int*)d_ws;                  // NN*NN/32
    int*   deg  = (int*)(bits + (NN * NN / 32));               // NN
    float* cm1  = (float*)(deg + NN);                          // NHEAD*NHID
    float* cm2  = cm1 + NHEAD * NHID;                          // NCLASS
    int*   gb   = (int*)(cm2 + NCLASS);                        // NGB (zero region ends)
    int*   csr  = gb + NGB;                                    // NN*CAP
    float* s1   = (float*)(csr + NN * CAP);                    // NHEAD*NN
    float* s2   = s1 + NHEAD * NN;                             // NHEAD*NN
    float* out2 = s2 + NHEAD * NN;                             // NN*NCLASS
    float* s1o  = out2 + NN * NCLASS;                          // NN
    float* s2o  = s1o + NN;                                    // NN
    float* smallf = s2o + NN;                                  // NSMALL fp32
    unsigned short* Hb    = (unsigned short*)(smallf + NSMALL);// NN*512 bf16 (node-major)
    unsigned short* featb = Hb + (size_t)NN * NHEAD * NHID;    // NN*NFEAT bf16
    unsigned short* Wtb   = featb + (size_t)NN * NFEAT;        // NHEAD*NHID*NFEAT bf16
    float* outp = (float*)d_out;

    // zero bits+deg+cm1+cm2+barrier state (2.1 MB)
    hipMemsetAsync(d_ws, 0, (size_t)NZERO * 4, stream);

    // ---- cooperative grid sizing (runtime validates co-residency) ----
    static int coop_blocks = -2;
    if (coop_blocks == -2) {
        int maxB = 0, ncu = 0, dev = 0;
        if (hipOccupancyMaxActiveBlocksPerMultiprocessor(
                &maxB, reinterpret_cast<const void*>(&k_fused), 256, 0) != hipSuccess)
            maxB = 0;
        (void)hipGetDevice(&dev);
        if (hipDeviceGetAttribute(&ncu, hipDeviceAttributeMultiprocessorCount, dev)
                != hipSuccess)
            ncu = 0;
        coop_blocks = (maxB > 0 && ncu > 0) ? maxB * ncu : 0;
    }
    int nblk = coop_blocks > 1024 ? 1024 : coop_blocks;

    bool done = false;
    if (nblk >= 64) {
        void* args[] = {
            (void*)&features, (void*)&W_heads, (void*)&a_heads, (void*)&b_heads,
            (void*)&W_out, (void*)&a_out, (void*)&b_out, (void*)&edges,
            (void*)&E, (void*)&csb,
            (void*)&featb, (void*)&Wtb, (void*)&smallf, (void*)&bits,
            (void*)&deg, (void*)&csr, (void*)&cm1, (void*)&cm2,
            (void*)&s1, (void*)&s2, (void*)&out2, (void*)&s1o, (void*)&s2o,
            (void*)&Hb, (void*)&outp, (void*)&gb
        };
        hipError_t err = hipLaunchCooperativeKernel((const void*)k_fused,
                                                    dim3(nblk), dim3(256),
                                                    args, 0, stream);
        if (err == hipSuccess) done = true;
        else (void)hipGetLastError();   // clear sticky error, use fallback
    }
    if (!done) {
        hipLaunchKernelGGL(k_prep, dim3(128 + csb + 896), dim3(256), 0, stream,
                           features, W_heads, a_heads, b_heads, W_out, a_out, b_out,
                           edges, E, csb, featb, Wtb, smallf, bits);
        hipLaunchKernelGGL(k_gemm_ext, dim3(256 + NN / 4), dim3(256), 0, stream,
                           featb, Wtb, smallf, Hb, s1, s2, cm1, bits, deg, csr);
        hipLaunchKernelGGL(k_attn1f, dim3(NN / 4), dim3(256), 0, stream,
                           deg, csr, s1, s2, Hb, smallf + SZ2, cm1,
                           smallf + SZ2 + SZ3, smallf + SZ2 + SZ3 + SZ4,
                           out2, s1o, s2o, cm2);
        hipLaunchKernelGGL(k_attn2, dim3(NN / 4), dim3(256), 0, stream,
                           deg, csr, s1o, s2o, out2,
                           smallf + SZ2 + SZ3 + SZ4 + SZ5, cm2, outp);
    }
}

// Round 5
// 222.646 us; speedup vs baseline: 2.3929x; 1.8375x over previous
//
#include <hip/hip_runtime.h>
#include <hip/hip_bf16.h>

#define NN 4096
#define NFEAT 512
#define NHID 64
#define NHEAD 8
#define NCLASS 16
#define CAP 192
#define LALPHA 0.2f

#define SZ2 (NHEAD*2*NHID)   // a_heads
#define SZ3 (NHEAD*NHID)     // b_heads
#define SZ4 (NFEAT*NCLASS)   // W_out
#define SZ5 (2*NCLASS)       // a_out
#define SZ6 (NCLASS)         // b_out
#define NSMALL (SZ2+SZ3+SZ4+SZ5+SZ6)
#define NGB 128              // grid-barrier words (3 barriers, 128B-spaced)
#define NZERO (NN*NN/32 + NN + NHEAD*NHID + NCLASS + NGB)   // bits+deg+cm1+cm2+gb

typedef __attribute__((ext_vector_type(8))) short bf16x8;
typedef __attribute__((ext_vector_type(4))) float f32x4;
typedef __attribute__((ext_vector_type(8))) unsigned short u16x8;

__device__ __forceinline__ float b2f(unsigned short h) {
    return __uint_as_float(((unsigned int)h) << 16);
}
__device__ __forceinline__ unsigned short f2b(float f) {
    unsigned int u = __float_as_uint(f);
    unsigned int r = (u + 0x7fffu + ((u >> 16) & 1u)) >> 16;
    return (unsigned short)r;
}
__device__ __forceinline__ float waveMax(float v) {
#pragma unroll
    for (int m = 32; m >= 1; m >>= 1) v = fmaxf(v, __shfl_xor(v, m, 64));
    return v;
}
__device__ __forceinline__ float waveSum(float v) {
#pragma unroll
    for (int m = 32; m >= 1; m >>= 1) v += __shfl_xor(v, m, 64);
    return v;
}
__device__ __forceinline__ float lrelu(float e) {
    return e >= 0.f ? e : LALPHA * e;
}

#if defined(__has_builtin)
#if __has_builtin(__builtin_amdgcn_fence)
#define GAT_HAS_FENCE 1
#endif
#endif
#ifdef GAT_HAS_FENCE
#define REL_FENCE() __builtin_amdgcn_fence(__ATOMIC_RELEASE, "agent")
#define ACQ_FENCE() __builtin_amdgcn_fence(__ATOMIC_ACQUIRE, "agent")
#else
#define REL_FENCE() __threadfence()
#define ACQ_FENCE() __threadfence()
#endif

// Minimal-coherence grid barrier:
//  - one release fence (L2 writeback) per block BEFORE arrival
//  - RELAXED fetch_add arrive, RELAXED flag store/poll (no per-poll cache inv!)
//  - one acquire fence (L2 inv) per block AFTER flag observation
// Round-4's acquire-spin invalidated L1/L2 every ~0.4us per spinning block --
// a grid-wide invalidation storm that poisoned working blocks (both here and
// in cg::grid_group::sync, which measured identically). This version does
// exactly one wbl2 + one inv per block per barrier.
__device__ __forceinline__ void gbar(int* gb, int idx, int nblk) {
    __syncthreads();
    if (threadIdx.x == 0) {
        REL_FENCE();                           // push this block's writes to L3
        int* ctr  = gb + idx * 32;
        int* flag = gb + idx * 32 + 16;
        int prev = __hip_atomic_fetch_add(ctr, 1, __ATOMIC_RELAXED,
                                          __HIP_MEMORY_SCOPE_AGENT);
        if (prev == nblk - 1) {
            __hip_atomic_store(flag, 1, __ATOMIC_RELAXED,
                               __HIP_MEMORY_SCOPE_AGENT);
        } else {
            while (__hip_atomic_load(flag, __ATOMIC_RELAXED,
                                     __HIP_MEMORY_SCOPE_AGENT) == 0)
                __builtin_amdgcn_s_sleep(8);
        }
        ACQ_FENCE();                           // invalidate stale L1/L2 once
    }
    __syncthreads();
}

// =====================================================================
// Fused kernel (phase code verbatim from the twice-verified version;
// only the barrier protocol changed).
// =====================================================================
__global__ void __launch_bounds__(256, 4)
k_fused(const void* __restrict__ f, const void* __restrict__ Wh_,
        const void* __restrict__ ah_, const void* __restrict__ bh_,
        const void* __restrict__ Wo_, const void* __restrict__ ao_,
        const void* __restrict__ bo_, const int* __restrict__ e32,
        int E, int csb,
        unsigned short* __restrict__ featb, unsigned short* __restrict__ Wtb,
        float* __restrict__ smallf, unsigned int* __restrict__ bits,
        int* __restrict__ deg, int* __restrict__ csr,
        float* __restrict__ cm1, float* __restrict__ cm2,
        float* __restrict__ s1, float* __restrict__ s2,
        float* __restrict__ out2, float* __restrict__ s1o, float* __restrict__ s2o,
        unsigned short* __restrict__ Hb, float* __restrict__ outp,
        int* __restrict__ gb)
{
    __shared__ __align__(16) char Bc[27712];
    __shared__ int sbf, s64f;
    int t = threadIdx.x, bid = blockIdx.x, nblk = gridDim.x;
    int wid = t >> 6, lane = t & 63;

    // dtype detection (block-local, no sync needed)
    if (t < 64) {
        unsigned int w = ((const unsigned int*)f)[t];
        unsigned int lo = w & 0xffffu, e = (lo >> 7) & 0xffu;
        unsigned long long bal = __ballot(lo == 0u || (e >= 100u && e <= 140u));
        if (t == 0) sbf = (__popcll(bal) >= 40);
        unsigned long long bal2 = __ballot(e32[2 * t + 1] == 0);
        if (t == 0) s64f = (__popcll(bal2) >= 48);
    }
    __syncthreads();
    bool bf = (sbf != 0);

    // ---- P0: prep (W transpose | edge bitmap | feature/small cast) ----
    int NVB0 = 128 + csb + 896;
    for (int vb = bid; vb < NVB0; vb += nblk) {
        if (vb < 128) {
            float (*tile)[33] = (float(*)[33])Bc;
            int h = vb >> 4, k0 = (vb & 15) * 32;
            int nn = t & 63, kh = t >> 6;
#pragma unroll
            for (int i = 0; i < 8; ++i) {
                int kk = kh * 8 + i;
                int si = (h << 15) + (k0 + kk) * NHID + nn;
                float v = bf ? b2f(((const unsigned short*)Wh_)[si])
                             : ((const float*)Wh_)[si];
                tile[nn][kk] = v;
            }
            __syncthreads();
            int n2 = t >> 2, kk0 = (t & 3) * 8;
            u16x8 o;
#pragma unroll
            for (int i = 0; i < 8; ++i) o[i] = f2b(tile[n2][kk0 + i]);
            *(u16x8*)&Wtb[(size_t)((h << 6) + n2) * NFEAT + k0 + kk0] = o;
            __syncthreads();
        } else if (vb < 128 + csb) {
            int i = (vb - 128) * 256 + t;
            if (i < E) {
                int s, tt;
                if (s64f) { s = e32[2 * i]; tt = e32[2 * (E + i)]; }
                else      { s = e32[i];     tt = e32[E + i]; }
                s &= (NN - 1); tt &= (NN - 1);
                unsigned int pos = (unsigned int)s * NN + (unsigned int)tt;
                atomicOr(&bits[pos >> 5], 1u << (pos & 31u));
            }
        } else {
            const int NF8 = NN * NFEAT / 8;
            const int TOT = NF8 + NSMALL;
            for (int i = (vb - 128 - csb) * 256 + t; i < TOT; i += 896 * 256) {
                if (i < NF8) {
                    if (bf) {
                        *(u16x8*)&featb[i * 8] = ((const u16x8*)f)[i];
                    } else {
                        float4 lo = ((const float4*)f)[i * 2];
                        float4 hi = ((const float4*)f)[i * 2 + 1];
                        u16x8 o;
                        o[0] = f2b(lo.x); o[1] = f2b(lo.y); o[2] = f2b(lo.z); o[3] = f2b(lo.w);
                        o[4] = f2b(hi.x); o[5] = f2b(hi.y); o[6] = f2b(hi.z); o[7] = f2b(hi.w);
                        *(u16x8*)&featb[i * 8] = o;
                    }
                } else {
                    int r = i - NF8;
                    const void* sp; int off;
                    if (r < SZ2)                        { sp = ah_; off = r; }
                    else if (r < SZ2 + SZ3)             { sp = bh_; off = r - SZ2; }
                    else if (r < SZ2 + SZ3 + SZ4)       { sp = Wo_; off = r - SZ2 - SZ3; }
                    else if (r < SZ2 + SZ3 + SZ4 + SZ5) { sp = ao_; off = r - SZ2 - SZ3 - SZ4; }
                    else                                { sp = bo_; off = r - SZ2 - SZ3 - SZ4 - SZ5; }
                    smallf[r] = bf ? b2f(((const unsigned short*)sp)[off])
                                   : ((const float*)sp)[off];
                }
            }
        }
    }
    gbar(gb, 0, nblk);

    // ---- P1: extract (bitmap -> global csr/deg) + gemm1 ----
    for (int vb = bid; vb < 1024; vb += nblk) {
        {   // extract: registers/shuffles only, no LDS
            int n = vb * 4 + wid;
            uint2 w2 = *(const uint2*)&bits[n * 128 + lane * 2];
            int c = __popc(w2.x) + __popc(w2.y);
            int incl = c;
#pragma unroll
            for (int off = 1; off < 64; off <<= 1) {
                int u = __shfl_up(incl, off, 64);
                if (lane >= off) incl += u;
            }
            int excl = incl - c;
            int total = __shfl(incl, 63, 64);
            if (lane == 0) deg[n] = total;
            int base = n * CAP;
            int tbase = lane * 64;
            unsigned int x = w2.x;
            while (x) {
                int b = __ffs(x) - 1; x &= x - 1;
                if (excl < CAP) csr[base + excl] = tbase + b;
                ++excl;
            }
            unsigned int y = w2.y;
            while (y) {
                int b = __ffs(y) - 1; y &= y - 1;
                if (excl < CAP) csr[base + excl] = tbase + 32 + b;
                ++excl;
            }
        }
        {   // gemm1 tile: h = vb>>7, rows m0..m0+31, wave owns 16 cols
            float* sp1   = (float*)Bc;        // [32]
            float* sp2   = sp1 + 32;          // [32]
            float* cms64 = sp2 + 32;          // [64]
            if (t < 32) sp1[t] = 0.f;
            else if (t < 64) sp2[t - 32] = 0.f;
            __syncthreads();
            int h = vb >> 7, m0 = (vb & 127) << 5;
            int quad = lane >> 4, l16 = lane & 15;
            f32x4 acc0 = {}, acc1 = {};
            const unsigned short* a0p = featb + (size_t)(m0 + l16) * NFEAT + quad * 8;
            const unsigned short* a1p = a0p + 16 * NFEAT;
            const unsigned short* bp  = Wtb + ((size_t)h << 15) + (size_t)(wid * 16 + l16) * NFEAT + quad * 8;
#pragma unroll 4
            for (int k0 = 0; k0 < NFEAT; k0 += 32) {
                bf16x8 a0 = *(const bf16x8*)(a0p + k0);
                bf16x8 a1 = *(const bf16x8*)(a1p + k0);
                bf16x8 b  = *(const bf16x8*)(bp + k0);
                acc0 = __builtin_amdgcn_mfma_f32_16x16x32_bf16(a0, b, acc0, 0, 0, 0);
                acc1 = __builtin_amdgcn_mfma_f32_16x16x32_bf16(a1, b, acc1, 0, 0, 0);
            }
            const float* av = smallf + h * 2 * NHID;
            int col = wid * 16 + l16;
            float av1 = av[col], av2 = av[NHID + col];
            float p1v[2][4], p2v[2][4];
            float csum = 0.f;
#pragma unroll
            for (int rh = 0; rh < 2; ++rh)
#pragma unroll
                for (int r = 0; r < 4; ++r) {
                    float v = rh ? acc1[r] : acc0[r];
                    int row = m0 + rh * 16 + quad * 4 + r;
                    Hb[((size_t)row << 9) + (h << 6) + col] = f2b(v);
                    p1v[rh][r] = v * av1;
                    p2v[rh][r] = v * av2;
                    csum += v;
                }
#pragma unroll
            for (int m = 8; m >= 1; m >>= 1)
#pragma unroll
                for (int rh = 0; rh < 2; ++rh)
#pragma unroll
                    for (int r = 0; r < 4; ++r) {
                        p1v[rh][r] += __shfl_xor(p1v[rh][r], m, 64);
                        p2v[rh][r] += __shfl_xor(p2v[rh][r], m, 64);
                    }
            if (l16 == 0) {
#pragma unroll
                for (int rh = 0; rh < 2; ++rh)
#pragma unroll
                    for (int r = 0; r < 4; ++r) {
                        atomicAdd(&sp1[rh * 16 + quad * 4 + r], p1v[rh][r]);
                        atomicAdd(&sp2[rh * 16 + quad * 4 + r], p2v[rh][r]);
                    }
            }
            csum += __shfl_xor(csum, 16, 64);
            csum += __shfl_xor(csum, 32, 64);
            if (lane < 16) cms64[wid * 16 + lane] = csum;
            __syncthreads();
            if (t < 32) {
                s1[(h << 12) + m0 + t] = sp1[t];
                s2[(h << 12) + m0 + t] = sp2[t];
            }
            if (t < 64) atomicAdd(&cm1[h * NHID + t], cms64[t]);
        }
    }
    gbar(gb, 1, nblk);

    // ---- P2: attn1 (all heads per wave) + bias + ELU + fused gemm2/scores2 ----
    {
        float* sW   = (float*)Bc;               // [4][CAP*8], reused as X row
        int*   sTl  = (int*)(Bc + 24576);       // [4][CAP]
        float* cmsL = (float*)(Bc + 27648);     // [16]
        if (t < NCLASS) cmsL[t] = 0.f;
        __syncthreads();
        const float* bhf = smallf + SZ2;
        const float* Wof = smallf + SZ2 + SZ3;
        const float* aof = Wof + SZ4;
        for (int vb = bid; vb < 1024; vb += nblk) {
            int n = vb * 4 + wid;
            int h = lane >> 3, jslot = lane & 7;
            int d = min(deg[n], CAP);
            float* sWw = sW + wid * (CAP * 8);
            int*   sTw = sTl + wid * CAP;
            const int* row = csr + (size_t)n * CAP;
            float acc[8] = {};
            float rden = 1.f;
            if (d > 0) {
                const float* s2h = s2 + ((size_t)h << 12);
                float s1n = s1[(h << 12) + n];
                float mx = -1e30f;
                for (int jb = 0; jb < d; jb += 8) {
                    int j = jb + jslot;
                    int tt = (j < d) ? row[j] : 0;
                    float e = (j < d) ? lrelu(s1n + s2h[tt]) : -1e30f;
                    sWw[(j << 3) + h] = e;
                    if (h == 0) sTw[j] = tt;
                    mx = fmaxf(mx, e);
                }
                mx = fmaxf(mx, __shfl_xor(mx, 1, 64));
                mx = fmaxf(mx, __shfl_xor(mx, 2, 64));
                mx = fmaxf(mx, __shfl_xor(mx, 4, 64));
                float den = 0.f;
                for (int jb = 0; jb < d; jb += 8) {
                    int j = jb + jslot;
                    float e = sWw[(j << 3) + h];
                    float w = __expf(e - mx);
                    sWw[(j << 3) + h] = w;
                    den += w;
                }
                den += __shfl_xor(den, 1, 64);
                den += __shfl_xor(den, 2, 64);
                den += __shfl_xor(den, 4, 64);
                rden = 1.f / den;
                const unsigned short* Hp = Hb + lane * 8;
                int j = 0;
#pragma unroll 2
                for (; j + 2 <= d; j += 2) {
                    int t0 = sTw[j], t1 = sTw[j + 1];
                    float w0 = sWw[(j << 3) + h];
                    float w1 = sWw[((j + 1) << 3) + h];
                    u16x8 v0 = *(const u16x8*)(Hp + ((size_t)t0 << 9));
                    u16x8 v1 = *(const u16x8*)(Hp + ((size_t)t1 << 9));
#pragma unroll
                    for (int i = 0; i < 8; ++i)
                        acc[i] += w0 * b2f(v0[i]) + w1 * b2f(v1[i]);
                }
                if (j < d) {
                    int t0 = sTw[j];
                    float w0 = sWw[(j << 3) + h];
                    u16x8 v0 = *(const u16x8*)(Hp + ((size_t)t0 << 9));
#pragma unroll
                    for (int i = 0; i < 8; ++i) acc[i] += w0 * b2f(v0[i]);
                }
            }
            float o[8];
            if (d == 0) {
#pragma unroll
                for (int i = 0; i < 8; ++i) o[i] = cm1[lane * 8 + i] * (1.0f / NN);
            } else {
#pragma unroll
                for (int i = 0; i < 8; ++i) o[i] = acc[i] * rden;
            }
#pragma unroll
            for (int i = 0; i < 8; ++i) {
                float v = o[i] + bhf[lane * 8 + i];
                o[i] = v > 0.f ? v : __expf(v) - 1.f;     // ELU
            }
            float* xw = sWw;
            *(float4*)&xw[lane * 8]     = make_float4(o[0], o[1], o[2], o[3]);
            *(float4*)&xw[lane * 8 + 4] = make_float4(o[4], o[5], o[6], o[7]);
            int c = lane & 15, sub = lane >> 4;
            const float* xp = xw + sub * 128;
            const float* wp = Wof + sub * 128 * NCLASS + c;
            float a2 = 0.f;
#pragma unroll 8
            for (int kk = 0; kk < 128; ++kk) a2 += xp[kk] * wp[kk * NCLASS];
            a2 += __shfl_xor(a2, 16, 64);
            a2 += __shfl_xor(a2, 32, 64);
            if (lane < 16) out2[n * NCLASS + c] = a2;
            float r1 = a2 * aof[c], r2 = a2 * aof[NCLASS + c];
#pragma unroll
            for (int m = 8; m >= 1; m >>= 1) {
                r1 += __shfl_xor(r1, m, 16);
                r2 += __shfl_xor(r2, m, 16);
            }
            if (lane == 0) { s1o[n] = r1; s2o[n] = r2; }
            if (lane < 16) atomicAdd(&cmsL[c], a2);
        }
        __syncthreads();
        if (t < NCLASS) atomicAdd(&cm2[t], cmsL[t]);
    }
    gbar(gb, 2, nblk);

    // ---- P3: attn2 + bias + log_softmax ----
    {
        float* wv  = (float*)Bc;            // [4][CAP]
        float* o2s = (float*)(Bc + 3072);   // [4][16]
        const float* bof = smallf + SZ2 + SZ3 + SZ4 + SZ5;
        for (int vb = bid; vb < 1024; vb += nblk) {
            int n = vb * 4 + wid;
            int c = lane & 15;
            int d = min(deg[n], CAP);
            float val;
            if (d == 0) {
                val = cm2[c] * (1.0f / NN);
            } else {
                float s1n = s1o[n];
                const int* rowp = csr + (size_t)n * CAP;
                float* wvw = wv + wid * CAP;
                int t0 = (lane < d)       ? rowp[lane]       : 0;
                int t1 = (lane + 64 < d)  ? rowp[lane + 64]  : 0;
                int t2 = (lane + 128 < d) ? rowp[lane + 128] : 0;
                float e0 = (lane < d)       ? lrelu(s1n + s2o[t0]) : -1e30f;
                float e1 = (lane + 64 < d)  ? lrelu(s1n + s2o[t1]) : -1e30f;
                float e2 = (lane + 128 < d) ? lrelu(s1n + s2o[t2]) : -1e30f;
                float m = waveMax(fmaxf(e0, fmaxf(e1, e2)));
                float w0 = (lane < d)       ? __expf(e0 - m) : 0.f;
                float w1 = (lane + 64 < d)  ? __expf(e1 - m) : 0.f;
                float w2 = (lane + 128 < d) ? __expf(e2 - m) : 0.f;
                float den = waveSum(w0 + w1 + w2);
                wvw[lane]       = w0;
                wvw[lane + 64]  = w1;
                wvw[lane + 128] = w2;
                int g2 = lane >> 2, q = lane & 3;
                float a4[4] = {};
                for (int j = g2; j < d; j += 16) {
                    float w = wvw[j];
                    int tt = rowp[j];
                    float4 v = *(const float4*)(out2 + tt * NCLASS + q * 4);
                    a4[0] += w * v.x; a4[1] += w * v.y;
                    a4[2] += w * v.z; a4[3] += w * v.w;
                }
#pragma unroll
                for (int m2 = 4; m2 <= 32; m2 <<= 1)
#pragma unroll
                    for (int i = 0; i < 4; ++i) a4[i] += __shfl_xor(a4[i], m2, 64);
                if (lane < 4)
                    *(float4*)&o2s[wid * 16 + lane * 4] = make_float4(a4[0], a4[1], a4[2], a4[3]);
                val = o2s[wid * 16 + c] / den;
            }
            val += bof[c];
            float mx = val;
#pragma unroll
            for (int m = 8; m >= 1; m >>= 1) mx = fmaxf(mx, __shfl_xor(mx, m, 16));
            float se = __expf(val - mx);
#pragma unroll
            for (int m = 8; m >= 1; m >>= 1) se += __shfl_xor(se, m, 16);
            float res = val - mx - __logf(se);
            if (lane < 16) outp[n * NCLASS + lane] = res;
        }
    }
}

// =====================================================================
// Fallback kernels (verbatim round-1, known-correct at 147 us)
// =====================================================================
__global__ void __launch_bounds__(256)
k_prep(const void* __restrict__ f, const void* __restrict__ Wh_,
       const void* __restrict__ ah_, const void* __restrict__ bh_,
       const void* __restrict__ Wo_, const void* __restrict__ ao_,
       const void* __restrict__ bo_, const int* __restrict__ e32,
       int E, int csb,
       unsigned short* __restrict__ featb,
       unsigned short* __restrict__ Wtb,
       float* __restrict__ smallf,
       unsigned int* __restrict__ bits) {
    __shared__ int sbf;
    int t = threadIdx.x;
    if (t < 64) {
        unsigned int w = ((const unsigned int*)f)[t];
        unsigned int lo = w & 0xffffu, e = (lo >> 7) & 0xffu;
        unsigned long long bal = __ballot(lo == 0u || (e >= 100u && e <= 140u));
        if (t == 0) sbf = (__popcll(bal) >= 40);
    }
    __syncthreads();
    bool bf = (sbf != 0);
    if (blockIdx.x < 128) {
        __shared__ float tile[64][33];
        int h = blockIdx.x >> 4, k0 = (blockIdx.x & 15) * 32;
        int n = t & 63, kh = t >> 6;
#pragma unroll
        for (int i = 0; i < 8; ++i) {
            int kk = kh * 8 + i;
            int si = (h << 15) + (k0 + kk) * NHID + n;
            float v = bf ? b2f(((const unsigned short*)Wh_)[si])
                         : ((const float*)Wh_)[si];
            tile[n][kk] = v;
        }
        __syncthreads();
        int n2 = t >> 2, kk0 = (t & 3) * 8;
        u16x8 o;
#pragma unroll
        for (int i = 0; i < 8; ++i) o[i] = f2b(tile[n2][kk0 + i]);
        *(u16x8*)&Wtb[(size_t)((h << 6) + n2) * NFEAT + k0 + kk0] = o;
    } else if ((int)blockIdx.x < 128 + csb) {
        __shared__ int s64f;
        if (t < 64) {
            unsigned long long bal = __ballot(e32[2 * t + 1] == 0);
            if (t == 0) s64f = (__popcll(bal) >= 48);
        }
        __syncthreads();
        int i = (blockIdx.x - 128) * 256 + t;
        if (i < E) {
            int s, tt;
            if (s64f) { s = e32[2 * i]; tt = e32[2 * (E + i)]; }
            else      { s = e32[i];     tt = e32[E + i]; }
            s &= (NN - 1); tt &= (NN - 1);
            unsigned int pos = (unsigned int)s * NN + (unsigned int)tt;
            atomicOr(&bits[pos >> 5], 1u << (pos & 31u));
        }
    } else {
        const int NF8 = NN * NFEAT / 8;
        int i = (blockIdx.x - 128 - csb) * 256 + t;
        int stride = (gridDim.x - 128 - csb) * 256;
        const int TOT = NF8 + NSMALL;
        for (; i < TOT; i += stride) {
            if (i < NF8) {
                if (bf) {
                    *(u16x8*)&featb[i * 8] = ((const u16x8*)f)[i];
                } else {
                    float4 lo = ((const float4*)f)[i * 2];
                    float4 hi = ((const float4*)f)[i * 2 + 1];
                    u16x8 o;
                    o[0] = f2b(lo.x); o[1] = f2b(lo.y); o[2] = f2b(lo.z); o[3] = f2b(lo.w);
                    o[4] = f2b(hi.x); o[5] = f2b(hi.y); o[6] = f2b(hi.z); o[7] = f2b(hi.w);
                    *(u16x8*)&featb[i * 8] = o;
                }
            } else {
                int r = i - NF8;
                const void* sp; int off;
                if (r < SZ2)                        { sp = ah_; off = r; }
                else if (r < SZ2 + SZ3)             { sp = bh_; off = r - SZ2; }
                else if (r < SZ2 + SZ3 + SZ4)       { sp = Wo_; off = r - SZ2 - SZ3; }
                else if (r < SZ2 + SZ3 + SZ4 + SZ5) { sp = ao_; off = r - SZ2 - SZ3 - SZ4; }
                else                                { sp = bo_; off = r - SZ2 - SZ3 - SZ4 - SZ5; }
                smallf[r] = bf ? b2f(((const unsigned short*)sp)[off])
                               : ((const float*)sp)[off];
            }
        }
    }
}

__global__ void __launch_bounds__(256)
k_gemm_ext(const unsigned short* __restrict__ Ab,
           const unsigned short* __restrict__ Wtb,
           const float* __restrict__ ah,
           unsigned short* __restrict__ Hb,
           float* __restrict__ s1, float* __restrict__ s2,
           float* __restrict__ cm1,
           const unsigned int* __restrict__ bits,
           int* __restrict__ deg, int* __restrict__ csr) {
    int t = threadIdx.x;
    if (blockIdx.x >= 256) {
        int wid = t >> 6, lane = t & 63;
        int n = (blockIdx.x - 256) * 4 + wid;
        uint2 w = *(const uint2*)&bits[n * 128 + lane * 2];
        int c = __popc(w.x) + __popc(w.y);
        int incl = c;
#pragma unroll
        for (int off = 1; off < 64; off <<= 1) {
            int u = __shfl_up(incl, off, 64);
            if (lane >= off) incl += u;
        }
        int excl = incl - c;
        int total = __shfl(incl, 63, 64);
        if (lane == 0) deg[n] = total;
        int base = n * CAP;
        int tbase = lane * 64;
        unsigned int x = w.x;
        while (x) {
            int b = __ffs(x) - 1; x &= x - 1;
            if (excl < CAP) csr[base + excl] = tbase + b;
            ++excl;
        }
        unsigned int y = w.y;
        while (y) {
            int b = __ffs(y) - 1; y &= y - 1;
            if (excl < CAP) csr[base + excl] = tbase + 32 + b;
            ++excl;
        }
        return;
    }
    __shared__ float cms[64];
    if (t < 64) cms[t] = 0.f;
    __syncthreads();
    int w = t >> 6, l = t & 63;
    int quad = l >> 4, l16 = l & 15;
    int h = blockIdx.x >> 5;
    int m0 = (blockIdx.x & 31) * 128 + w * 32;
    f32x4 acc[2][4] = {};
    const unsigned short* a0p = Ab + (size_t)(m0 + l16) * NFEAT + quad * 8;
    const unsigned short* a1p = a0p + 16 * NFEAT;
    const unsigned short* bp  = Wtb + ((size_t)h << 15) + (size_t)l16 * NFEAT + quad * 8;
#pragma unroll 4
    for (int k0 = 0; k0 < NFEAT; k0 += 32) {
        bf16x8 a0 = *(const bf16x8*)(a0p + k0);
        bf16x8 a1 = *(const bf16x8*)(a1p + k0);
#pragma unroll
        for (int nt = 0; nt < 4; ++nt) {
            bf16x8 b = *(const bf16x8*)(bp + (size_t)nt * 16 * NFEAT + k0);
            acc[0][nt] = __builtin_amdgcn_mfma_f32_16x16x32_bf16(a0, b, acc[0][nt], 0, 0, 0);
            acc[1][nt] = __builtin_amdgcn_mfma_f32_16x16x32_bf16(a1, b, acc[1][nt], 0, 0, 0);
        }
    }
    const float* av = ah + h * 2 * NHID;
    float p1[2][4] = {}, p2[2][4] = {};
#pragma unroll
    for (int rh = 0; rh < 2; ++rh) {
#pragma unroll
        for (int nt = 0; nt < 4; ++nt) {
            int col = nt * 16 + l16;
            float av1 = av[col], av2 = av[NHID + col];
            float csum = 0.f;
#pragma unroll
            for (int r = 0; r < 4; ++r) {
                float v = acc[rh][nt][r];
                int row = m0 + rh * 16 + quad * 4 + r;
                Hb[((size_t)row << 9) + (h << 6) + col] = f2b(v);
                p1[rh][r] += v * av1;
                p2[rh][r] += v * av2;
                csum += v;
            }
            atomicAdd(&cms[col], csum);
        }
    }
#pragma unroll
    for (int m = 8; m >= 1; m >>= 1)
#pragma unroll
        for (int rh = 0; rh < 2; ++rh)
#pragma unroll
            for (int r = 0; r < 4; ++r) {
                p1[rh][r] += __shfl_xor(p1[rh][r], m, 64);
                p2[rh][r] += __shfl_xor(p2[rh][r], m, 64);
            }
    if (l16 == 0) {
#pragma unroll
        for (int rh = 0; rh < 2; ++rh)
#pragma unroll
            for (int r = 0; r < 4; ++r) {
                int row = m0 + rh * 16 + quad * 4 + r;
                s1[(h << 12) + row] = p1[rh][r];
                s2[(h << 12) + row] = p2[rh][r];
            }
    }
    __syncthreads();
    if (t < 64) atomicAdd(&cm1[h * NHID + t], cms[t]);
}

__global__ void __launch_bounds__(256)
k_attn1f(const int* __restrict__ deg, const int* __restrict__ csr,
         const float* __restrict__ s1, const float* __restrict__ s2,
         const unsigned short* __restrict__ Hb,
         const float* __restrict__ bh, const float* __restrict__ cm1,
         const float* __restrict__ Wo, const float* __restrict__ ao,
         float* __restrict__ out2, float* __restrict__ s1o,
         float* __restrict__ s2o, float* __restrict__ cm2) {
    __shared__ float sW[4][CAP * 8];
    __shared__ int   sT[4][CAP];
    __shared__ float xr[4][NFEAT];
    __shared__ float cms[NCLASS];
    int t = threadIdx.x;
    if (t < NCLASS) cms[t] = 0.f;
    __syncthreads();
    int wid = t >> 6, lane = t & 63;
    int n = blockIdx.x * 4 + wid;
    int h = lane >> 3, jslot = lane & 7;
    int d = min(deg[n], CAP);
    float acc[8] = {};
    float rden = 1.f;
    if (d > 0) {
        const int* row = csr + (size_t)n * CAP;
        const float* s2h = s2 + ((size_t)h << 12);
        float s1n = s1[(h << 12) + n];
        float mx = -1e30f;
        for (int jb = 0; jb < d; jb += 8) {
            int j = jb + jslot;
            int tt = (j < d) ? row[j] : 0;
            float e = (j < d) ? lrelu(s1n + s2h[tt]) : -1e30f;
            sW[wid][(j << 3) + h] = e;
            if (h == 0) sT[wid][j] = tt;
            mx = fmaxf(mx, e);
        }
        mx = fmaxf(mx, __shfl_xor(mx, 1, 64));
        mx = fmaxf(mx, __shfl_xor(mx, 2, 64));
        mx = fmaxf(mx, __shfl_xor(mx, 4, 64));
        float den = 0.f;
        for (int jb = 0; jb < d; jb += 8) {
            int j = jb + jslot;
            float e = sW[wid][(j << 3) + h];
            float w = __expf(e - mx);
            sW[wid][(j << 3) + h] = w;
            den += w;
        }
        den += __shfl_xor(den, 1, 64);
        den += __shfl_xor(den, 2, 64);
        den += __shfl_xor(den, 4, 64);
        rden = 1.f / den;
        const unsigned short* Hp = Hb + lane * 8;
        int j = 0;
#pragma unroll 2
        for (; j + 2 <= d; j += 2) {
            int t0 = sT[wid][j], t1 = sT[wid][j + 1];
            float w0 = sW[wid][(j << 3) + h];
            float w1 = sW[wid][((j + 1) << 3) + h];
            u16x8 v0 = *(const u16x8*)(Hp + ((size_t)t0 << 9));
            u16x8 v1 = *(const u16x8*)(Hp + ((size_t)t1 << 9));
#pragma unroll
            for (int i = 0; i < 8; ++i)
                acc[i] += w0 * b2f(v0[i]) + w1 * b2f(v1[i]);
        }
        if (j < d) {
            int t0 = sT[wid][j];
            float w0 = sW[wid][(j << 3) + h];
            u16x8 v0 = *(const u16x8*)(Hp + ((size_t)t0 << 9));
#pragma unroll
            for (int i = 0; i < 8; ++i) acc[i] += w0 * b2f(v0[i]);
        }
    }
    float o[8];
    if (d == 0) {
#pragma unroll
        for (int i = 0; i < 8; ++i) o[i] = cm1[lane * 8 + i] * (1.0f / NN);
    } else {
#pragma unroll
        for (int i = 0; i < 8; ++i) o[i] = acc[i] * rden;
    }
#pragma unroll
    for (int i = 0; i < 8; ++i) {
        float v = o[i] + bh[lane * 8 + i];
        o[i] = v > 0.f ? v : __expf(v) - 1.f;
    }
    float* xw = xr[wid];
    *(float4*)&xw[lane * 8]     = make_float4(o[0], o[1], o[2], o[3]);
    *(float4*)&xw[lane * 8 + 4] = make_float4(o[4], o[5], o[6], o[7]);
    int c = lane & 15, sub = lane >> 4;
    const float* xp = xw + sub * 128;
    const float* wp = Wo + sub * 128 * NCLASS + c;
    float a2 = 0.f;
#pragma unroll 8
    for (int kk = 0; kk < 128; ++kk) a2 += xp[kk] * wp[kk * NCLASS];
    a2 += __shfl_xor(a2, 16, 64);
    a2 += __shfl_xor(a2, 32, 64);
    if (lane < 16) out2[n * NCLASS + c] = a2;
    float r1 = a2 * ao[c], r2 = a2 * ao[NCLASS + c];
#pragma unroll
    for (int m = 8; m >= 1; m >>= 1) {
        r1 += __shfl_xor(r1, m, 16);
        r2 += __shfl_xor(r2, m, 16);
    }
    if (lane == 0) { s1o[n] = r1; s2o[n] = r2; }
    if (lane < 16) atomicAdd(&cms[c], a2);
    __syncthreads();
    if (t < NCLASS) atomicAdd(&cm2[t], cms[t]);
}

__global__ void __launch_bounds__(256)
k_attn2(const int* __restrict__ deg, const int* __restrict__ csr,
        const float* __restrict__ s1o, const float* __restrict__ s2o,
        const float* __restrict__ out2, const float* __restrict__ bo,
        const float* __restrict__ cm2, float* __restrict__ outp) {
    __shared__ float wv[4][CAP];
    __shared__ float o2s[4][16];
    int wid = threadIdx.x >> 6, lane = threadIdx.x & 63;
    int n = blockIdx.x * 4 + wid;
    int c = lane & 15;
    int d = min(deg[n], CAP);
    float val;
    if (d == 0) {
        val = cm2[c] * (1.0f / NN);
    } else {
        float s1n = s1o[n];
        const int* rowp = csr + (size_t)n * CAP;
        int t0 = (lane < d)       ? rowp[lane]       : 0;
        int t1 = (lane + 64 < d)  ? rowp[lane + 64]  : 0;
        int t2 = (lane + 128 < d) ? rowp[lane + 128] : 0;
        float e0 = (lane < d)       ? lrelu(s1n + s2o[t0]) : -1e30f;
        float e1 = (lane + 64 < d)  ? lrelu(s1n + s2o[t1]) : -1e30f;
        float e2 = (lane + 128 < d) ? lrelu(s1n + s2o[t2]) : -1e30f;
        float m = waveMax(fmaxf(e0, fmaxf(e1, e2)));
        float w0 = (lane < d)       ? __expf(e0 - m) : 0.f;
        float w1 = (lane + 64 < d)  ? __expf(e1 - m) : 0.f;
        float w2 = (lane + 128 < d) ? __expf(e2 - m) : 0.f;
        float den = waveSum(w0 + w1 + w2);
        wv[wid][lane]       = w0;
        wv[wid][lane + 64]  = w1;
        wv[wid][lane + 128] = w2;
        int g2 = lane >> 2, q = lane & 3;
        float a4[4] = {};
        for (int j = g2; j < d; j += 16) {
            float w = wv[wid][j];
            int tt = rowp[j];
            float4 v = *(const float4*)(out2 + tt * NCLASS + q * 4);
            a4[0] += w * v.x; a4[1] += w * v.y;
            a4[2] += w * v.z; a4[3] += w * v.w;
        }
#pragma unroll
        for (int m2 = 4; m2 <= 32; m2 <<= 1)
#pragma unroll
            for (int i = 0; i < 4; ++i) a4[i] += __shfl_xor(a4[i], m2, 64);
        if (lane < 4)
            *(float4*)&o2s[wid][lane * 4] = make_float4(a4[0], a4[1], a4[2], a4[3]);
        val = o2s[wid][c] / den;
    }
    val += bo[c];
    float mx = val;
#pragma unroll
    for (int m = 8; m >= 1; m >>= 1) mx = fmaxf(mx, __shfl_xor(mx, m, 16));
    float se = __expf(val - mx);
#pragma unroll
    for (int m = 8; m >= 1; m >>= 1) se += __shfl_xor(se, m, 16);
    float res = val - mx - __logf(se);
    if (lane < 16) outp[n * NCLASS + lane] = res;
}

extern "C" void kernel_launch(void* const* d_in, const int* in_sizes, int n_in,
                              void* d_out, int out_size, void* d_ws, size_t ws_size,
                              hipStream_t stream) {
    const void* features = d_in[0];
    const int*  edges    = (const int*)d_in[1];
    const void* W_heads  = d_in[2];
    const void* a_heads  = d_in[3];
    const void* b_heads  = d_in[4];
    const void* W_out    = d_in[5];
    const void* a_out    = d_in[6];
    const void* b_out    = d_in[7];
    int E = in_sizes[1] / 2;
    int csb = (E + 255) / 256;

    // ---- workspace layout (4B units); bits,deg,cm1,cm2,gb contiguous zero region ----
    unsigned int* bits = (unsigned int*)d_ws;                  // NN*NN/32
    int*   deg  = (int*)(bits + (NN * NN / 32));               // NN
    float* cm1  = (float*)(deg + NN);                          // NHEAD*NHID
    float* cm2  = cm1 + NHEAD * NHID;                          // NCLASS
    int*   gb   = (int*)(cm2 + NCLASS);                        // NGB (zero region ends)
    int*   csr  = gb + NGB;                                    // NN*CAP
    float* s1   = (float*)(csr + NN * CAP);                    // NHEAD*NN
    float* s2   = s1 + NHEAD * NN;                             // NHEAD*NN
    float* out2 = s2 + NHEAD * NN;                             // NN*NCLASS
    float* s1o  = out2 + NN * NCLASS;                          // NN
    float* s2o  = s1o + NN;                                    // NN
    float* smallf = s2o + NN;                                  // NSMALL fp32
    unsigned short* Hb    = (unsigned short*)(smallf + NSMALL);// NN*512 bf16 (node-major)
    unsigned short* featb = Hb + (size_t)NN * NHEAD * NHID;    // NN*NFEAT bf16
    unsigned short* Wtb   = featb + (size_t)NN * NFEAT;        // NHEAD*NHID*NFEAT bf16
    float* outp = (float*)d_out;

    // zero bits+deg+cm1+cm2+barrier state (2.1 MB)
    hipMemsetAsync(d_ws, 0, (size_t)NZERO * 4, stream);

    // ---- cooperative grid sizing (runtime validates co-residency) ----
    static int coop_blocks = -2;
    if (coop_blocks == -2) {
        int maxB = 0, ncu = 0, dev = 0;
        if (hipOccupancyMaxActiveBlocksPerMultiprocessor(
                &maxB, reinterpret_cast<const void*>(&k_fused), 256, 0) != hipSuccess)
            maxB = 0;
        (void)hipGetDevice(&dev);
        if (hipDeviceGetAttribute(&ncu, hipDeviceAttributeMultiprocessorCount, dev)
                != hipSuccess)
            ncu = 0;
        coop_blocks = (maxB > 0 && ncu > 0) ? maxB * ncu : 0;
    }
    int nblk = coop_blocks > 1024 ? 1024 : coop_blocks;

    bool done = false;
    if (nblk >= 64) {
        void* args[] = {
            (void*)&features, (void*)&W_heads, (void*)&a_heads, (void*)&b_heads,
            (void*)&W_out, (void*)&a_out, (void*)&b_out, (void*)&edges,
            (void*)&E, (void*)&csb,
            (void*)&featb, (void*)&Wtb, (void*)&smallf, (void*)&bits,
            (void*)&deg, (void*)&csr, (void*)&cm1, (void*)&cm2,
            (void*)&s1, (void*)&s2, (void*)&out2, (void*)&s1o, (void*)&s2o,
            (void*)&Hb, (void*)&outp, (void*)&gb
        };
        hipError_t err = hipLaunchCooperativeKernel((const void*)k_fused,
                                                    dim3(nblk), dim3(256),
                                                    args, 0, stream);
        if (err == hipSuccess) done = true;
        else (void)hipGetLastError();   // clear sticky error, use fallback
    }
    if (!done) {
        hipLaunchKernelGGL(k_prep, dim3(128 + csb + 896), dim3(256), 0, stream,
                           features, W_heads, a_heads, b_heads, W_out, a_out, b_out,
                           edges, E, csb, featb, Wtb, smallf, bits);
        hipLaunchKernelGGL(k_gemm_ext, dim3(256 + NN / 4), dim3(256), 0, stream,
                           featb, Wtb, smallf, Hb, s1, s2, cm1, bits, deg, csr);
        hipLaunchKernelGGL(k_attn1f, dim3(NN / 4), dim3(256), 0, stream,
                           deg, csr, s1, s2, Hb, smallf + SZ2, cm1,
                           smallf + SZ2 + SZ3, smallf + SZ2 + SZ3 + SZ4,
                           out2, s1o, s2o, cm2);
        hipLaunchKernelGGL(k_attn2, dim3(NN / 4), dim3(256), 0, stream,
                           deg, csr, s1o, s2o, out2,
                           smallf + SZ2 + SZ3 + SZ4 + SZ5, cm2, outp);
    }
}

// Round 6
// 194.724 us; speedup vs baseline: 2.7360x; 1.1434x over previous
//
#include <hip/hip_runtime.h>
#include <hip/hip_bf16.h>

#define NN 4096
#define NFEAT 512
#define NHID 64
#define NHEAD 8
#define NCLASS 16
#define CAP 192
#define LALPHA 0.2f

#define SZ2 (NHEAD*2*NHID)   // a_heads
#define SZ3 (NHEAD*NHID)     // b_heads
#define SZ4 (NFEAT*NCLASS)   // W_out
#define SZ5 (2*NCLASS)       // a_out
#define SZ6 (NCLASS)         // b_out
#define NSMALL (SZ2+SZ3+SZ4+SZ5+SZ6)
#define NGB 1152             // 64 counters*16 + 8 flags*16
#define NZERO (NN*NN/32 + NN + NHEAD*NHID + NCLASS + NGB)   // bits+deg+cm1+cm2+gb

typedef __attribute__((ext_vector_type(8))) short bf16x8;
typedef __attribute__((ext_vector_type(4))) float f32x4;
typedef __attribute__((ext_vector_type(8))) unsigned short u16x8;

__device__ __forceinline__ float b2f(unsigned short h) {
    return __uint_as_float(((unsigned int)h) << 16);
}
__device__ __forceinline__ unsigned short f2b(float f) {
    unsigned int u = __float_as_uint(f);
    unsigned int r = (u + 0x7fffu + ((u >> 16) & 1u)) >> 16;
    return (unsigned short)r;
}
__device__ __forceinline__ float waveMax(float v) {
#pragma unroll
    for (int m = 32; m >= 1; m >>= 1) v = fmaxf(v, __shfl_xor(v, m, 64));
    return v;
}
__device__ __forceinline__ float waveSum(float v) {
#pragma unroll
    for (int m = 32; m >= 1; m >>= 1) v += __shfl_xor(v, m, 64);
    return v;
}
__device__ __forceinline__ float lrelu(float e) {
    return e >= 0.f ? e : LALPHA * e;
}

#if defined(__has_builtin)
#if __has_builtin(__builtin_amdgcn_fence)
#define GAT_HAS_FENCE 1
#endif
#endif
#ifdef GAT_HAS_FENCE
#define REL_FENCE() __builtin_amdgcn_fence(__ATOMIC_RELEASE, "agent")
#define ACQ_FENCE() __builtin_amdgcn_fence(__ATOMIC_ACQUIRE, "agent")
#else
#define REL_FENCE() __threadfence()
#define ACQ_FENCE() __threadfence()
#endif

// Sharded grid barrier (round-5's relaxed protocol + contention fixes):
//  - arrivals: relaxed fetch_add on gb[(bid&63)*16]  -> <=16 RMWs per line
//  - block 0 wave 0: one counter per lane, wave-reduce, wait sum==nblk*epoch
//  - release: 8 replicated flag lines gb[1024+(i<<4)]; waiter polls bid&7
//  - exactly one REL (wbl2) before arrival, one ACQ (inv) after release.
// Counters/flags are epoch-cumulative -> no re-zero between barriers.
__device__ __forceinline__ void gbar(int* gb, int epoch, int nblk) {
    __syncthreads();
    int t = threadIdx.x, bid = blockIdx.x;
    if (t == 0) {
        REL_FENCE();
        __hip_atomic_fetch_add(gb + ((bid & 63) << 4), 1, __ATOMIC_RELAXED,
                               __HIP_MEMORY_SCOPE_AGENT);
    }
    if (bid == 0) {
        if (t < 64) {
            int target = nblk * epoch;
            for (;;) {
                int v = __hip_atomic_load(gb + (t << 4), __ATOMIC_RELAXED,
                                          __HIP_MEMORY_SCOPE_AGENT);
#pragma unroll
                for (int m = 32; m >= 1; m >>= 1) v += __shfl_xor(v, m, 64);
                if (v >= target) break;
                __builtin_amdgcn_s_sleep(2);
            }
            if (t < 8)
                __hip_atomic_store(gb + 1024 + (t << 4), epoch, __ATOMIC_RELAXED,
                                   __HIP_MEMORY_SCOPE_AGENT);
            if (t == 0) ACQ_FENCE();
        }
    } else if (t == 0) {
        int* flag = gb + 1024 + ((bid & 7) << 4);
        while (__hip_atomic_load(flag, __ATOMIC_RELAXED,
                                 __HIP_MEMORY_SCOPE_AGENT) < epoch)
            __builtin_amdgcn_s_sleep(16);
        ACQ_FENCE();
    }
    __syncthreads();
}

// =====================================================================
// Fused kernel (phase code verbatim from the thrice-verified version;
// only barrier protocol + P2 prefetch depth changed).
// =====================================================================
__global__ void __launch_bounds__(256, 4)
k_fused(const void* __restrict__ f, const void* __restrict__ Wh_,
        const void* __restrict__ ah_, const void* __restrict__ bh_,
        const void* __restrict__ Wo_, const void* __restrict__ ao_,
        const void* __restrict__ bo_, const int* __restrict__ e32,
        int E, int csb,
        unsigned short* __restrict__ featb, unsigned short* __restrict__ Wtb,
        float* __restrict__ smallf, unsigned int* __restrict__ bits,
        int* __restrict__ deg, int* __restrict__ csr,
        float* __restrict__ cm1, float* __restrict__ cm2,
        float* __restrict__ s1, float* __restrict__ s2,
        float* __restrict__ out2, float* __restrict__ s1o, float* __restrict__ s2o,
        unsigned short* __restrict__ Hb, float* __restrict__ outp,
        int* __restrict__ gb)
{
    __shared__ __align__(16) char Bc[27712];
    __shared__ int sbf, s64f;
    int t = threadIdx.x, bid = blockIdx.x, nblk = gridDim.x;
    int wid = t >> 6, lane = t & 63;

    // dtype detection (block-local, no sync needed)
    if (t < 64) {
        unsigned int w = ((const unsigned int*)f)[t];
        unsigned int lo = w & 0xffffu, e = (lo >> 7) & 0xffu;
        unsigned long long bal = __ballot(lo == 0u || (e >= 100u && e <= 140u));
        if (t == 0) sbf = (__popcll(bal) >= 40);
        unsigned long long bal2 = __ballot(e32[2 * t + 1] == 0);
        if (t == 0) s64f = (__popcll(bal2) >= 48);
    }
    __syncthreads();
    bool bf = (sbf != 0);

    // ---- P0: prep (W transpose | edge bitmap | feature/small cast) ----
    int NVB0 = 128 + csb + 896;
    for (int vb = bid; vb < NVB0; vb += nblk) {
        if (vb < 128) {
            float (*tile)[33] = (float(*)[33])Bc;
            int h = vb >> 4, k0 = (vb & 15) * 32;
            int nn = t & 63, kh = t >> 6;
#pragma unroll
            for (int i = 0; i < 8; ++i) {
                int kk = kh * 8 + i;
                int si = (h << 15) + (k0 + kk) * NHID + nn;
                float v = bf ? b2f(((const unsigned short*)Wh_)[si])
                             : ((const float*)Wh_)[si];
                tile[nn][kk] = v;
            }
            __syncthreads();
            int n2 = t >> 2, kk0 = (t & 3) * 8;
            u16x8 o;
#pragma unroll
            for (int i = 0; i < 8; ++i) o[i] = f2b(tile[n2][kk0 + i]);
            *(u16x8*)&Wtb[(size_t)((h << 6) + n2) * NFEAT + k0 + kk0] = o;
            __syncthreads();
        } else if (vb < 128 + csb) {
            int i = (vb - 128) * 256 + t;
            if (i < E) {
                int s, tt;
                if (s64f) { s = e32[2 * i]; tt = e32[2 * (E + i)]; }
                else      { s = e32[i];     tt = e32[E + i]; }
                s &= (NN - 1); tt &= (NN - 1);
                unsigned int pos = (unsigned int)s * NN + (unsigned int)tt;
                atomicOr(&bits[pos >> 5], 1u << (pos & 31u));
            }
        } else {
            const int NF8 = NN * NFEAT / 8;
            const int TOT = NF8 + NSMALL;
            for (int i = (vb - 128 - csb) * 256 + t; i < TOT; i += 896 * 256) {
                if (i < NF8) {
                    if (bf) {
                        *(u16x8*)&featb[i * 8] = ((const u16x8*)f)[i];
                    } else {
                        float4 lo = ((const float4*)f)[i * 2];
                        float4 hi = ((const float4*)f)[i * 2 + 1];
                        u16x8 o;
                        o[0] = f2b(lo.x); o[1] = f2b(lo.y); o[2] = f2b(lo.z); o[3] = f2b(lo.w);
                        o[4] = f2b(hi.x); o[5] = f2b(hi.y); o[6] = f2b(hi.z); o[7] = f2b(hi.w);
                        *(u16x8*)&featb[i * 8] = o;
                    }
                } else {
                    int r = i - NF8;
                    const void* sp; int off;
                    if (r < SZ2)                        { sp = ah_; off = r; }
                    else if (r < SZ2 + SZ3)             { sp = bh_; off = r - SZ2; }
                    else if (r < SZ2 + SZ3 + SZ4)       { sp = Wo_; off = r - SZ2 - SZ3; }
                    else if (r < SZ2 + SZ3 + SZ4 + SZ5) { sp = ao_; off = r - SZ2 - SZ3 - SZ4; }
                    else                                { sp = bo_; off = r - SZ2 - SZ3 - SZ4 - SZ5; }
                    smallf[r] = bf ? b2f(((const unsigned short*)sp)[off])
                                   : ((const float*)sp)[off];
                }
            }
        }
    }
    gbar(gb, 1, nblk);

    // ---- P1: extract (bitmap -> global csr/deg) + gemm1 ----
    for (int vb = bid; vb < 1024; vb += nblk) {
        {   // extract: registers/shuffles only, no LDS
            int n = vb * 4 + wid;
            uint2 w2 = *(const uint2*)&bits[n * 128 + lane * 2];
            int c = __popc(w2.x) + __popc(w2.y);
            int incl = c;
#pragma unroll
            for (int off = 1; off < 64; off <<= 1) {
                int u = __shfl_up(incl, off, 64);
                if (lane >= off) incl += u;
            }
            int excl = incl - c;
            int total = __shfl(incl, 63, 64);
            if (lane == 0) deg[n] = total;
            int base = n * CAP;
            int tbase = lane * 64;
            unsigned int x = w2.x;
            while (x) {
                int b = __ffs(x) - 1; x &= x - 1;
                if (excl < CAP) csr[base + excl] = tbase + b;
                ++excl;
            }
            unsigned int y = w2.y;
            while (y) {
                int b = __ffs(y) - 1; y &= y - 1;
                if (excl < CAP) csr[base + excl] = tbase + 32 + b;
                ++excl;
            }
        }
        {   // gemm1 tile: h = vb>>7, rows m0..m0+31, wave owns 16 cols
            float* sp1   = (float*)Bc;        // [32]
            float* sp2   = sp1 + 32;          // [32]
            float* cms64 = sp2 + 32;          // [64]
            if (t < 32) sp1[t] = 0.f;
            else if (t < 64) sp2[t - 32] = 0.f;
            __syncthreads();
            int h = vb >> 7, m0 = (vb & 127) << 5;
            int quad = lane >> 4, l16 = lane & 15;
            f32x4 acc0 = {}, acc1 = {};
            const unsigned short* a0p = featb + (size_t)(m0 + l16) * NFEAT + quad * 8;
            const unsigned short* a1p = a0p + 16 * NFEAT;
            const unsigned short* bp  = Wtb + ((size_t)h << 15) + (size_t)(wid * 16 + l16) * NFEAT + quad * 8;
#pragma unroll 4
            for (int k0 = 0; k0 < NFEAT; k0 += 32) {
                bf16x8 a0 = *(const bf16x8*)(a0p + k0);
                bf16x8 a1 = *(const bf16x8*)(a1p + k0);
                bf16x8 b  = *(const bf16x8*)(bp + k0);
                acc0 = __builtin_amdgcn_mfma_f32_16x16x32_bf16(a0, b, acc0, 0, 0, 0);
                acc1 = __builtin_amdgcn_mfma_f32_16x16x32_bf16(a1, b, acc1, 0, 0, 0);
            }
            const float* av = smallf + h * 2 * NHID;
            int col = wid * 16 + l16;
            float av1 = av[col], av2 = av[NHID + col];
            float p1v[2][4], p2v[2][4];
            float csum = 0.f;
#pragma unroll
            for (int rh = 0; rh < 2; ++rh)
#pragma unroll
                for (int r = 0; r < 4; ++r) {
                    float v = rh ? acc1[r] : acc0[r];
                    int row = m0 + rh * 16 + quad * 4 + r;
                    Hb[((size_t)row << 9) + (h << 6) + col] = f2b(v);
                    p1v[rh][r] = v * av1;
                    p2v[rh][r] = v * av2;
                    csum += v;
                }
#pragma unroll
            for (int m = 8; m >= 1; m >>= 1)
#pragma unroll
                for (int rh = 0; rh < 2; ++rh)
#pragma unroll
                    for (int r = 0; r < 4; ++r) {
                        p1v[rh][r] += __shfl_xor(p1v[rh][r], m, 64);
                        p2v[rh][r] += __shfl_xor(p2v[rh][r], m, 64);
                    }
            if (l16 == 0) {
#pragma unroll
                for (int rh = 0; rh < 2; ++rh)
#pragma unroll
                    for (int r = 0; r < 4; ++r) {
                        atomicAdd(&sp1[rh * 16 + quad * 4 + r], p1v[rh][r]);
                        atomicAdd(&sp2[rh * 16 + quad * 4 + r], p2v[rh][r]);
                    }
            }
            csum += __shfl_xor(csum, 16, 64);
            csum += __shfl_xor(csum, 32, 64);
            if (lane < 16) cms64[wid * 16 + lane] = csum;
            __syncthreads();
            if (t < 32) {
                s1[(h << 12) + m0 + t] = sp1[t];
                s2[(h << 12) + m0 + t] = sp2[t];
            }
            if (t < 64) atomicAdd(&cm1[h * NHID + t], cms64[t]);
        }
    }
    gbar(gb, 2, nblk);

    // ---- P2: attn1 (all heads per wave) + bias + ELU + fused gemm2/scores2 ----
    {
        float* sW   = (float*)Bc;               // [4][CAP*8], reused as X row
        int*   sTl  = (int*)(Bc + 24576);       // [4][CAP]
        float* cmsL = (float*)(Bc + 27648);     // [16]
        if (t < NCLASS) cmsL[t] = 0.f;
        __syncthreads();
        const float* bhf = smallf + SZ2;
        const float* Wof = smallf + SZ2 + SZ3;
        const float* aof = Wof + SZ4;
        for (int vb = bid; vb < 1024; vb += nblk) {
            int n = vb * 4 + wid;
            int h = lane >> 3, jslot = lane & 7;
            int d = min(deg[n], CAP);
            float* sWw = sW + wid * (CAP * 8);
            int*   sTw = sTl + wid * CAP;
            const int* row = csr + (size_t)n * CAP;
            float acc[8] = {};
            float rden = 1.f;
            if (d > 0) {
                const float* s2h = s2 + ((size_t)h << 12);
                float s1n = s1[(h << 12) + n];
                float mx = -1e30f;
                for (int jb = 0; jb < d; jb += 8) {
                    int j = jb + jslot;
                    int tt = (j < d) ? row[j] : 0;
                    float e = (j < d) ? lrelu(s1n + s2h[tt]) : -1e30f;
                    sWw[(j << 3) + h] = e;
                    if (h == 0) sTw[j] = tt;
                    mx = fmaxf(mx, e);
                }
                mx = fmaxf(mx, __shfl_xor(mx, 1, 64));
                mx = fmaxf(mx, __shfl_xor(mx, 2, 64));
                mx = fmaxf(mx, __shfl_xor(mx, 4, 64));
                float den = 0.f;
                for (int jb = 0; jb < d; jb += 8) {
                    int j = jb + jslot;
                    float e = sWw[(j << 3) + h];
                    float w = __expf(e - mx);
                    sWw[(j << 3) + h] = w;
                    den += w;
                }
                den += __shfl_xor(den, 1, 64);
                den += __shfl_xor(den, 2, 64);
                den += __shfl_xor(den, 4, 64);
                rden = 1.f / den;
                const unsigned short* Hp = Hb + lane * 8;
                int j = 0;
                for (; j + 4 <= d; j += 4) {      // 4 loads in flight
                    int t0 = sTw[j],     t1 = sTw[j + 1];
                    int t2 = sTw[j + 2], t3 = sTw[j + 3];
                    float w0 = sWw[(j << 3) + h];
                    float w1 = sWw[((j + 1) << 3) + h];
                    float w2 = sWw[((j + 2) << 3) + h];
                    float w3 = sWw[((j + 3) << 3) + h];
                    u16x8 v0 = *(const u16x8*)(Hp + ((size_t)t0 << 9));
                    u16x8 v1 = *(const u16x8*)(Hp + ((size_t)t1 << 9));
                    u16x8 v2 = *(const u16x8*)(Hp + ((size_t)t2 << 9));
                    u16x8 v3 = *(const u16x8*)(Hp + ((size_t)t3 << 9));
#pragma unroll
                    for (int i = 0; i < 8; ++i)
                        acc[i] += w0 * b2f(v0[i]) + w1 * b2f(v1[i])
                                + w2 * b2f(v2[i]) + w3 * b2f(v3[i]);
                }
                for (; j < d; ++j) {
                    int t0 = sTw[j];
                    float w0 = sWw[(j << 3) + h];
                    u16x8 v0 = *(const u16x8*)(Hp + ((size_t)t0 << 9));
#pragma unroll
                    for (int i = 0; i < 8; ++i) acc[i] += w0 * b2f(v0[i]);
                }
            }
            float o[8];
            if (d == 0) {
#pragma unroll
                for (int i = 0; i < 8; ++i) o[i] = cm1[lane * 8 + i] * (1.0f / NN);
            } else {
#pragma unroll
                for (int i = 0; i < 8; ++i) o[i] = acc[i] * rden;
            }
#pragma unroll
            for (int i = 0; i < 8; ++i) {
                float v = o[i] + bhf[lane * 8 + i];
                o[i] = v > 0.f ? v : __expf(v) - 1.f;     // ELU
            }
            float* xw = sWw;
            *(float4*)&xw[lane * 8]     = make_float4(o[0], o[1], o[2], o[3]);
            *(float4*)&xw[lane * 8 + 4] = make_float4(o[4], o[5], o[6], o[7]);
            int c = lane & 15, sub = lane >> 4;
            const float* xp = xw + sub * 128;
            const float* wp = Wof + sub * 128 * NCLASS + c;
            float a2 = 0.f;
#pragma unroll 8
            for (int kk = 0; kk < 128; ++kk) a2 += xp[kk] * wp[kk * NCLASS];
            a2 += __shfl_xor(a2, 16, 64);
            a2 += __shfl_xor(a2, 32, 64);
            if (lane < 16) out2[n * NCLASS + c] = a2;
            float r1 = a2 * aof[c], r2 = a2 * aof[NCLASS + c];
#pragma unroll
            for (int m = 8; m >= 1; m >>= 1) {
                r1 += __shfl_xor(r1, m, 16);
                r2 += __shfl_xor(r2, m, 16);
            }
            if (lane == 0) { s1o[n] = r1; s2o[n] = r2; }
            if (lane < 16) atomicAdd(&cmsL[c], a2);
        }
        __syncthreads();
        if (t < NCLASS) atomicAdd(&cm2[t], cmsL[t]);
    }
    gbar(gb, 3, nblk);

    // ---- P3: attn2 + bias + log_softmax ----
    {
        float* wv  = (float*)Bc;            // [4][CAP]
        float* o2s = (float*)(Bc + 3072);   // [4][16]
        const float* bof = smallf + SZ2 + SZ3 + SZ4 + SZ5;
        for (int vb = bid; vb < 1024; vb += nblk) {
            int n = vb * 4 + wid;
            int c = lane & 15;
            int d = min(deg[n], CAP);
            float val;
            if (d == 0) {
                val = cm2[c] * (1.0f / NN);
            } else {
                float s1n = s1o[n];
                const int* rowp = csr + (size_t)n * CAP;
                float* wvw = wv + wid * CAP;
                int t0 = (lane < d)       ? rowp[lane]       : 0;
                int t1 = (lane + 64 < d)  ? rowp[lane + 64]  : 0;
                int t2 = (lane + 128 < d) ? rowp[lane + 128] : 0;
                float e0 = (lane < d)       ? lrelu(s1n + s2o[t0]) : -1e30f;
                float e1 = (lane + 64 < d)  ? lrelu(s1n + s2o[t1]) : -1e30f;
                float e2 = (lane + 128 < d) ? lrelu(s1n + s2o[t2]) : -1e30f;
                float m = waveMax(fmaxf(e0, fmaxf(e1, e2)));
                float w0 = (lane < d)       ? __expf(e0 - m) : 0.f;
                float w1 = (lane + 64 < d)  ? __expf(e1 - m) : 0.f;
                float w2 = (lane + 128 < d) ? __expf(e2 - m) : 0.f;
                float den = waveSum(w0 + w1 + w2);
                wvw[lane]       = w0;
                wvw[lane + 64]  = w1;
                wvw[lane + 128] = w2;
                int g2 = lane >> 2, q = lane & 3;
                float a4[4] = {};
                for (int j = g2; j < d; j += 16) {
                    float w = wvw[j];
                    int tt = rowp[j];
                    float4 v = *(const float4*)(out2 + tt * NCLASS + q * 4);
                    a4[0] += w * v.x; a4[1] += w * v.y;
                    a4[2] += w * v.z; a4[3] += w * v.w;
                }
#pragma unroll
                for (int m2 = 4; m2 <= 32; m2 <<= 1)
#pragma unroll
                    for (int i = 0; i < 4; ++i) a4[i] += __shfl_xor(a4[i], m2, 64);
                if (lane < 4)
                    *(float4*)&o2s[wid * 16 + lane * 4] = make_float4(a4[0], a4[1], a4[2], a4[3]);
                val = o2s[wid * 16 + c] / den;
            }
            val += bof[c];
            float mx = val;
#pragma unroll
            for (int m = 8; m >= 1; m >>= 1) mx = fmaxf(mx, __shfl_xor(mx, m, 16));
            float se = __expf(val - mx);
#pragma unroll
            for (int m = 8; m >= 1; m >>= 1) se += __shfl_xor(se, m, 16);
            float res = val - mx - __logf(se);
            if (lane < 16) outp[n * NCLASS + lane] = res;
        }
    }
}

// =====================================================================
// Fallback kernels (verbatim round-1, known-correct at 147 us)
// =====================================================================
__global__ void __launch_bounds__(256)
k_prep(const void* __restrict__ f, const void* __restrict__ Wh_,
       const void* __restrict__ ah_, const void* __restrict__ bh_,
       const void* __restrict__ Wo_, const void* __restrict__ ao_,
       const void* __restrict__ bo_, const int* __restrict__ e32,
       int E, int csb,
       unsigned short* __restrict__ featb,
       unsigned short* __restrict__ Wtb,
       float* __restrict__ smallf,
       unsigned int* __restrict__ bits) {
    __shared__ int sbf;
    int t = threadIdx.x;
    if (t < 64) {
        unsigned int w = ((const unsigned int*)f)[t];
        unsigned int lo = w & 0xffffu, e = (lo >> 7) & 0xffu;
        unsigned long long bal = __ballot(lo == 0u || (e >= 100u && e <= 140u));
        if (t == 0) sbf = (__popcll(bal) >= 40);
    }
    __syncthreads();
    bool bf = (sbf != 0);
    if (blockIdx.x < 128) {
        __shared__ float tile[64][33];
        int h = blockIdx.x >> 4, k0 = (blockIdx.x & 15) * 32;
        int n = t & 63, kh = t >> 6;
#pragma unroll
        for (int i = 0; i < 8; ++i) {
            int kk = kh * 8 + i;
            int si = (h << 15) + (k0 + kk) * NHID + n;
            float v = bf ? b2f(((const unsigned short*)Wh_)[si])
                         : ((const float*)Wh_)[si];
            tile[n][kk] = v;
        }
        __syncthreads();
        int n2 = t >> 2, kk0 = (t & 3) * 8;
        u16x8 o;
#pragma unroll
        for (int i = 0; i < 8; ++i) o[i] = f2b(tile[n2][kk0 + i]);
        *(u16x8*)&Wtb[(size_t)((h << 6) + n2) * NFEAT + k0 + kk0] = o;
    } else if ((int)blockIdx.x < 128 + csb) {
        __shared__ int s64f;
        if (t < 64) {
            unsigned long long bal = __ballot(e32[2 * t + 1] == 0);
            if (t == 0) s64f = (__popcll(bal) >= 48);
        }
        __syncthreads();
        int i = (blockIdx.x - 128) * 256 + t;
        if (i < E) {
            int s, tt;
            if (s64f) { s = e32[2 * i]; tt = e32[2 * (E + i)]; }
            else      { s = e32[i];     tt = e32[E + i]; }
            s &= (NN - 1); tt &= (NN - 1);
            unsigned int pos = (unsigned int)s * NN + (unsigned int)tt;
            atomicOr(&bits[pos >> 5], 1u << (pos & 31u));
        }
    } else {
        const int NF8 = NN * NFEAT / 8;
        int i = (blockIdx.x - 128 - csb) * 256 + t;
        int stride = (gridDim.x - 128 - csb) * 256;
        const int TOT = NF8 + NSMALL;
        for (; i < TOT; i += stride) {
            if (i < NF8) {
                if (bf) {
                    *(u16x8*)&featb[i * 8] = ((const u16x8*)f)[i];
                } else {
                    float4 lo = ((const float4*)f)[i * 2];
                    float4 hi = ((const float4*)f)[i * 2 + 1];
                    u16x8 o;
                    o[0] = f2b(lo.x); o[1] = f2b(lo.y); o[2] = f2b(lo.z); o[3] = f2b(lo.w);
                    o[4] = f2b(hi.x); o[5] = f2b(hi.y); o[6] = f2b(hi.z); o[7] = f2b(hi.w);
                    *(u16x8*)&featb[i * 8] = o;
                }
            } else {
                int r = i - NF8;
                const void* sp; int off;
                if (r < SZ2)                        { sp = ah_; off = r; }
                else if (r < SZ2 + SZ3)             { sp = bh_; off = r - SZ2; }
                else if (r < SZ2 + SZ3 + SZ4)       { sp = Wo_; off = r - SZ2 - SZ3; }
                else if (r < SZ2 + SZ3 + SZ4 + SZ5) { sp = ao_; off = r - SZ2 - SZ3 - SZ4; }
                else                                { sp = bo_; off = r - SZ2 - SZ3 - SZ4 - SZ5; }
                smallf[r] = bf ? b2f(((const unsigned short*)sp)[off])
                               : ((const float*)sp)[off];
            }
        }
    }
}

__global__ void __launch_bounds__(256)
k_gemm_ext(const unsigned short* __restrict__ Ab,
           const unsigned short* __restrict__ Wtb,
           const float* __restrict__ ah,
           unsigned short* __restrict__ Hb,
           float* __restrict__ s1, float* __restrict__ s2,
           float* __restrict__ cm1,
           const unsigned int* __restrict__ bits,
           int* __restrict__ deg, int* __restrict__ csr) {
    int t = threadIdx.x;
    if (blockIdx.x >= 256) {
        int wid = t >> 6, lane = t & 63;
        int n = (blockIdx.x - 256) * 4 + wid;
        uint2 w = *(const uint2*)&bits[n * 128 + lane * 2];
        int c = __popc(w.x) + __popc(w.y);
        int incl = c;
#pragma unroll
        for (int off = 1; off < 64; off <<= 1) {
            int u = __shfl_up(incl, off, 64);
            if (lane >= off) incl += u;
        }
        int excl = incl - c;
        int total = __shfl(incl, 63, 64);
        if (lane == 0) deg[n] = total;
        int base = n * CAP;
        int tbase = lane * 64;
        unsigned int x = w.x;
        while (x) {
            int b = __ffs(x) - 1; x &= x - 1;
            if (excl < CAP) csr[base + excl] = tbase + b;
            ++excl;
        }
        unsigned int y = w.y;
        while (y) {
            int b = __ffs(y) - 1; y &= y - 1;
            if (excl < CAP) csr[base + excl] = tbase + 32 + b;
            ++excl;
        }
        return;
    }
    __shared__ float cms[64];
    if (t < 64) cms[t] = 0.f;
    __syncthreads();
    int w = t >> 6, l = t & 63;
    int quad = l >> 4, l16 = l & 15;
    int h = blockIdx.x >> 5;
    int m0 = (blockIdx.x & 31) * 128 + w * 32;
    f32x4 acc[2][4] = {};
    const unsigned short* a0p = Ab + (size_t)(m0 + l16) * NFEAT + quad * 8;
    const unsigned short* a1p = a0p + 16 * NFEAT;
    const unsigned short* bp  = Wtb + ((size_t)h << 15) + (size_t)l16 * NFEAT + quad * 8;
#pragma unroll 4
    for (int k0 = 0; k0 < NFEAT; k0 += 32) {
        bf16x8 a0 = *(const bf16x8*)(a0p + k0);
        bf16x8 a1 = *(const bf16x8*)(a1p + k0);
#pragma unroll
        for (int nt = 0; nt < 4; ++nt) {
            bf16x8 b = *(const bf16x8*)(bp + (size_t)nt * 16 * NFEAT + k0);
            acc[0][nt] = __builtin_amdgcn_mfma_f32_16x16x32_bf16(a0, b, acc[0][nt], 0, 0, 0);
            acc[1][nt] = __builtin_amdgcn_mfma_f32_16x16x32_bf16(a1, b, acc[1][nt], 0, 0, 0);
        }
    }
    const float* av = ah + h * 2 * NHID;
    float p1[2][4] = {}, p2[2][4] = {};
#pragma unroll
    for (int rh = 0; rh < 2; ++rh) {
#pragma unroll
        for (int nt = 0; nt < 4; ++nt) {
            int col = nt * 16 + l16;
            float av1 = av[col], av2 = av[NHID + col];
            float csum = 0.f;
#pragma unroll
            for (int r = 0; r < 4; ++r) {
                float v = acc[rh][nt][r];
                int row = m0 + rh * 16 + quad * 4 + r;
                Hb[((size_t)row << 9) + (h << 6) + col] = f2b(v);
                p1[rh][r] += v * av1;
                p2[rh][r] += v * av2;
                csum += v;
            }
            atomicAdd(&cms[col], csum);
        }
    }
#pragma unroll
    for (int m = 8; m >= 1; m >>= 1)
#pragma unroll
        for (int rh = 0; rh < 2; ++rh)
#pragma unroll
            for (int r = 0; r < 4; ++r) {
                p1[rh][r] += __shfl_xor(p1[rh][r], m, 64);
                p2[rh][r] += __shfl_xor(p2[rh][r], m, 64);
            }
    if (l16 == 0) {
#pragma unroll
        for (int rh = 0; rh < 2; ++rh)
#pragma unroll
            for (int r = 0; r < 4; ++r) {
                int row = m0 + rh * 16 + quad * 4 + r;
                s1[(h << 12) + row] = p1[rh][r];
                s2[(h << 12) + row] = p2[rh][r];
            }
    }
    __syncthreads();
    if (t < 64) atomicAdd(&cm1[h * NHID + t], cms[t]);
}

__global__ void __launch_bounds__(256)
k_attn1f(const int* __restrict__ deg, const int* __restrict__ csr,
         const float* __restrict__ s1, const float* __restrict__ s2,
         const unsigned short* __restrict__ Hb,
         const float* __restrict__ bh, const float* __restrict__ cm1,
         const float* __restrict__ Wo, const float* __restrict__ ao,
         float* __restrict__ out2, float* __restrict__ s1o,
         float* __restrict__ s2o, float* __restrict__ cm2) {
    __shared__ float sW[4][CAP * 8];
    __shared__ int   sT[4][CAP];
    __shared__ float xr[4][NFEAT];
    __shared__ float cms[NCLASS];
    int t = threadIdx.x;
    if (t < NCLASS) cms[t] = 0.f;
    __syncthreads();
    int wid = t >> 6, lane = t & 63;
    int n = blockIdx.x * 4 + wid;
    int h = lane >> 3, jslot = lane & 7;
    int d = min(deg[n], CAP);
    float acc[8] = {};
    float rden = 1.f;
    if (d > 0) {
        const int* row = csr + (size_t)n * CAP;
        const float* s2h = s2 + ((size_t)h << 12);
        float s1n = s1[(h << 12) + n];
        float mx = -1e30f;
        for (int jb = 0; jb < d; jb += 8) {
            int j = jb + jslot;
            int tt = (j < d) ? row[j] : 0;
            float e = (j < d) ? lrelu(s1n + s2h[tt]) : -1e30f;
            sW[wid][(j << 3) + h] = e;
            if (h == 0) sT[wid][j] = tt;
            mx = fmaxf(mx, e);
        }
        mx = fmaxf(mx, __shfl_xor(mx, 1, 64));
        mx = fmaxf(mx, __shfl_xor(mx, 2, 64));
        mx = fmaxf(mx, __shfl_xor(mx, 4, 64));
        float den = 0.f;
        for (int jb = 0; jb < d; jb += 8) {
            int j = jb + jslot;
            float e = sW[wid][(j << 3) + h];
            float w = __expf(e - mx);
            sW[wid][(j << 3) + h] = w;
            den += w;
        }
        den += __shfl_xor(den, 1, 64);
        den += __shfl_xor(den, 2, 64);
        den += __shfl_xor(den, 4, 64);
        rden = 1.f / den;
        const unsigned short* Hp = Hb + lane * 8;
        int j = 0;
#pragma unroll 2
        for (; j + 2 <= d; j += 2) {
            int t0 = sT[wid][j], t1 = sT[wid][j + 1];
            float w0 = sW[wid][(j << 3) + h];
            float w1 = sW[wid][((j + 1) << 3) + h];
            u16x8 v0 = *(const u16x8*)(Hp + ((size_t)t0 << 9));
            u16x8 v1 = *(const u16x8*)(Hp + ((size_t)t1 << 9));
#pragma unroll
            for (int i = 0; i < 8; ++i)
                acc[i] += w0 * b2f(v0[i]) + w1 * b2f(v1[i]);
        }
        if (j < d) {
            int t0 = sT[wid][j];
            float w0 = sW[wid][(j << 3) + h];
            u16x8 v0 = *(const u16x8*)(Hp + ((size_t)t0 << 9));
#pragma unroll
            for (int i = 0; i < 8; ++i) acc[i] += w0 * b2f(v0[i]);
        }
    }
    float o[8];
    if (d == 0) {
#pragma unroll
        for (int i = 0; i < 8; ++i) o[i] = cm1[lane * 8 + i] * (1.0f / NN);
    } else {
#pragma unroll
        for (int i = 0; i < 8; ++i) o[i] = acc[i] * rden;
    }
#pragma unroll
    for (int i = 0; i < 8; ++i) {
        float v = o[i] + bh[lane * 8 + i];
        o[i] = v > 0.f ? v : __expf(v) - 1.f;
    }
    float* xw = xr[wid];
    *(float4*)&xw[lane * 8]     = make_float4(o[0], o[1], o[2], o[3]);
    *(float4*)&xw[lane * 8 + 4] = make_float4(o[4], o[5], o[6], o[7]);
    int c = lane & 15, sub = lane >> 4;
    const float* xp = xw + sub * 128;
    const float* wp = Wo + sub * 128 * NCLASS + c;
    float a2 = 0.f;
#pragma unroll 8
    for (int kk = 0; kk < 128; ++kk) a2 += xp[kk] * wp[kk * NCLASS];
    a2 += __shfl_xor(a2, 16, 64);
    a2 += __shfl_xor(a2, 32, 64);
    if (lane < 16) out2[n * NCLASS + c] = a2;
    float r1 = a2 * ao[c], r2 = a2 * ao[NCLASS + c];
#pragma unroll
    for (int m = 8; m >= 1; m >>= 1) {
        r1 += __shfl_xor(r1, m, 16);
        r2 += __shfl_xor(r2, m, 16);
    }
    if (lane == 0) { s1o[n] = r1; s2o[n] = r2; }
    if (lane < 16) atomicAdd(&cms[c], a2);
    __syncthreads();
    if (t < NCLASS) atomicAdd(&cm2[t], cms[t]);
}

__global__ void __launch_bounds__(256)
k_attn2(const int* __restrict__ deg, const int* __restrict__ csr,
        const float* __restrict__ s1o, const float* __restrict__ s2o,
        const float* __restrict__ out2, const float* __restrict__ bo,
        const float* __restrict__ cm2, float* __restrict__ outp) {
    __shared__ float wv[4][CAP];
    __shared__ float o2s[4][16];
    int wid = threadIdx.x >> 6, lane = threadIdx.x & 63;
    int n = blockIdx.x * 4 + wid;
    int c = lane & 15;
    int d = min(deg[n], CAP);
    float val;
    if (d == 0) {
        val = cm2[c] * (1.0f / NN);
    } else {
        float s1n = s1o[n];
        const int* rowp = csr + (size_t)n * CAP;
        int t0 = (lane < d)       ? rowp[lane]       : 0;
        int t1 = (lane + 64 < d)  ? rowp[lane + 64]  : 0;
        int t2 = (lane + 128 < d) ? rowp[lane + 128] : 0;
        float e0 = (lane < d)       ? lrelu(s1n + s2o[t0]) : -1e30f;
        float e1 = (lane + 64 < d)  ? lrelu(s1n + s2o[t1]) : -1e30f;
        float e2 = (lane + 128 < d) ? lrelu(s1n + s2o[t2]) : -1e30f;
        float m = waveMax(fmaxf(e0, fmaxf(e1, e2)));
        float w0 = (lane < d)       ? __expf(e0 - m) : 0.f;
        float w1 = (lane + 64 < d)  ? __expf(e1 - m) : 0.f;
        float w2 = (lane + 128 < d) ? __expf(e2 - m) : 0.f;
        float den = waveSum(w0 + w1 + w2);
        wv[wid][lane]       = w0;
        wv[wid][lane + 64]  = w1;
        wv[wid][lane + 128] = w2;
        int g2 = lane >> 2, q = lane & 3;
        float a4[4] = {};
        for (int j = g2; j < d; j += 16) {
            float w = wv[wid][j];
            int tt = rowp[j];
            float4 v = *(const float4*)(out2 + tt * NCLASS + q * 4);
            a4[0] += w * v.x; a4[1] += w * v.y;
            a4[2] += w * v.z; a4[3] += w * v.w;
        }
#pragma unroll
        for (int m2 = 4; m2 <= 32; m2 <<= 1)
#pragma unroll
            for (int i = 0; i < 4; ++i) a4[i] += __shfl_xor(a4[i], m2, 64);
        if (lane < 4)
            *(float4*)&o2s[wid][lane * 4] = make_float4(a4[0], a4[1], a4[2], a4[3]);
        val = o2s[wid][c] / den;
    }
    val += bo[c];
    float mx = val;
#pragma unroll
    for (int m = 8; m >= 1; m >>= 1) mx = fmaxf(mx, __shfl_xor(mx, m, 16));
    float se = __expf(val - mx);
#pragma unroll
    for (int m = 8; m >= 1; m >>= 1) se += __shfl_xor(se, m, 16);
    float res = val - mx - __logf(se);
    if (lane < 16) outp[n * NCLASS + lane] = res;
}

extern "C" void kernel_launch(void* const* d_in, const int* in_sizes, int n_in,
                              void* d_out, int out_size, void* d_ws, size_t ws_size,
                              hipStream_t stream) {
    const void* features = d_in[0];
    const int*  edges    = (const int*)d_in[1];
    const void* W_heads  = d_in[2];
    const void* a_heads  = d_in[3];
    const void* b_heads  = d_in[4];
    const void* W_out    = d_in[5];
    const void* a_out    = d_in[6];
    const void* b_out    = d_in[7];
    int E = in_sizes[1] / 2;
    int csb = (E + 255) / 256;

    // ---- workspace layout (4B units); bits,deg,cm1,cm2,gb contiguous zero region ----
    unsigned int* bits = (unsigned int*)d_ws;                  // NN*NN/32
    int*   deg  = (int*)(bits + (NN * NN / 32));               // NN
    float* cm1  = (float*)(deg + NN);                          // NHEAD*NHID
    float* cm2  = cm1 + NHEAD * NHID;                          // NCLASS
    int*   gb   = (int*)(cm2 + NCLASS);                        // NGB (zero region ends)
    int*   csr  = gb + NGB;                                    // NN*CAP
    float* s1   = (float*)(csr + NN * CAP);                    // NHEAD*NN
    float* s2   = s1 + NHEAD * NN;                             // NHEAD*NN
    float* out2 = s2 + NHEAD * NN;                             // NN*NCLASS
    float* s1o  = out2 + NN * NCLASS;                          // NN
    float* s2o  = s1o + NN;                                    // NN
    float* smallf = s2o + NN;                                  // NSMALL fp32
    unsigned short* Hb    = (unsigned short*)(smallf + NSMALL);// NN*512 bf16 (node-major)
    unsigned short* featb = Hb + (size_t)NN * NHEAD * NHID;    // NN*NFEAT bf16
    unsigned short* Wtb   = featb + (size_t)NN * NFEAT;        // NHEAD*NHID*NFEAT bf16
    float* outp = (float*)d_out;

    // zero bits+deg+cm1+cm2+barrier state (2.1 MB)
    hipMemsetAsync(d_ws, 0, (size_t)NZERO * 4, stream);

    // ---- co-residency capacity from the runtime's occupancy math ----
    // Regular launch is safe iff grid <= blocksPerCU * numCU (all blocks
    // resident before any barrier spin). LDS 28160B -> 5/CU -> 1280 >= 1024.
    static int coop_blocks = -2;
    if (coop_blocks == -2) {
        int maxB = 0, ncu = 0, dev = 0;
        if (hipOccupancyMaxActiveBlocksPerMultiprocessor(
                &maxB, reinterpret_cast<const void*>(&k_fused), 256, 0) != hipSuccess)
            maxB = 0;
        (void)hipGetDevice(&dev);
        if (hipDeviceGetAttribute(&ncu, hipDeviceAttributeMultiprocessorCount, dev)
                != hipSuccess)
            ncu = 0;
        coop_blocks = (maxB > 0 && ncu > 0) ? maxB * ncu : 0;
    }
    int nblk = coop_blocks > 1024 ? 1024 : coop_blocks;

    if (nblk >= 64) {
        hipLaunchKernelGGL(k_fused, dim3(nblk), dim3(256), 0, stream,
                           features, W_heads, a_heads, b_heads,
                           W_out, a_out, b_out, edges, E, csb,
                           featb, Wtb, smallf, bits, deg, csr, cm1, cm2,
                           s1, s2, out2, s1o, s2o, Hb, outp, gb);
    } else {
        hipLaunchKernelGGL(k_prep, dim3(128 + csb + 896), dim3(256), 0, stream,
                           features, W_heads, a_heads, b_heads, W_out, a_out, b_out,
                           edges, E, csb, featb, Wtb, smallf, bits);
        hipLaunchKernelGGL(k_gemm_ext, dim3(256 + NN / 4), dim3(256), 0, stream,
                           featb, Wtb, smallf, Hb, s1, s2, cm1, bits, deg, csr);
        hipLaunchKernelGGL(k_attn1f, dim3(NN / 4), dim3(256), 0, stream,
                           deg, csr, s1, s2, Hb, smallf + SZ2, cm1,
                           smallf + SZ2 + SZ3, smallf + SZ2 + SZ3 + SZ4,
                           out2, s1o, s2o, cm2);
        hipLaunchKernelGGL(k_attn2, dim3(NN / 4), dim3(256), 0, stream,
                           deg, csr, s1o, s2o, out2,
                           smallf + SZ2 + SZ3 + SZ4 + SZ5, cm2, outp);
    }
}

// Round 7
// 155.470 us; speedup vs baseline: 3.4268x; 1.2525x over previous
//
#include <hip/hip_runtime.h>
#include <hip/hip_bf16.h>

#define NN 4096
#define NFEAT 512
#define NHID 64
#define NHEAD 8
#define NCLASS 16
#define CAP 192
#define LALPHA 0.2f

#define SZ2 (NHEAD*2*NHID)   // a_heads
#define SZ3 (NHEAD*NHID)     // b_heads
#define SZ4 (NFEAT*NCLASS)   // W_out
#define SZ5 (2*NCLASS)       // a_out
#define SZ6 (NCLASS)         // b_out
#define NSMALL (SZ2+SZ3+SZ4+SZ5+SZ6)
#define NZERO (NN*NN/32 + NN + NHEAD*NHID + NCLASS)   // bits+deg+cm1+cm2

typedef __attribute__((ext_vector_type(8))) short bf16x8;
typedef __attribute__((ext_vector_type(4))) float f32x4;
typedef __attribute__((ext_vector_type(8))) unsigned short u16x8;

__device__ __forceinline__ float b2f(unsigned short h) {
    return __uint_as_float(((unsigned int)h) << 16);
}
__device__ __forceinline__ unsigned short f2b(float f) {
    unsigned int u = __float_as_uint(f);
    unsigned int r = (u + 0x7fffu + ((u >> 16) & 1u)) >> 16;
    return (unsigned short)r;
}
__device__ __forceinline__ float waveMax(float v) {
#pragma unroll
    for (int m = 32; m >= 1; m >>= 1) v = fmaxf(v, __shfl_xor(v, m, 64));
    return v;
}
__device__ __forceinline__ float waveSum(float v) {
#pragma unroll
    for (int m = 32; m >= 1; m >>= 1) v += __shfl_xor(v, m, 64);
    return v;
}
__device__ __forceinline__ float lrelu(float e) {
    return e >= 0.f ? e : LALPHA * e;
}

// ---------- prep: W-transpose + edge-bitmap OR + feature/small casts ----------
__global__ void __launch_bounds__(256)
k_prep(const void* __restrict__ f, const void* __restrict__ Wh_,
       const void* __restrict__ ah_, const void* __restrict__ bh_,
       const void* __restrict__ Wo_, const void* __restrict__ ao_,
       const void* __restrict__ bo_, const int* __restrict__ e32,
       int E, int csb,
       unsigned short* __restrict__ featb,
       unsigned short* __restrict__ Wtb,
       float* __restrict__ smallf,
       unsigned int* __restrict__ bits) {
    __shared__ int sbf;
    int t = threadIdx.x;
    if (t < 64) {
        unsigned int w = ((const unsigned int*)f)[t];
        unsigned int lo = w & 0xffffu, e = (lo >> 7) & 0xffu;
        unsigned long long bal = __ballot(lo == 0u || (e >= 100u && e <= 140u));
        if (t == 0) sbf = (__popcll(bal) >= 40);
    }
    __syncthreads();
    bool bf = (sbf != 0);
    if (blockIdx.x < 128) {
        __shared__ float tile[64][33];
        int h = blockIdx.x >> 4, k0 = (blockIdx.x & 15) * 32;
        int n = t & 63, kh = t >> 6;
#pragma unroll
        for (int i = 0; i < 8; ++i) {
            int kk = kh * 8 + i;
            int si = (h << 15) + (k0 + kk) * NHID + n;
            float v = bf ? b2f(((const unsigned short*)Wh_)[si])
                         : ((const float*)Wh_)[si];
            tile[n][kk] = v;
        }
        __syncthreads();
        int n2 = t >> 2, kk0 = (t & 3) * 8;
        u16x8 o;
#pragma unroll
        for (int i = 0; i < 8; ++i) o[i] = f2b(tile[n2][kk0 + i]);
        *(u16x8*)&Wtb[(size_t)((h << 6) + n2) * NFEAT + k0 + kk0] = o;
    } else if ((int)blockIdx.x < 128 + csb) {
        // fire-and-forget bitmap OR
        __shared__ int s64f;
        if (t < 64) {
            unsigned long long bal = __ballot(e32[2 * t + 1] == 0);
            if (t == 0) s64f = (__popcll(bal) >= 48);
        }
        __syncthreads();
        int i = (blockIdx.x - 128) * 256 + t;
        if (i < E) {
            int s, tt;
            if (s64f) { s = e32[2 * i]; tt = e32[2 * (E + i)]; }
            else      { s = e32[i];     tt = e32[E + i]; }
            s &= (NN - 1); tt &= (NN - 1);
            unsigned int pos = (unsigned int)s * NN + (unsigned int)tt;
            atomicOr(&bits[pos >> 5], 1u << (pos & 31u));
        }
    } else {
        const int NF8 = NN * NFEAT / 8;
        int i = (blockIdx.x - 128 - csb) * 256 + t;
        int stride = (gridDim.x - 128 - csb) * 256;
        const int TOT = NF8 + NSMALL;
        for (; i < TOT; i += stride) {
            if (i < NF8) {
                if (bf) {
                    *(u16x8*)&featb[i * 8] = ((const u16x8*)f)[i];
                } else {
                    float4 lo = ((const float4*)f)[i * 2];
                    float4 hi = ((const float4*)f)[i * 2 + 1];
                    u16x8 o;
                    o[0] = f2b(lo.x); o[1] = f2b(lo.y); o[2] = f2b(lo.z); o[3] = f2b(lo.w);
                    o[4] = f2b(hi.x); o[5] = f2b(hi.y); o[6] = f2b(hi.z); o[7] = f2b(hi.w);
                    *(u16x8*)&featb[i * 8] = o;
                }
            } else {
                int r = i - NF8;
                const void* sp; int off;
                if (r < SZ2)                        { sp = ah_; off = r; }
                else if (r < SZ2 + SZ3)             { sp = bh_; off = r - SZ2; }
                else if (r < SZ2 + SZ3 + SZ4)       { sp = Wo_; off = r - SZ2 - SZ3; }
                else if (r < SZ2 + SZ3 + SZ4 + SZ5) { sp = ao_; off = r - SZ2 - SZ3 - SZ4; }
                else                                { sp = bo_; off = r - SZ2 - SZ3 - SZ4 - SZ5; }
                smallf[r] = bf ? b2f(((const unsigned short*)sp)[off])
                               : ((const float*)sp)[off];
            }
        }
    }
}

// ---------- merged extract + gemm1, 1024 blocks (verified fused-P1 body) ----------
// Each block: extract 4 nodes' bitmap rows -> csr/deg, THEN one 32-row x 16-col/wave
// GEMM tile (h = bid>>7). 4 blocks/CU -> 4x the latency-hiding waves of the old
// 256-block GEMM (1 wave/SIMD was the round-1 defect).
__global__ void __launch_bounds__(256)
k_gemm1024(const unsigned short* __restrict__ featb,
           const unsigned short* __restrict__ Wtb,
           const float* __restrict__ ah,
           unsigned short* __restrict__ Hb,
           float* __restrict__ s1, float* __restrict__ s2,
           float* __restrict__ cm1,
           const unsigned int* __restrict__ bits,
           int* __restrict__ deg, int* __restrict__ csr) {
    __shared__ float sp1[32], sp2[32], cms64[64];
    int t = threadIdx.x, bid = blockIdx.x;
    int wid = t >> 6, lane = t & 63;
    {   // ---- extract: registers/shuffles only ----
        int n = bid * 4 + wid;
        uint2 w2 = *(const uint2*)&bits[n * 128 + lane * 2];
        int c = __popc(w2.x) + __popc(w2.y);
        int incl = c;
#pragma unroll
        for (int off = 1; off < 64; off <<= 1) {
            int u = __shfl_up(incl, off, 64);
            if (lane >= off) incl += u;
        }
        int excl = incl - c;
        int total = __shfl(incl, 63, 64);
        if (lane == 0) deg[n] = total;
        int base = n * CAP;
        int tbase = lane * 64;
        unsigned int x = w2.x;
        while (x) {
            int b = __ffs(x) - 1; x &= x - 1;
            if (excl < CAP) csr[base + excl] = tbase + b;
            ++excl;
        }
        unsigned int y = w2.y;
        while (y) {
            int b = __ffs(y) - 1; y &= y - 1;
            if (excl < CAP) csr[base + excl] = tbase + 32 + b;
            ++excl;
        }
    }
    // ---- gemm1 tile: h = bid>>7, rows m0..m0+31, wave owns 16 cols ----
    if (t < 32) sp1[t] = 0.f;
    else if (t < 64) sp2[t - 32] = 0.f;
    __syncthreads();
    int h = bid >> 7, m0 = (bid & 127) << 5;
    int quad = lane >> 4, l16 = lane & 15;
    f32x4 acc0 = {}, acc1 = {};
    const unsigned short* a0p = featb + (size_t)(m0 + l16) * NFEAT + quad * 8;
    const unsigned short* a1p = a0p + 16 * NFEAT;
    const unsigned short* bp  = Wtb + ((size_t)h << 15) + (size_t)(wid * 16 + l16) * NFEAT + quad * 8;
#pragma unroll 4
    for (int k0 = 0; k0 < NFEAT; k0 += 32) {
        bf16x8 a0 = *(const bf16x8*)(a0p + k0);
        bf16x8 a1 = *(const bf16x8*)(a1p + k0);
        bf16x8 b  = *(const bf16x8*)(bp + k0);
        acc0 = __builtin_amdgcn_mfma_f32_16x16x32_bf16(a0, b, acc0, 0, 0, 0);
        acc1 = __builtin_amdgcn_mfma_f32_16x16x32_bf16(a1, b, acc1, 0, 0, 0);
    }
    const float* av = ah + h * 2 * NHID;
    int col = wid * 16 + l16;
    float av1 = av[col], av2 = av[NHID + col];
    float p1v[2][4], p2v[2][4];
    float csum = 0.f;
#pragma unroll
    for (int rh = 0; rh < 2; ++rh)
#pragma unroll
        for (int r = 0; r < 4; ++r) {
            float v = rh ? acc1[r] : acc0[r];
            int row = m0 + rh * 16 + quad * 4 + r;
            Hb[((size_t)row << 9) + (h << 6) + col] = f2b(v);   // node-major
            p1v[rh][r] = v * av1;
            p2v[rh][r] = v * av2;
            csum += v;
        }
#pragma unroll
    for (int m = 8; m >= 1; m >>= 1)
#pragma unroll
        for (int rh = 0; rh < 2; ++rh)
#pragma unroll
            for (int r = 0; r < 4; ++r) {
                p1v[rh][r] += __shfl_xor(p1v[rh][r], m, 64);
                p2v[rh][r] += __shfl_xor(p2v[rh][r], m, 64);
            }
    if (l16 == 0) {
#pragma unroll
        for (int rh = 0; rh < 2; ++rh)
#pragma unroll
            for (int r = 0; r < 4; ++r) {
                atomicAdd(&sp1[rh * 16 + quad * 4 + r], p1v[rh][r]);
                atomicAdd(&sp2[rh * 16 + quad * 4 + r], p2v[rh][r]);
            }
    }
    csum += __shfl_xor(csum, 16, 64);
    csum += __shfl_xor(csum, 32, 64);
    if (lane < 16) cms64[wid * 16 + lane] = csum;
    __syncthreads();
    if (t < 32) {
        s1[(h << 12) + m0 + t] = sp1[t];
        s2[(h << 12) + m0 + t] = sp2[t];
    }
    if (t < 64) atomicAdd(&cm1[h * NHID + t], cms64[t]);
}

// ---------- fused layer-1: all-head softmax + SpMM + bias + ELU + gemm2 + scores2 ----------
__global__ void __launch_bounds__(256)
k_attn1f(const int* __restrict__ deg, const int* __restrict__ csr,
         const float* __restrict__ s1, const float* __restrict__ s2,
         const unsigned short* __restrict__ Hb,
         const float* __restrict__ bh, const float* __restrict__ cm1,
         const float* __restrict__ Wo, const float* __restrict__ ao,
         float* __restrict__ out2, float* __restrict__ s1o,
         float* __restrict__ s2o, float* __restrict__ cm2) {
    __shared__ float sW[4][CAP * 8];
    __shared__ int   sT[4][CAP];
    __shared__ float xr[4][NFEAT];
    __shared__ float cms[NCLASS];
    int t = threadIdx.x;
    if (t < NCLASS) cms[t] = 0.f;
    __syncthreads();
    int wid = t >> 6, lane = t & 63;
    int n = blockIdx.x * 4 + wid;
    int h = lane >> 3, jslot = lane & 7;
    int d = min(deg[n], CAP);
    float acc[8] = {};
    float rden = 1.f;
    if (d > 0) {
        const int* row = csr + (size_t)n * CAP;
        const float* s2h = s2 + ((size_t)h << 12);
        float s1n = s1[(h << 12) + n];
        float mx = -1e30f;
        for (int jb = 0; jb < d; jb += 8) {
            int j = jb + jslot;
            int tt = (j < d) ? row[j] : 0;
            float e = (j < d) ? lrelu(s1n + s2h[tt]) : -1e30f;
            sW[wid][(j << 3) + h] = e;
            if (h == 0) sT[wid][j] = tt;
            mx = fmaxf(mx, e);
        }
        mx = fmaxf(mx, __shfl_xor(mx, 1, 64));
        mx = fmaxf(mx, __shfl_xor(mx, 2, 64));
        mx = fmaxf(mx, __shfl_xor(mx, 4, 64));
        float den = 0.f;
        for (int jb = 0; jb < d; jb += 8) {
            int j = jb + jslot;
            float e = sW[wid][(j << 3) + h];
            float w = __expf(e - mx);
            sW[wid][(j << 3) + h] = w;
            den += w;
        }
        den += __shfl_xor(den, 1, 64);
        den += __shfl_xor(den, 2, 64);
        den += __shfl_xor(den, 4, 64);
        rden = 1.f / den;
        const unsigned short* Hp = Hb + lane * 8;
        int j = 0;
        for (; j + 4 <= d; j += 4) {      // 4 loads in flight (verified round 6)
            int t0 = sT[wid][j],     t1 = sT[wid][j + 1];
            int t2 = sT[wid][j + 2], t3 = sT[wid][j + 3];
            float w0 = sW[wid][(j << 3) + h];
            float w1 = sW[wid][((j + 1) << 3) + h];
            float w2 = sW[wid][((j + 2) << 3) + h];
            float w3 = sW[wid][((j + 3) << 3) + h];
            u16x8 v0 = *(const u16x8*)(Hp + ((size_t)t0 << 9));
            u16x8 v1 = *(const u16x8*)(Hp + ((size_t)t1 << 9));
            u16x8 v2 = *(const u16x8*)(Hp + ((size_t)t2 << 9));
            u16x8 v3 = *(const u16x8*)(Hp + ((size_t)t3 << 9));
#pragma unroll
            for (int i = 0; i < 8; ++i)
                acc[i] += w0 * b2f(v0[i]) + w1 * b2f(v1[i])
                        + w2 * b2f(v2[i]) + w3 * b2f(v3[i]);
        }
        for (; j < d; ++j) {
            int t0 = sT[wid][j];
            float w0 = sW[wid][(j << 3) + h];
            u16x8 v0 = *(const u16x8*)(Hp + ((size_t)t0 << 9));
#pragma unroll
            for (int i = 0; i < 8; ++i) acc[i] += w0 * b2f(v0[i]);
        }
    }
    float o[8];
    if (d == 0) {
#pragma unroll
        for (int i = 0; i < 8; ++i) o[i] = cm1[lane * 8 + i] * (1.0f / NN);
    } else {
#pragma unroll
        for (int i = 0; i < 8; ++i) o[i] = acc[i] * rden;
    }
#pragma unroll
    for (int i = 0; i < 8; ++i) {
        float v = o[i] + bh[lane * 8 + i];
        o[i] = v > 0.f ? v : __expf(v) - 1.f;     // ELU
    }
    float* xw = xr[wid];
    *(float4*)&xw[lane * 8]     = make_float4(o[0], o[1], o[2], o[3]);
    *(float4*)&xw[lane * 8 + 4] = make_float4(o[4], o[5], o[6], o[7]);
    int c = lane & 15, sub = lane >> 4;
    const float* xp = xw + sub * 128;
    const float* wp = Wo + sub * 128 * NCLASS + c;
    float a2 = 0.f;
#pragma unroll 8
    for (int kk = 0; kk < 128; ++kk) a2 += xp[kk] * wp[kk * NCLASS];
    a2 += __shfl_xor(a2, 16, 64);
    a2 += __shfl_xor(a2, 32, 64);
    if (lane < 16) out2[n * NCLASS + c] = a2;
    float r1 = a2 * ao[c], r2 = a2 * ao[NCLASS + c];
#pragma unroll
    for (int m = 8; m >= 1; m >>= 1) {
        r1 += __shfl_xor(r1, m, 16);
        r2 += __shfl_xor(r2, m, 16);
    }
    if (lane == 0) { s1o[n] = r1; s2o[n] = r2; }
    if (lane < 16) atomicAdd(&cms[c], a2);
    __syncthreads();
    if (t < NCLASS) atomicAdd(&cm2[t], cms[t]);
}

// ---------- layer-2: softmax + SpMM + bias + log_softmax ----------
__global__ void __launch_bounds__(256)
k_attn2(const int* __restrict__ deg, const int* __restrict__ csr,
        const float* __restrict__ s1o, const float* __restrict__ s2o,
        const float* __restrict__ out2, const float* __restrict__ bo,
        const float* __restrict__ cm2, float* __restrict__ outp) {
    __shared__ float wv[4][CAP];
    __shared__ float o2s[4][16];
    int wid = threadIdx.x >> 6, lane = threadIdx.x & 63;
    int n = blockIdx.x * 4 + wid;
    int c = lane & 15;
    int d = min(deg[n], CAP);
    float val;
    if (d == 0) {
        val = cm2[c] * (1.0f / NN);
    } else {
        float s1n = s1o[n];
        const int* rowp = csr + (size_t)n * CAP;
        int t0 = (lane < d)       ? rowp[lane]       : 0;
        int t1 = (lane + 64 < d)  ? rowp[lane + 64]  : 0;
        int t2 = (lane + 128 < d) ? rowp[lane + 128] : 0;
        float e0 = (lane < d)       ? lrelu(s1n + s2o[t0]) : -1e30f;
        float e1 = (lane + 64 < d)  ? lrelu(s1n + s2o[t1]) : -1e30f;
        float e2 = (lane + 128 < d) ? lrelu(s1n + s2o[t2]) : -1e30f;
        float m = waveMax(fmaxf(e0, fmaxf(e1, e2)));
        float w0 = (lane < d)       ? __expf(e0 - m) : 0.f;
        float w1 = (lane + 64 < d)  ? __expf(e1 - m) : 0.f;
        float w2 = (lane + 128 < d) ? __expf(e2 - m) : 0.f;
        float den = waveSum(w0 + w1 + w2);
        wv[wid][lane]       = w0;
        wv[wid][lane + 64]  = w1;
        wv[wid][lane + 128] = w2;
        int g2 = lane >> 2, q = lane & 3;
        float a4[4] = {};
        for (int j = g2; j < d; j += 16) {
            float w = wv[wid][j];
            int tt = rowp[j];
            float4 v = *(const float4*)(out2 + tt * NCLASS + q * 4);
            a4[0] += w * v.x; a4[1] += w * v.y;
            a4[2] += w * v.z; a4[3] += w * v.w;
        }
#pragma unroll
        for (int m2 = 4; m2 <= 32; m2 <<= 1)
#pragma unroll
            for (int i = 0; i < 4; ++i) a4[i] += __shfl_xor(a4[i], m2, 64);
        if (lane < 4)
            *(float4*)&o2s[wid][lane * 4] = make_float4(a4[0], a4[1], a4[2], a4[3]);
        val = o2s[wid][c] / den;
    }
    val += bo[c];
    float mx = val;
#pragma unroll
    for (int m = 8; m >= 1; m >>= 1) mx = fmaxf(mx, __shfl_xor(mx, m, 16));
    float se = __expf(val - mx);
#pragma unroll
    for (int m = 8; m >= 1; m >>= 1) se += __shfl_xor(se, m, 16);
    float res = val - mx - __logf(se);
    if (lane < 16) outp[n * NCLASS + lane] = res;
}

extern "C" void kernel_launch(void* const* d_in, const int* in_sizes, int n_in,
                              void* d_out, int out_size, void* d_ws, size_t ws_size,
                              hipStream_t stream) {
    const void* features = d_in[0];
    const int*  edges    = (const int*)d_in[1];
    const void* W_heads  = d_in[2];
    const void* a_heads  = d_in[3];
    const void* b_heads  = d_in[4];
    const void* W_out    = d_in[5];
    const void* a_out    = d_in[6];
    const void* b_out    = d_in[7];
    int E = in_sizes[1] / 2;
    int csb = (E + 255) / 256;

    // ---- workspace layout (4B units); bits,deg,cm1,cm2 contiguous zero region ----
    unsigned int* bits = (unsigned int*)d_ws;                  // NN*NN/32
    int*   deg  = (int*)(bits + (NN * NN / 32));               // NN
    float* cm1  = (float*)(deg + NN);                          // NHEAD*NHID
    float* cm2  = cm1 + NHEAD * NHID;                          // NCLASS (zero region ends)
    int*   csr  = (int*)(cm2 + NCLASS);                        // NN*CAP
    float* s1   = (float*)(csr + NN * CAP);                    // NHEAD*NN
    float* s2   = s1 + NHEAD * NN;                             // NHEAD*NN
    float* out2 = s2 + NHEAD * NN;                             // NN*NCLASS
    float* s1o  = out2 + NN * NCLASS;                          // NN
    float* s2o  = s1o + NN;                                    // NN
    float* smallf = s2o + NN;                                  // NSMALL fp32
    unsigned short* Hb    = (unsigned short*)(smallf + NSMALL);// NN*512 bf16 (node-major)
    unsigned short* featb = Hb + (size_t)NN * NHEAD * NHID;    // NN*NFEAT bf16
    unsigned short* Wtb   = featb + (size_t)NN * NFEAT;        // NHEAD*NHID*NFEAT bf16
    float* outp = (float*)d_out;

    hipMemsetAsync(d_ws, 0, (size_t)NZERO * 4, stream);        // bits+deg+cm1+cm2
    hipLaunchKernelGGL(k_prep, dim3(128 + csb + 896), dim3(256), 0, stream,
                       features, W_heads, a_heads, b_heads, W_out, a_out, b_out,
                       edges, E, csb, featb, Wtb, smallf, bits);
    hipLaunchKernelGGL(k_gemm1024, dim3(1024), dim3(256), 0, stream,
                       featb, Wtb, smallf, Hb, s1, s2, cm1, bits, deg, csr);
    hipLaunchKernelGGL(k_attn1f, dim3(NN / 4), dim3(256), 0, stream,
                       deg, csr, s1, s2, Hb, smallf + SZ2, cm1,
                       smallf + SZ2 + SZ3, smallf + SZ2 + SZ3 + SZ4,
                       out2, s1o, s2o, cm2);
    hipLaunchKernelGGL(k_attn2, dim3(NN / 4), dim3(256), 0, stream,
                       deg, csr, s1o, s2o, out2,
                       smallf + SZ2 + SZ3 + SZ4 + SZ5, cm2, outp);
}

// Round 8
// 143.726 us; speedup vs baseline: 3.7068x; 1.0817x over previous
//
#include <hip/hip_runtime.h>
#include <hip/hip_bf16.h>

#define NN 4096
#define NFEAT 512
#define NHID 64
#define NHEAD 8
#define NCLASS 16
#define CAP 160
#define LALPHA 0.2f

#define SZ2 (NHEAD*2*NHID)   // a_heads
#define SZ3 (NHEAD*NHID)     // b_heads
#define SZ4 (NFEAT*NCLASS)   // W_out
#define SZ5 (2*NCLASS)       // a_out
#define SZ6 (NCLASS)         // b_out
#define NSMALL (SZ2+SZ3+SZ4+SZ5+SZ6)

typedef __attribute__((ext_vector_type(8))) short bf16x8;
typedef __attribute__((ext_vector_type(4))) float f32x4;
typedef __attribute__((ext_vector_type(8))) unsigned short u16x8;

__device__ __forceinline__ float b2f(unsigned short h) {
    return __uint_as_float(((unsigned int)h) << 16);
}
__device__ __forceinline__ unsigned short f2b(float f) {
    unsigned int u = __float_as_uint(f);
    unsigned int r = (u + 0x7fffu + ((u >> 16) & 1u)) >> 16;
    return (unsigned short)r;
}
__device__ __forceinline__ float waveMax(float v) {
#pragma unroll
    for (int m = 32; m >= 1; m >>= 1) v = fmaxf(v, __shfl_xor(v, m, 64));
    return v;
}
__device__ __forceinline__ float waveSum(float v) {
#pragma unroll
    for (int m = 32; m >= 1; m >>= 1) v += __shfl_xor(v, m, 64);
    return v;
}
__device__ __forceinline__ float lrelu(float e) {
    return e >= 0.f ? e : LALPHA * e;
}

// ---------- K0: zero bits/cm1/cm2 + W-transpose + feature/small casts ----------
// Replaces the hipMemsetAsync dispatch: every block zeroes its bits slice first
// (1 store/thread at grid 2048), block 0 also zeroes cm1+cm2. deg needs no zero
// (K2 writes it with a plain store).
__global__ void __launch_bounds__(256)
k_prep0(const void* __restrict__ f, const void* __restrict__ Wh_,
        const void* __restrict__ ah_, const void* __restrict__ bh_,
        const void* __restrict__ Wo_, const void* __restrict__ ao_,
        const void* __restrict__ bo_,
        unsigned short* __restrict__ featb,
        unsigned short* __restrict__ Wtb,
        float* __restrict__ smallf,
        unsigned int* __restrict__ bits,
        float* __restrict__ cmz) {
    int t = threadIdx.x, bid = blockIdx.x;
    for (int i = bid * 256 + t; i < NN * NN / 32; i += gridDim.x * 256)
        bits[i] = 0u;
    if (bid == 0)
        for (int i = t; i < NHEAD * NHID + NCLASS; i += 256) cmz[i] = 0.f;
    __shared__ int sbf;
    if (t < 64) {
        unsigned int w = ((const unsigned int*)f)[t];
        unsigned int lo = w & 0xffffu, e = (lo >> 7) & 0xffu;
        unsigned long long bal = __ballot(lo == 0u || (e >= 100u && e <= 140u));
        if (t == 0) sbf = (__popcll(bal) >= 40);
    }
    __syncthreads();
    bool bf = (sbf != 0);
    if (bid < 128) {
        __shared__ float tile[64][33];
        int h = bid >> 4, k0 = (bid & 15) * 32;
        int n = t & 63, kh = t >> 6;
#pragma unroll
        for (int i = 0; i < 8; ++i) {
            int kk = kh * 8 + i;
            int si = (h << 15) + (k0 + kk) * NHID + n;
            float v = bf ? b2f(((const unsigned short*)Wh_)[si])
                         : ((const float*)Wh_)[si];
            tile[n][kk] = v;
        }
        __syncthreads();
        int n2 = t >> 2, kk0 = (t & 3) * 8;
        u16x8 o;
#pragma unroll
        for (int i = 0; i < 8; ++i) o[i] = f2b(tile[n2][kk0 + i]);
        *(u16x8*)&Wtb[(size_t)((h << 6) + n2) * NFEAT + k0 + kk0] = o;
    } else {
        const int NF8 = NN * NFEAT / 8;
        int i = (bid - 128) * 256 + t;
        int stride = (gridDim.x - 128) * 256;
        const int TOT = NF8 + NSMALL;
        for (; i < TOT; i += stride) {
            if (i < NF8) {
                if (bf) {
                    *(u16x8*)&featb[i * 8] = ((const u16x8*)f)[i];
                } else {
                    float4 lo = ((const float4*)f)[i * 2];
                    float4 hi = ((const float4*)f)[i * 2 + 1];
                    u16x8 o;
                    o[0] = f2b(lo.x); o[1] = f2b(lo.y); o[2] = f2b(lo.z); o[3] = f2b(lo.w);
                    o[4] = f2b(hi.x); o[5] = f2b(hi.y); o[6] = f2b(hi.z); o[7] = f2b(hi.w);
                    *(u16x8*)&featb[i * 8] = o;
                }
            } else {
                int r = i - NF8;
                const void* sp; int off;
                if (r < SZ2)                        { sp = ah_; off = r; }
                else if (r < SZ2 + SZ3)             { sp = bh_; off = r - SZ2; }
                else if (r < SZ2 + SZ3 + SZ4)       { sp = Wo_; off = r - SZ2 - SZ3; }
                else if (r < SZ2 + SZ3 + SZ4 + SZ5) { sp = ao_; off = r - SZ2 - SZ3 - SZ4; }
                else                                { sp = bo_; off = r - SZ2 - SZ3 - SZ4 - SZ5; }
                smallf[r] = bf ? b2f(((const unsigned short*)sp)[off])
                               : ((const float*)sp)[off];
            }
        }
    }
}

// ---------- K1: gemm1 (blocks [0,256), r1's 32x64 B-reuse tiling) + bitmap OR ----------
__global__ void __launch_bounds__(256)
k_gemm_or(const unsigned short* __restrict__ Ab,
          const unsigned short* __restrict__ Wtb,
          const float* __restrict__ ah,
          unsigned short* __restrict__ Hb,
          float* __restrict__ s1, float* __restrict__ s2,
          float* __restrict__ cm1,
          const int* __restrict__ e32, int E,
          unsigned int* __restrict__ bits) {
    int t = threadIdx.x;
    if (blockIdx.x >= 256) {
        // fire-and-forget bitmap OR
        __shared__ int s64f;
        if (t < 64) {
            unsigned long long bal = __ballot(e32[2 * t + 1] == 0);
            if (t == 0) s64f = (__popcll(bal) >= 48);
        }
        __syncthreads();
        int i = (blockIdx.x - 256) * 256 + t;
        if (i < E) {
            int s, tt;
            if (s64f) { s = e32[2 * i]; tt = e32[2 * (E + i)]; }
            else      { s = e32[i];     tt = e32[E + i]; }
            s &= (NN - 1); tt &= (NN - 1);
            unsigned int pos = (unsigned int)s * NN + (unsigned int)tt;
            atomicOr(&bits[pos >> 5], 1u << (pos & 31u));
        }
        return;
    }
    // ---- gemm1 (verbatim round-1 body): h = b>>5, wave = 32 rows x 64 cols ----
    __shared__ float cms[64];
    if (t < 64) cms[t] = 0.f;
    __syncthreads();
    int w = t >> 6, l = t & 63;
    int quad = l >> 4, l16 = l & 15;
    int h = blockIdx.x >> 5;
    int m0 = (blockIdx.x & 31) * 128 + w * 32;
    f32x4 acc[2][4] = {};
    const unsigned short* a0p = Ab + (size_t)(m0 + l16) * NFEAT + quad * 8;
    const unsigned short* a1p = a0p + 16 * NFEAT;
    const unsigned short* bp  = Wtb + ((size_t)h << 15) + (size_t)l16 * NFEAT + quad * 8;
#pragma unroll 4
    for (int k0 = 0; k0 < NFEAT; k0 += 32) {
        bf16x8 a0 = *(const bf16x8*)(a0p + k0);
        bf16x8 a1 = *(const bf16x8*)(a1p + k0);
#pragma unroll
        for (int nt = 0; nt < 4; ++nt) {
            bf16x8 b = *(const bf16x8*)(bp + (size_t)nt * 16 * NFEAT + k0);
            acc[0][nt] = __builtin_amdgcn_mfma_f32_16x16x32_bf16(a0, b, acc[0][nt], 0, 0, 0);
            acc[1][nt] = __builtin_amdgcn_mfma_f32_16x16x32_bf16(a1, b, acc[1][nt], 0, 0, 0);
        }
    }
    const float* av = ah + h * 2 * NHID;
    float p1[2][4] = {}, p2[2][4] = {};
#pragma unroll
    for (int rh = 0; rh < 2; ++rh) {
#pragma unroll
        for (int nt = 0; nt < 4; ++nt) {
            int col = nt * 16 + l16;
            float av1 = av[col], av2 = av[NHID + col];
            float csum = 0.f;
#pragma unroll
            for (int r = 0; r < 4; ++r) {
                float v = acc[rh][nt][r];
                int row = m0 + rh * 16 + quad * 4 + r;
                Hb[((size_t)row << 9) + (h << 6) + col] = f2b(v);   // node-major
                p1[rh][r] += v * av1;
                p2[rh][r] += v * av2;
                csum += v;
            }
            atomicAdd(&cms[col], csum);
        }
    }
#pragma unroll
    for (int m = 8; m >= 1; m >>= 1)
#pragma unroll
        for (int rh = 0; rh < 2; ++rh)
#pragma unroll
            for (int r = 0; r < 4; ++r) {
                p1[rh][r] += __shfl_xor(p1[rh][r], m, 64);
                p2[rh][r] += __shfl_xor(p2[rh][r], m, 64);
            }
    if (l16 == 0) {
#pragma unroll
        for (int rh = 0; rh < 2; ++rh)
#pragma unroll
            for (int r = 0; r < 4; ++r) {
                int row = m0 + rh * 16 + quad * 4 + r;
                s1[(h << 12) + row] = p1[rh][r];
                s2[(h << 12) + row] = p2[rh][r];
            }
    }
    __syncthreads();
    if (t < 64) atomicAdd(&cm1[h * NHID + t], cms[t]);
}

// ---------- K2: extract->LDS + attn1 (all heads/wave) + bias + ELU + gemm2 + scores2 ----------
// Each block extracts its own 4 nodes' adjacency into LDS sT (writes csr/deg for K3),
// then runs the verified attn1 body reading neighbors from LDS.
// LDS 23.1 KB -> 5-7 blocks/CU (vs 4 with the old 35.9 KB).
__global__ void __launch_bounds__(256)
k_eattn1(const unsigned int* __restrict__ bits,
         int* __restrict__ deg, int* __restrict__ csr,
         const float* __restrict__ s1, const float* __restrict__ s2,
         const unsigned short* __restrict__ Hb,
         const float* __restrict__ bh, const float* __restrict__ cm1,
         const float* __restrict__ Wo, const float* __restrict__ ao,
         float* __restrict__ out2, float* __restrict__ s1o,
         float* __restrict__ s2o, float* __restrict__ cm2) {
    __shared__ float sW[4][CAP * 8];   // weights; reused as X row after gather
    __shared__ int   sT[4][CAP];
    __shared__ float cms[NCLASS];
    int t = threadIdx.x;
    if (t < NCLASS) cms[t] = 0.f;
    int wid = t >> 6, lane = t & 63;
    int n = blockIdx.x * 4 + wid;
    int d;
    {   // ---- extract own node's bitmap row into sT (r1-verified scan body) ----
        uint2 w2 = *(const uint2*)&bits[n * 128 + lane * 2];
        int c = __popc(w2.x) + __popc(w2.y);
        int incl = c;
#pragma unroll
        for (int off = 1; off < 64; off <<= 1) {
            int u = __shfl_up(incl, off, 64);
            if (lane >= off) incl += u;
        }
        int excl = incl - c;
        int total = __shfl(incl, 63, 64);
        if (lane == 0) deg[n] = total;
        int tbase = lane * 64;
        unsigned int x = w2.x;
        while (x) {
            int b = __ffs(x) - 1; x &= x - 1;
            if (excl < CAP) sT[wid][excl] = tbase + b;
            ++excl;
        }
        unsigned int y = w2.y;
        while (y) {
            int b = __ffs(y) - 1; y &= y - 1;
            if (excl < CAP) sT[wid][excl] = tbase + 32 + b;
            ++excl;
        }
        d = min(total, CAP);
    }
    __syncthreads();
    // coalesced csr write-back for K3
    for (int k = lane; k < d; k += 64) csr[(size_t)n * CAP + k] = sT[wid][k];
    int h = lane >> 3, jslot = lane & 7;
    float acc[8] = {};
    float rden = 1.f;
    if (d > 0) {
        const float* s2h = s2 + ((size_t)h << 12);
        float s1n = s1[(h << 12) + n];
        float mx = -1e30f;
        for (int jb = 0; jb < d; jb += 8) {
            int j = jb + jslot;
            int tt = (j < d) ? sT[wid][j] : 0;
            float e = (j < d) ? lrelu(s1n + s2h[tt]) : -1e30f;
            sW[wid][(j << 3) + h] = e;
            mx = fmaxf(mx, e);
        }
        mx = fmaxf(mx, __shfl_xor(mx, 1, 64));
        mx = fmaxf(mx, __shfl_xor(mx, 2, 64));
        mx = fmaxf(mx, __shfl_xor(mx, 4, 64));
        float den = 0.f;
        for (int jb = 0; jb < d; jb += 8) {
            int j = jb + jslot;
            float e = sW[wid][(j << 3) + h];
            float w = __expf(e - mx);
            sW[wid][(j << 3) + h] = w;
            den += w;
        }
        den += __shfl_xor(den, 1, 64);
        den += __shfl_xor(den, 2, 64);
        den += __shfl_xor(den, 4, 64);
        rden = 1.f / den;
        const unsigned short* Hp = Hb + lane * 8;
        int j = 0;
        for (; j + 4 <= d; j += 4) {      // 4 loads in flight (verified r6/r7)
            int t0 = sT[wid][j],     t1 = sT[wid][j + 1];
            int t2 = sT[wid][j + 2], t3 = sT[wid][j + 3];
            float w0 = sW[wid][(j << 3) + h];
            float w1 = sW[wid][((j + 1) << 3) + h];
            float w2 = sW[wid][((j + 2) << 3) + h];
            float w3 = sW[wid][((j + 3) << 3) + h];
            u16x8 v0 = *(const u16x8*)(Hp + ((size_t)t0 << 9));
            u16x8 v1 = *(const u16x8*)(Hp + ((size_t)t1 << 9));
            u16x8 v2 = *(const u16x8*)(Hp + ((size_t)t2 << 9));
            u16x8 v3 = *(const u16x8*)(Hp + ((size_t)t3 << 9));
#pragma unroll
            for (int i = 0; i < 8; ++i)
                acc[i] += w0 * b2f(v0[i]) + w1 * b2f(v1[i])
                        + w2 * b2f(v2[i]) + w3 * b2f(v3[i]);
        }
        for (; j < d; ++j) {
            int t0 = sT[wid][j];
            float w0 = sW[wid][(j << 3) + h];
            u16x8 v0 = *(const u16x8*)(Hp + ((size_t)t0 << 9));
#pragma unroll
            for (int i = 0; i < 8; ++i) acc[i] += w0 * b2f(v0[i]);
        }
    }
    float o[8];
    if (d == 0) {
#pragma unroll
        for (int i = 0; i < 8; ++i) o[i] = cm1[lane * 8 + i] * (1.0f / NN);
    } else {
#pragma unroll
        for (int i = 0; i < 8; ++i) o[i] = acc[i] * rden;
    }
#pragma unroll
    for (int i = 0; i < 8; ++i) {
        float v = o[i] + bh[lane * 8 + i];
        o[i] = v > 0.f ? v : __expf(v) - 1.f;     // ELU
    }
    // reuse this wave's weight region as its X row (verified fused-P2 pattern)
    float* xw = sW[wid];
    *(float4*)&xw[lane * 8]     = make_float4(o[0], o[1], o[2], o[3]);
    *(float4*)&xw[lane * 8 + 4] = make_float4(o[4], o[5], o[6], o[7]);
    int c = lane & 15, sub = lane >> 4;
    const float* xp = xw + sub * 128;
    const float* wp = Wo + sub * 128 * NCLASS + c;
    float a2 = 0.f;
#pragma unroll 8
    for (int kk = 0; kk < 128; ++kk) a2 += xp[kk] * wp[kk * NCLASS];
    a2 += __shfl_xor(a2, 16, 64);
    a2 += __shfl_xor(a2, 32, 64);
    if (lane < 16) out2[n * NCLASS + c] = a2;
    float r1 = a2 * ao[c], r2 = a2 * ao[NCLASS + c];
#pragma unroll
    for (int m = 8; m >= 1; m >>= 1) {
        r1 += __shfl_xor(r1, m, 16);
        r2 += __shfl_xor(r2, m, 16);
    }
    if (lane == 0) { s1o[n] = r1; s2o[n] = r2; }
    if (lane < 16) atomicAdd(&cms[c], a2);
    __syncthreads();
    if (t < NCLASS) atomicAdd(&cm2[t], cms[t]);
}

// ---------- K3: attn2 + bias + log_softmax ----------
__global__ void __launch_bounds__(256)
k_attn2(const int* __restrict__ deg, const int* __restrict__ csr,
        const float* __restrict__ s1o, const float* __restrict__ s2o,
        const float* __restrict__ out2, const float* __restrict__ bo,
        const float* __restrict__ cm2, float* __restrict__ outp) {
    __shared__ float wv[4][CAP];
    __shared__ float o2s[4][16];
    int wid = threadIdx.x >> 6, lane = threadIdx.x & 63;
    int n = blockIdx.x * 4 + wid;
    int c = lane & 15;
    int d = min(deg[n], CAP);
    float val;
    if (d == 0) {
        val = cm2[c] * (1.0f / NN);
    } else {
        float s1n = s1o[n];
        const int* rowp = csr + (size_t)n * CAP;
        int t0 = (lane < d)       ? rowp[lane]       : 0;
        int t1 = (lane + 64 < d)  ? rowp[lane + 64]  : 0;
        int t2 = (lane + 128 < d) ? rowp[lane + 128] : 0;
        float e0 = (lane < d)       ? lrelu(s1n + s2o[t0]) : -1e30f;
        float e1 = (lane + 64 < d)  ? lrelu(s1n + s2o[t1]) : -1e30f;
        float e2 = (lane + 128 < d) ? lrelu(s1n + s2o[t2]) : -1e30f;
        float m = waveMax(fmaxf(e0, fmaxf(e1, e2)));
        float w0 = (lane < d)       ? __expf(e0 - m) : 0.f;
        float w1 = (lane + 64 < d)  ? __expf(e1 - m) : 0.f;
        float w2 = (lane + 128 < d) ? __expf(e2 - m) : 0.f;
        float den = waveSum(w0 + w1 + w2);
        wv[wid][lane] = w0;
        if (lane + 64 < CAP)  wv[wid][lane + 64]  = w1;
        if (lane + 128 < CAP) wv[wid][lane + 128] = w2;
        int g2 = lane >> 2, q = lane & 3;
        float a4[4] = {};
        for (int j = g2; j < d; j += 16) {
            float w = wv[wid][j];
            int tt = rowp[j];
            float4 v = *(const float4*)(out2 + tt * NCLASS + q * 4);
            a4[0] += w * v.x; a4[1] += w * v.y;
            a4[2] += w * v.z; a4[3] += w * v.w;
        }
#pragma unroll
        for (int m2 = 4; m2 <= 32; m2 <<= 1)
#pragma unroll
            for (int i = 0; i < 4; ++i) a4[i] += __shfl_xor(a4[i], m2, 64);
        if (lane < 4)
            *(float4*)&o2s[wid][lane * 4] = make_float4(a4[0], a4[1], a4[2], a4[3]);
        val = o2s[wid][c] / den;
    }
    val += bo[c];
    float mx = val;
#pragma unroll
    for (int m = 8; m >= 1; m >>= 1) mx = fmaxf(mx, __shfl_xor(mx, m, 16));
    float se = __expf(val - mx);
#pragma unroll
    for (int m = 8; m >= 1; m >>= 1) se += __shfl_xor(se, m, 16);
    float res = val - mx - __logf(se);
    if (lane < 16) outp[n * NCLASS + lane] = res;
}

extern "C" void kernel_launch(void* const* d_in, const int* in_sizes, int n_in,
                              void* d_out, int out_size, void* d_ws, size_t ws_size,
                              hipStream_t stream) {
    const void* features = d_in[0];
    const int*  edges    = (const int*)d_in[1];
    const void* W_heads  = d_in[2];
    const void* a_heads  = d_in[3];
    const void* b_heads  = d_in[4];
    const void* W_out    = d_in[5];
    const void* a_out    = d_in[6];
    const void* b_out    = d_in[7];
    int E = in_sizes[1] / 2;
    int csb = (E + 255) / 256;

    // ---- workspace layout (4B units) ----
    unsigned int* bits = (unsigned int*)d_ws;                  // NN*NN/32 (zeroed in K0)
    int*   deg  = (int*)(bits + (NN * NN / 32));               // NN (plain stores, no zero)
    float* cm1  = (float*)(deg + NN);                          // NHEAD*NHID (zeroed in K0)
    float* cm2  = cm1 + NHEAD * NHID;                          // NCLASS    (zeroed in K0)
    int*   csr  = (int*)(cm2 + NCLASS);                        // NN*CAP
    float* s1   = (float*)(csr + NN * CAP);                    // NHEAD*NN
    float* s2   = s1 + NHEAD * NN;                             // NHEAD*NN
    float* out2 = s2 + NHEAD * NN;                             // NN*NCLASS
    float* s1o  = out2 + NN * NCLASS;                          // NN
    float* s2o  = s1o + NN;                                    // NN
    float* smallf = s2o + NN;                                  // NSMALL fp32
    unsigned short* Hb    = (unsigned short*)(smallf + NSMALL);// NN*512 bf16 (node-major)
    unsigned short* featb = Hb + (size_t)NN * NHEAD * NHID;    // NN*NFEAT bf16
    unsigned short* Wtb   = featb + (size_t)NN * NFEAT;        // NHEAD*NHID*NFEAT bf16
    float* outp = (float*)d_out;

    // K0: zero (bits/cm1/cm2) + W-T + casts  [grid 2048 so bits zeroing is 1 store/thread]
    hipLaunchKernelGGL(k_prep0, dim3(2048), dim3(256), 0, stream,
                       features, W_heads, a_heads, b_heads, W_out, a_out, b_out,
                       featb, Wtb, smallf, bits, cm1);
    // K1: gemm1 (256 blocks, B-reuse tiling) + bitmap OR (csb blocks)
    hipLaunchKernelGGL(k_gemm_or, dim3(256 + csb), dim3(256), 0, stream,
                       featb, Wtb, smallf, Hb, s1, s2, cm1, edges, E, bits);
    // K2: extract->LDS + attn1 + gemm2 fused
    hipLaunchKernelGGL(k_eattn1, dim3(NN / 4), dim3(256), 0, stream,
                       bits, deg, csr, s1, s2, Hb, smallf + SZ2, cm1,
                       smallf + SZ2 + SZ3, smallf + SZ2 + SZ3 + SZ4,
                       out2, s1o, s2o, cm2);
    // K3: attn2
    hipLaunchKernelGGL(k_attn2, dim3(NN / 4), dim3(256), 0, stream,
                       deg, csr, s1o, s2o, out2,
                       smallf + SZ2 + SZ3 + SZ4 + SZ5, cm2, outp);
}

// Round 9
// 142.274 us; speedup vs baseline: 3.7447x; 1.0102x over previous
//
#include <hip/hip_runtime.h>
#include <hip/hip_bf16.h>

#define NN 4096
#define NFEAT 512
#define NHID 64
#define NHEAD 8
#define NCLASS 16
#define CAP 160
#define LALPHA 0.2f

#define SZ2 (NHEAD*2*NHID)   // a_heads
#define SZ3 (NHEAD*NHID)     // b_heads
#define SZ4 (NFEAT*NCLASS)   // W_out
#define SZ5 (2*NCLASS)       // a_out
#define SZ6 (NCLASS)         // b_out
#define NSMALL (SZ2+SZ3+SZ4+SZ5+SZ6)

typedef __attribute__((ext_vector_type(8))) short bf16x8;
typedef __attribute__((ext_vector_type(4))) float f32x4;
typedef __attribute__((ext_vector_type(8))) unsigned short u16x8;

__device__ __forceinline__ float b2f(unsigned short h) {
    return __uint_as_float(((unsigned int)h) << 16);
}
__device__ __forceinline__ unsigned short f2b(float f) {
    unsigned int u = __float_as_uint(f);
    unsigned int r = (u + 0x7fffu + ((u >> 16) & 1u)) >> 16;
    return (unsigned short)r;
}
__device__ __forceinline__ float waveMax(float v) {
#pragma unroll
    for (int m = 32; m >= 1; m >>= 1) v = fmaxf(v, __shfl_xor(v, m, 64));
    return v;
}
__device__ __forceinline__ float waveSum(float v) {
#pragma unroll
    for (int m = 32; m >= 1; m >>= 1) v += __shfl_xor(v, m, 64);
    return v;
}
__device__ __forceinline__ float lrelu(float e) {
    return e >= 0.f ? e : LALPHA * e;
}

// ---------- K0: zero bits/cm1/cm2 + W-transpose + casts ----------
// bf16 fast-path: when features are already bf16 the 12MB cast pass is skipped
// entirely (K1 reads the input tensor directly); only small params are cast.
__global__ void __launch_bounds__(256)
k_prep0(const void* __restrict__ f, const void* __restrict__ Wh_,
        const void* __restrict__ ah_, const void* __restrict__ bh_,
        const void* __restrict__ Wo_, const void* __restrict__ ao_,
        const void* __restrict__ bo_,
        unsigned short* __restrict__ featb,
        unsigned short* __restrict__ Wtb,
        float* __restrict__ smallf,
        unsigned int* __restrict__ bits,
        float* __restrict__ cmz) {
    int t = threadIdx.x, bid = blockIdx.x;
    for (int i = bid * 256 + t; i < NN * NN / 32; i += gridDim.x * 256)
        bits[i] = 0u;
    if (bid == 0)
        for (int i = t; i < NHEAD * NHID + NCLASS; i += 256) cmz[i] = 0.f;
    __shared__ int sbf;
    if (t < 64) {
        unsigned int w = ((const unsigned int*)f)[t];
        unsigned int lo = w & 0xffffu, e = (lo >> 7) & 0xffu;
        unsigned long long bal = __ballot(lo == 0u || (e >= 100u && e <= 140u));
        if (t == 0) sbf = (__popcll(bal) >= 40);
    }
    __syncthreads();
    bool bf = (sbf != 0);
    if (bid < 128) {
        __shared__ float tile[64][33];
        int h = bid >> 4, k0 = (bid & 15) * 32;
        int n = t & 63, kh = t >> 6;
#pragma unroll
        for (int i = 0; i < 8; ++i) {
            int kk = kh * 8 + i;
            int si = (h << 15) + (k0 + kk) * NHID + n;
            float v = bf ? b2f(((const unsigned short*)Wh_)[si])
                         : ((const float*)Wh_)[si];
            tile[n][kk] = v;
        }
        __syncthreads();
        int n2 = t >> 2, kk0 = (t & 3) * 8;
        u16x8 o;
#pragma unroll
        for (int i = 0; i < 8; ++i) o[i] = f2b(tile[n2][kk0 + i]);
        *(u16x8*)&Wtb[(size_t)((h << 6) + n2) * NFEAT + k0 + kk0] = o;
    } else {
        const int NF8 = NN * NFEAT / 8;
        const int TOT = NF8 + NSMALL;
        int stride = (gridDim.x - 128) * 256;
        int start = bf ? NF8 : 0;          // bf16: skip the feature cast pass
        for (int i = start + (bid - 128) * 256 + t; i < TOT; i += stride) {
            if (i < NF8) {
                float4 lo = ((const float4*)f)[i * 2];
                float4 hi = ((const float4*)f)[i * 2 + 1];
                u16x8 o;
                o[0] = f2b(lo.x); o[1] = f2b(lo.y); o[2] = f2b(lo.z); o[3] = f2b(lo.w);
                o[4] = f2b(hi.x); o[5] = f2b(hi.y); o[6] = f2b(hi.z); o[7] = f2b(hi.w);
                *(u16x8*)&featb[i * 8] = o;
            } else {
                int r = i - NF8;
                const void* sp; int off;
                if (r < SZ2)                        { sp = ah_; off = r; }
                else if (r < SZ2 + SZ3)             { sp = bh_; off = r - SZ2; }
                else if (r < SZ2 + SZ3 + SZ4)       { sp = Wo_; off = r - SZ2 - SZ3; }
                else if (r < SZ2 + SZ3 + SZ4 + SZ5) { sp = ao_; off = r - SZ2 - SZ3 - SZ4; }
                else                                { sp = bo_; off = r - SZ2 - SZ3 - SZ4 - SZ5; }
                smallf[r] = bf ? b2f(((const unsigned short*)sp)[off])
                               : ((const float*)sp)[off];
            }
        }
    }
}

// ---------- K1: gemm1 (r1 B-reuse tiling, A from input directly if bf16) + bitmap OR ----------
__global__ void __launch_bounds__(256)
k_gemm_or(const void* __restrict__ f,
          const unsigned short* __restrict__ featb,
          const unsigned short* __restrict__ Wtb,
          const float* __restrict__ ah,
          unsigned short* __restrict__ Hb,
          float* __restrict__ s1, float* __restrict__ s2,
          float* __restrict__ cm1,
          const int* __restrict__ e32, int E,
          unsigned int* __restrict__ bits) {
    int t = threadIdx.x;
    if (blockIdx.x >= 256) {
        // fire-and-forget bitmap OR
        __shared__ int s64f;
        if (t < 64) {
            unsigned long long bal = __ballot(e32[2 * t + 1] == 0);
            if (t == 0) s64f = (__popcll(bal) >= 48);
        }
        __syncthreads();
        int i = (blockIdx.x - 256) * 256 + t;
        if (i < E) {
            int s, tt;
            if (s64f) { s = e32[2 * i]; tt = e32[2 * (E + i)]; }
            else      { s = e32[i];     tt = e32[E + i]; }
            s &= (NN - 1); tt &= (NN - 1);
            unsigned int pos = (unsigned int)s * NN + (unsigned int)tt;
            atomicOr(&bits[pos >> 5], 1u << (pos & 31u));
        }
        return;
    }
    // dtype probe: bf16 input -> read features directly (same layout as featb)
    __shared__ int sbf;
    if (t < 64) {
        unsigned int w = ((const unsigned int*)f)[t];
        unsigned int lo = w & 0xffffu, e = (lo >> 7) & 0xffu;
        unsigned long long bal = __ballot(lo == 0u || (e >= 100u && e <= 140u));
        if (t == 0) sbf = (__popcll(bal) >= 40);
    }
    __shared__ float cms[64];
    if (t < 64) cms[t] = 0.f;
    __syncthreads();
    const unsigned short* Ab = sbf ? (const unsigned short*)f : featb;
    int w = t >> 6, l = t & 63;
    int quad = l >> 4, l16 = l & 15;
    int h = blockIdx.x >> 5;
    int m0 = (blockIdx.x & 31) * 128 + w * 32;
    f32x4 acc[2][4] = {};
    const unsigned short* a0p = Ab + (size_t)(m0 + l16) * NFEAT + quad * 8;
    const unsigned short* a1p = a0p + 16 * NFEAT;
    const unsigned short* bp  = Wtb + ((size_t)h << 15) + (size_t)l16 * NFEAT + quad * 8;
#pragma unroll 4
    for (int k0 = 0; k0 < NFEAT; k0 += 32) {
        bf16x8 a0 = *(const bf16x8*)(a0p + k0);
        bf16x8 a1 = *(const bf16x8*)(a1p + k0);
#pragma unroll
        for (int nt = 0; nt < 4; ++nt) {
            bf16x8 b = *(const bf16x8*)(bp + (size_t)nt * 16 * NFEAT + k0);
            acc[0][nt] = __builtin_amdgcn_mfma_f32_16x16x32_bf16(a0, b, acc[0][nt], 0, 0, 0);
            acc[1][nt] = __builtin_amdgcn_mfma_f32_16x16x32_bf16(a1, b, acc[1][nt], 0, 0, 0);
        }
    }
    const float* av = ah + h * 2 * NHID;
    float p1[2][4] = {}, p2[2][4] = {};
#pragma unroll
    for (int rh = 0; rh < 2; ++rh) {
#pragma unroll
        for (int nt = 0; nt < 4; ++nt) {
            int col = nt * 16 + l16;
            float av1 = av[col], av2 = av[NHID + col];
            float csum = 0.f;
#pragma unroll
            for (int r = 0; r < 4; ++r) {
                float v = acc[rh][nt][r];
                int row = m0 + rh * 16 + quad * 4 + r;
                Hb[((size_t)row << 9) + (h << 6) + col] = f2b(v);   // node-major
                p1[rh][r] += v * av1;
                p2[rh][r] += v * av2;
                csum += v;
            }
            atomicAdd(&cms[col], csum);
        }
    }
#pragma unroll
    for (int m = 8; m >= 1; m >>= 1)
#pragma unroll
        for (int rh = 0; rh < 2; ++rh)
#pragma unroll
            for (int r = 0; r < 4; ++r) {
                p1[rh][r] += __shfl_xor(p1[rh][r], m, 64);
                p2[rh][r] += __shfl_xor(p2[rh][r], m, 64);
            }
    if (l16 == 0) {
#pragma unroll
        for (int rh = 0; rh < 2; ++rh)
#pragma unroll
            for (int r = 0; r < 4; ++r) {
                int row = m0 + rh * 16 + quad * 4 + r;
                s1[(h << 12) + row] = p1[rh][r];
                s2[(h << 12) + row] = p2[rh][r];
            }
    }
    __syncthreads();
    if (t < 64) atomicAdd(&cm1[h * NHID + t], cms[t]);
}

// ---------- K2: extract->LDS + attn1 (all heads/wave) + bias + ELU + gemm2 + scores2 ----------
__global__ void __launch_bounds__(256)
k_eattn1(const unsigned int* __restrict__ bits,
         int* __restrict__ deg, int* __restrict__ csr,
         const float* __restrict__ s1, const float* __restrict__ s2,
         const unsigned short* __restrict__ Hb,
         const float* __restrict__ bh, const float* __restrict__ cm1,
         const float* __restrict__ Wo, const float* __restrict__ ao,
         float* __restrict__ out2, float* __restrict__ s1o,
         float* __restrict__ s2o, float* __restrict__ cm2) {
    __shared__ float sW[4][CAP * 8];   // weights; reused as X row after gather
    __shared__ int   sT[4][CAP];
    __shared__ float cms[NCLASS];
    int t = threadIdx.x;
    if (t < NCLASS) cms[t] = 0.f;
    int wid = t >> 6, lane = t & 63;
    int n = blockIdx.x * 4 + wid;
    int d;
    {   // ---- extract own node's bitmap row into sT ----
        uint2 w2 = *(const uint2*)&bits[n * 128 + lane * 2];
        int c = __popc(w2.x) + __popc(w2.y);
        int incl = c;
#pragma unroll
        for (int off = 1; off < 64; off <<= 1) {
            int u = __shfl_up(incl, off, 64);
            if (lane >= off) incl += u;
        }
        int excl = incl - c;
        int total = __shfl(incl, 63, 64);
        if (lane == 0) deg[n] = total;
        int tbase = lane * 64;
        unsigned int x = w2.x;
        while (x) {
            int b = __ffs(x) - 1; x &= x - 1;
            if (excl < CAP) sT[wid][excl] = tbase + b;
            ++excl;
        }
        unsigned int y = w2.y;
        while (y) {
            int b = __ffs(y) - 1; y &= y - 1;
            if (excl < CAP) sT[wid][excl] = tbase + 32 + b;
            ++excl;
        }
        d = min(total, CAP);
    }
    __syncthreads();
    // coalesced csr write-back for K3
    for (int k = lane; k < d; k += 64) csr[(size_t)n * CAP + k] = sT[wid][k];
    int h = lane >> 3, jslot = lane & 7;
    float acc[8] = {};
    float rden = 1.f;
    if (d > 0) {
        const float* s2h = s2 + ((size_t)h << 12);
        float s1n = s1[(h << 12) + n];
        float mx = -1e30f;
        for (int jb = 0; jb < d; jb += 8) {
            int j = jb + jslot;
            int tt = (j < d) ? sT[wid][j] : 0;
            float e = (j < d) ? lrelu(s1n + s2h[tt]) : -1e30f;
            sW[wid][(j << 3) + h] = e;
            mx = fmaxf(mx, e);
        }
        mx = fmaxf(mx, __shfl_xor(mx, 1, 64));
        mx = fmaxf(mx, __shfl_xor(mx, 2, 64));
        mx = fmaxf(mx, __shfl_xor(mx, 4, 64));
        float den = 0.f;
        for (int jb = 0; jb < d; jb += 8) {
            int j = jb + jslot;
            float e = sW[wid][(j << 3) + h];
            float w = __expf(e - mx);
            sW[wid][(j << 3) + h] = w;
            den += w;
        }
        den += __shfl_xor(den, 1, 64);
        den += __shfl_xor(den, 2, 64);
        den += __shfl_xor(den, 4, 64);
        rden = 1.f / den;
        const unsigned short* Hp = Hb + lane * 8;
        int j = 0;
        for (; j + 8 <= d; j += 8) {      // 8 loads in flight (was 4)
            int tt[8]; float ww[8];
#pragma unroll
            for (int q = 0; q < 8; ++q) {
                tt[q] = sT[wid][j + q];
                ww[q] = sW[wid][((j + q) << 3) + h];
            }
            u16x8 vv[8];
#pragma unroll
            for (int q = 0; q < 8; ++q)
                vv[q] = *(const u16x8*)(Hp + ((size_t)tt[q] << 9));
#pragma unroll
            for (int q = 0; q < 8; ++q)
#pragma unroll
                for (int i = 0; i < 8; ++i)
                    acc[i] += ww[q] * b2f(vv[q][i]);
        }
        for (; j < d; ++j) {
            int t0 = sT[wid][j];
            float w0 = sW[wid][(j << 3) + h];
            u16x8 v0 = *(const u16x8*)(Hp + ((size_t)t0 << 9));
#pragma unroll
            for (int i = 0; i < 8; ++i) acc[i] += w0 * b2f(v0[i]);
        }
    }
    float o[8];
    if (d == 0) {
#pragma unroll
        for (int i = 0; i < 8; ++i) o[i] = cm1[lane * 8 + i] * (1.0f / NN);
    } else {
#pragma unroll
        for (int i = 0; i < 8; ++i) o[i] = acc[i] * rden;
    }
#pragma unroll
    for (int i = 0; i < 8; ++i) {
        float v = o[i] + bh[lane * 8 + i];
        o[i] = v > 0.f ? v : __expf(v) - 1.f;     // ELU
    }
    // reuse this wave's weight region as its X row
    float* xw = sW[wid];
    *(float4*)&xw[lane * 8]     = make_float4(o[0], o[1], o[2], o[3]);
    *(float4*)&xw[lane * 8 + 4] = make_float4(o[4], o[5], o[6], o[7]);
    int c = lane & 15, sub = lane >> 4;
    const float* xp = xw + sub * 128;
    const float* wp = Wo + sub * 128 * NCLASS + c;
    float a2 = 0.f;
#pragma unroll 8
    for (int kk = 0; kk < 128; ++kk) a2 += xp[kk] * wp[kk * NCLASS];
    a2 += __shfl_xor(a2, 16, 64);
    a2 += __shfl_xor(a2, 32, 64);
    if (lane < 16) out2[n * NCLASS + c] = a2;
    float r1 = a2 * ao[c], r2 = a2 * ao[NCLASS + c];
#pragma unroll
    for (int m = 8; m >= 1; m >>= 1) {
        r1 += __shfl_xor(r1, m, 16);
        r2 += __shfl_xor(r2, m, 16);
    }
    if (lane == 0) { s1o[n] = r1; s2o[n] = r2; }
    if (lane < 16) atomicAdd(&cms[c], a2);
    __syncthreads();
    if (t < NCLASS) atomicAdd(&cm2[t], cms[t]);
}

// ---------- K3: attn2 + bias + log_softmax ----------
__global__ void __launch_bounds__(256)
k_attn2(const int* __restrict__ deg, const int* __restrict__ csr,
        const float* __restrict__ s1o, const float* __restrict__ s2o,
        const float* __restrict__ out2, const float* __restrict__ bo,
        const float* __restrict__ cm2, float* __restrict__ outp) {
    __shared__ float wv[4][CAP];
    __shared__ float o2s[4][16];
    int wid = threadIdx.x >> 6, lane = threadIdx.x & 63;
    int n = blockIdx.x * 4 + wid;
    int c = lane & 15;
    int d = min(deg[n], CAP);
    float val;
    if (d == 0) {
        val = cm2[c] * (1.0f / NN);
    } else {
        float s1n = s1o[n];
        const int* rowp = csr + (size_t)n * CAP;
        int t0 = (lane < d)       ? rowp[lane]       : 0;
        int t1 = (lane + 64 < d)  ? rowp[lane + 64]  : 0;
        int t2 = (lane + 128 < d) ? rowp[lane + 128] : 0;
        float e0 = (lane < d)       ? lrelu(s1n + s2o[t0]) : -1e30f;
        float e1 = (lane + 64 < d)  ? lrelu(s1n + s2o[t1]) : -1e30f;
        float e2 = (lane + 128 < d) ? lrelu(s1n + s2o[t2]) : -1e30f;
        float m = waveMax(fmaxf(e0, fmaxf(e1, e2)));
        float w0 = (lane < d)       ? __expf(e0 - m) : 0.f;
        float w1 = (lane + 64 < d)  ? __expf(e1 - m) : 0.f;
        float w2 = (lane + 128 < d) ? __expf(e2 - m) : 0.f;
        float den = waveSum(w0 + w1 + w2);
        wv[wid][lane] = w0;
        if (lane + 64 < CAP)  wv[wid][lane + 64]  = w1;
        if (lane + 128 < CAP) wv[wid][lane + 128] = w2;
        int g2 = lane >> 2, q = lane & 3;
        float a4[4] = {};
        for (int j = g2; j < d; j += 16) {
            float w = wv[wid][j];
            int tt = rowp[j];
            float4 v = *(const float4*)(out2 + tt * NCLASS + q * 4);
            a4[0] += w * v.x; a4[1] += w * v.y;
            a4[2] += w * v.z; a4[3] += w * v.w;
        }
#pragma unroll
        for (int m2 = 4; m2 <= 32; m2 <<= 1)
#pragma unroll
            for (int i = 0; i < 4; ++i) a4[i] += __shfl_xor(a4[i], m2, 64);
        if (lane < 4)
            *(float4*)&o2s[wid][lane * 4] = make_float4(a4[0], a4[1], a4[2], a4[3]);
        val = o2s[wid][c] / den;
    }
    val += bo[c];
    float mx = val;
#pragma unroll
    for (int m = 8; m >= 1; m >>= 1) mx = fmaxf(mx, __shfl_xor(mx, m, 16));
    float se = __expf(val - mx);
#pragma unroll
    for (int m = 8; m >= 1; m >>= 1) se += __shfl_xor(se, m, 16);
    float res = val - mx - __logf(se);
    if (lane < 16) outp[n * NCLASS + lane] = res;
}

extern "C" void kernel_launch(void* const* d_in, const int* in_sizes, int n_in,
                              void* d_out, int out_size, void* d_ws, size_t ws_size,
                              hipStream_t stream) {
    const void* features = d_in[0];
    const int*  edges    = (const int*)d_in[1];
    const void* W_heads  = d_in[2];
    const void* a_heads  = d_in[3];
    const void* b_heads  = d_in[4];
    const void* W_out    = d_in[5];
    const void* a_out    = d_in[6];
    const void* b_out    = d_in[7];
    int E = in_sizes[1] / 2;
    int csb = (E + 255) / 256;

    // ---- workspace layout (4B units) ----
    unsigned int* bits = (unsigned int*)d_ws;                  // NN*NN/32 (zeroed in K0)
    int*   deg  = (int*)(bits + (NN * NN / 32));               // NN (plain stores)
    float* cm1  = (float*)(deg + NN);                          // NHEAD*NHID (zeroed in K0)
    float* cm2  = cm1 + NHEAD * NHID;                          // NCLASS    (zeroed in K0)
    int*   csr  = (int*)(cm2 + NCLASS);                        // NN*CAP
    float* s1   = (float*)(csr + NN * CAP);                    // NHEAD*NN
    float* s2   = s1 + NHEAD * NN;                             // NHEAD*NN
    float* out2 = s2 + NHEAD * NN;                             // NN*NCLASS
    float* s1o  = out2 + NN * NCLASS;                          // NN
    float* s2o  = s1o + NN;                                    // NN
    float* smallf = s2o + NN;                                  // NSMALL fp32
    unsigned short* Hb    = (unsigned short*)(smallf + NSMALL);// NN*512 bf16 (node-major)
    unsigned short* featb = Hb + (size_t)NN * NHEAD * NHID;    // NN*NFEAT bf16
    unsigned short* Wtb   = featb + (size_t)NN * NFEAT;        // NHEAD*NHID*NFEAT bf16
    float* outp = (float*)d_out;

    // K0: zero (bits/cm1/cm2) + W-T + casts
    hipLaunchKernelGGL(k_prep0, dim3(2048), dim3(256), 0, stream,
                       features, W_heads, a_heads, b_heads, W_out, a_out, b_out,
                       featb, Wtb, smallf, bits, cm1);
    // K1: gemm1 (256 blocks, B-reuse tiling, direct-bf16 A) + bitmap OR
    hipLaunchKernelGGL(k_gemm_or, dim3(256 + csb), dim3(256), 0, stream,
                       features, featb, Wtb, smallf, Hb, s1, s2, cm1, edges, E, bits);
    // K2: extract->LDS + attn1 + gemm2 fused
    hipLaunchKernelGGL(k_eattn1, dim3(NN / 4), dim3(256), 0, stream,
                       bits, deg, csr, s1, s2, Hb, smallf + SZ2, cm1,
                       smallf + SZ2 + SZ3, smallf + SZ2 + SZ3 + SZ4,
                       out2, s1o, s2o, cm2);
    // K3: attn2
    hipLaunchKernelGGL(k_attn2, dim3(NN / 4), dim3(256), 0, stream,
                       deg, csr, s1o, s2o, out2,
                       smallf + SZ2 + SZ3 + SZ4 + SZ5, cm2, outp);
}

// Round 10
// 141.138 us; speedup vs baseline: 3.7748x; 1.0081x over previous
//
#include <hip/hip_runtime.h>
#include <hip/hip_bf16.h>

#define NN 4096
#define NFEAT 512
#define NHID 64
#define NHEAD 8
#define NCLASS 16
#define CAP 160
#define LALPHA 0.2f

#define SZ2 (NHEAD*2*NHID)   // a_heads
#define SZ3 (NHEAD*NHID)     // b_heads
#define SZ4 (NFEAT*NCLASS)   // W_out
#define SZ5 (2*NCLASS)       // a_out
#define SZ6 (NCLASS)         // b_out
#define NSMALL (SZ2+SZ3+SZ4+SZ5+SZ6)
#define NGB 128              // 2 barrier slots, 128B-spaced

typedef __attribute__((ext_vector_type(8))) short bf16x8;
typedef __attribute__((ext_vector_type(4))) float f32x4;
typedef __attribute__((ext_vector_type(8))) unsigned short u16x8;

__device__ __forceinline__ float b2f(unsigned short h) {
    return __uint_as_float(((unsigned int)h) << 16);
}
__device__ __forceinline__ unsigned short f2b(float f) {
    unsigned int u = __float_as_uint(f);
    unsigned int r = (u + 0x7fffu + ((u >> 16) & 1u)) >> 16;
    return (unsigned short)r;
}
__device__ __forceinline__ float waveMax(float v) {
#pragma unroll
    for (int m = 32; m >= 1; m >>= 1) v = fmaxf(v, __shfl_xor(v, m, 64));
    return v;
}
__device__ __forceinline__ float waveSum(float v) {
#pragma unroll
    for (int m = 32; m >= 1; m >>= 1) v += __shfl_xor(v, m, 64);
    return v;
}
__device__ __forceinline__ float lrelu(float e) {
    return e >= 0.f ? e : LALPHA * e;
}

#if defined(__has_builtin)
#if __has_builtin(__builtin_amdgcn_fence)
#define GAT_HAS_FENCE 1
#endif
#endif
#ifdef GAT_HAS_FENCE
#define REL_FENCE() __builtin_amdgcn_fence(__ATOMIC_RELEASE, "agent")
#define ACQ_FENCE() __builtin_amdgcn_fence(__ATOMIC_ACQUIRE, "agent")
#else
#define REL_FENCE() __threadfence()
#define ACQ_FENCE() __threadfence()
#endif

// r5/r6-verified minimal-coherence grid barrier (one wbl2 + one inv per block).
// gb state zeroed by host memset each iteration; each slot used exactly once.
__device__ __forceinline__ void gbar(int* gb, int idx, int nblk) {
    __syncthreads();
    if (threadIdx.x == 0) {
        REL_FENCE();
        int* ctr  = gb + idx * 32;
        int* flag = gb + idx * 32 + 16;
        int prev = __hip_atomic_fetch_add(ctr, 1, __ATOMIC_RELAXED,
                                          __HIP_MEMORY_SCOPE_AGENT);
        if (prev == nblk - 1) {
            __hip_atomic_store(flag, 1, __ATOMIC_RELAXED,
                               __HIP_MEMORY_SCOPE_AGENT);
        } else {
            while (__hip_atomic_load(flag, __ATOMIC_RELAXED,
                                     __HIP_MEMORY_SCOPE_AGENT) == 0)
                __builtin_amdgcn_s_sleep(8);
        }
        ACQ_FENCE();
    }
    __syncthreads();
}

// =====================================================================
// K01: {zero bits | probe | W-T | casts} -> gbar -> {bitmap OR | gemm1}
// All bodies verbatim from the verified r9 kernels; only fused.
// =====================================================================
__global__ void __launch_bounds__(256, 4)
k01(const void* __restrict__ f, const void* __restrict__ Wh_,
    const void* __restrict__ ah_, const void* __restrict__ bh_,
    const void* __restrict__ Wo_, const void* __restrict__ ao_,
    const void* __restrict__ bo_, const int* __restrict__ e32,
    int E, int csb,
    unsigned short* __restrict__ featb, unsigned short* __restrict__ Wtb,
    float* __restrict__ smallf, unsigned int* __restrict__ bits,
    unsigned short* __restrict__ Hb,
    float* __restrict__ s1, float* __restrict__ s2,
    float* __restrict__ cm1, int* __restrict__ gb) {
    __shared__ float tile[64][33];
    __shared__ float cms[64];
    __shared__ int sbf, s64f;
    int t = threadIdx.x, bid = blockIdx.x, nblk = gridDim.x;
    if (t < 64) {
        unsigned int w = ((const unsigned int*)f)[t];
        unsigned int lo = w & 0xffffu, e = (lo >> 7) & 0xffu;
        unsigned long long bal = __ballot(lo == 0u || (e >= 100u && e <= 140u));
        if (t == 0) sbf = (__popcll(bal) >= 40);
        unsigned long long bal2 = __ballot(e32[2 * t + 1] == 0);
        if (t == 0) s64f = (__popcll(bal2) >= 48);
    }
    __syncthreads();
    bool bf = (sbf != 0);
    // zero bits (cm1/cm2/gb are host-memset)
    for (int i = bid * 256 + t; i < NN * NN / 32; i += nblk * 256)
        bits[i] = 0u;
    // W transpose (blocks < 128, grid-stride-safe)
    for (int vb = bid; vb < 128; vb += nblk) {
        int h = vb >> 4, k0 = (vb & 15) * 32;
        int nn = t & 63, kh = t >> 6;
#pragma unroll
        for (int i = 0; i < 8; ++i) {
            int kk = kh * 8 + i;
            int si = (h << 15) + (k0 + kk) * NHID + nn;
            float v = bf ? b2f(((const unsigned short*)Wh_)[si])
                         : ((const float*)Wh_)[si];
            tile[nn][kk] = v;
        }
        __syncthreads();
        int n2 = t >> 2, kk0 = (t & 3) * 8;
        u16x8 o;
#pragma unroll
        for (int i = 0; i < 8; ++i) o[i] = f2b(tile[n2][kk0 + i]);
        *(u16x8*)&Wtb[(size_t)((h << 6) + n2) * NFEAT + k0 + kk0] = o;
        __syncthreads();
    }
    // feature cast (fp32 only) + small-param cast
    {
        const int NF8 = NN * NFEAT / 8;
        const int TOT = NF8 + NSMALL;
        int start = bf ? NF8 : 0;
        for (int i = start + bid * 256 + t; i < TOT; i += nblk * 256) {
            if (i < NF8) {
                float4 lo = ((const float4*)f)[i * 2];
                float4 hi = ((const float4*)f)[i * 2 + 1];
                u16x8 o;
                o[0] = f2b(lo.x); o[1] = f2b(lo.y); o[2] = f2b(lo.z); o[3] = f2b(lo.w);
                o[4] = f2b(hi.x); o[5] = f2b(hi.y); o[6] = f2b(hi.z); o[7] = f2b(hi.w);
                *(u16x8*)&featb[i * 8] = o;
            } else {
                int r = i - NF8;
                const void* sp; int off;
                if (r < SZ2)                        { sp = ah_; off = r; }
                else if (r < SZ2 + SZ3)             { sp = bh_; off = r - SZ2; }
                else if (r < SZ2 + SZ3 + SZ4)       { sp = Wo_; off = r - SZ2 - SZ3; }
                else if (r < SZ2 + SZ3 + SZ4 + SZ5) { sp = ao_; off = r - SZ2 - SZ3 - SZ4; }
                else                                { sp = bo_; off = r - SZ2 - SZ3 - SZ4 - SZ5; }
                smallf[r] = bf ? b2f(((const unsigned short*)sp)[off])
                               : ((const float*)sp)[off];
            }
        }
    }
    gbar(gb, 0, nblk);
    // post-barrier: OR chunks [0,csb) then gemm tiles [csb, csb+256)
    const unsigned short* Ab = bf ? (const unsigned short*)f : featb;
    const float* av8 = smallf;
    for (int vb = bid; vb < csb + 256; vb += nblk) {
        if (vb < csb) {
            int i = vb * 256 + t;
            if (i < E) {
                int s, tt;
                if (s64f) { s = e32[2 * i]; tt = e32[2 * (E + i)]; }
                else      { s = e32[i];     tt = e32[E + i]; }
                s &= (NN - 1); tt &= (NN - 1);
                unsigned int pos = (unsigned int)s * NN + (unsigned int)tt;
                atomicOr(&bits[pos >> 5], 1u << (pos & 31u));
            }
            continue;
        }
        int tl = vb - csb;              // gemm tile id in [0,256)
        if (t < 64) cms[t] = 0.f;
        __syncthreads();
        int w = t >> 6, l = t & 63;
        int quad = l >> 4, l16 = l & 15;
        int h = tl >> 5;
        int m0 = (tl & 31) * 128 + w * 32;
        f32x4 acc[2][4] = {};
        const unsigned short* a0p = Ab + (size_t)(m0 + l16) * NFEAT + quad * 8;
        const unsigned short* a1p = a0p + 16 * NFEAT;
        const unsigned short* bp  = Wtb + ((size_t)h << 15) + (size_t)l16 * NFEAT + quad * 8;
#pragma unroll 4
        for (int k0 = 0; k0 < NFEAT; k0 += 32) {
            bf16x8 a0 = *(const bf16x8*)(a0p + k0);
            bf16x8 a1 = *(const bf16x8*)(a1p + k0);
#pragma unroll
            for (int nt = 0; nt < 4; ++nt) {
                bf16x8 b = *(const bf16x8*)(bp + (size_t)nt * 16 * NFEAT + k0);
                acc[0][nt] = __builtin_amdgcn_mfma_f32_16x16x32_bf16(a0, b, acc[0][nt], 0, 0, 0);
                acc[1][nt] = __builtin_amdgcn_mfma_f32_16x16x32_bf16(a1, b, acc[1][nt], 0, 0, 0);
            }
        }
        const float* av = av8 + h * 2 * NHID;
        float p1[2][4] = {}, p2[2][4] = {};
#pragma unroll
        for (int rh = 0; rh < 2; ++rh) {
#pragma unroll
            for (int nt = 0; nt < 4; ++nt) {
                int col = nt * 16 + l16;
                float av1 = av[col], av2 = av[NHID + col];
                float csum = 0.f;
#pragma unroll
                for (int r = 0; r < 4; ++r) {
                    float v = acc[rh][nt][r];
                    int row = m0 + rh * 16 + quad * 4 + r;
                    Hb[((size_t)row << 9) + (h << 6) + col] = f2b(v);   // node-major
                    p1[rh][r] += v * av1;
                    p2[rh][r] += v * av2;
                    csum += v;
                }
                atomicAdd(&cms[col], csum);
            }
        }
#pragma unroll
        for (int m = 8; m >= 1; m >>= 1)
#pragma unroll
            for (int rh = 0; rh < 2; ++rh)
#pragma unroll
                for (int r = 0; r < 4; ++r) {
                    p1[rh][r] += __shfl_xor(p1[rh][r], m, 64);
                    p2[rh][r] += __shfl_xor(p2[rh][r], m, 64);
                }
        if (l16 == 0) {
#pragma unroll
            for (int rh = 0; rh < 2; ++rh)
#pragma unroll
                for (int r = 0; r < 4; ++r) {
                    int row = m0 + rh * 16 + quad * 4 + r;
                    s1[(h << 12) + row] = p1[rh][r];
                    s2[(h << 12) + row] = p2[rh][r];
                }
        }
        __syncthreads();
        if (t < 64) atomicAdd(&cm1[h * NHID + t], cms[t]);
        __syncthreads();
    }
}

// =====================================================================
// K23: {extract->LDS + attn1 + gemm2 + scores2} -> gbar -> {attn2 from own LDS}
// csr/deg globals eliminated (attn2 reads the block's own sT).
// Grid must be exactly NN/4 = 1024 (node ownership); launcher verifies.
// =====================================================================
__global__ void __launch_bounds__(256, 4)
k23(const unsigned int* __restrict__ bits,
    const float* __restrict__ s1, const float* __restrict__ s2,
    const unsigned short* __restrict__ Hb,
    const float* __restrict__ bh, const float* __restrict__ cm1,
    const float* __restrict__ Wo, const float* __restrict__ ao,
    const float* __restrict__ bo,
    float* __restrict__ out2, float* __restrict__ s1o,
    float* __restrict__ s2o, float* __restrict__ cm2,
    float* __restrict__ outp, int* __restrict__ gb) {
    __shared__ float sW[4][CAP * 8];   // weights -> X row -> attn2 weights
    __shared__ int   sT[4][CAP];       // adjacency, persists across the barrier
    __shared__ float cms[NCLASS];
    __shared__ float o2s[4][16];
    int t = threadIdx.x, bid = blockIdx.x, nblk = gridDim.x;
    if (t < NCLASS) cms[t] = 0.f;
    int wid = t >> 6, lane = t & 63;
    int n = bid * 4 + wid;
    int d;
    {   // ---- extract own node's bitmap row into sT ----
        uint2 w2 = *(const uint2*)&bits[n * 128 + lane * 2];
        int c = __popc(w2.x) + __popc(w2.y);
        int incl = c;
#pragma unroll
        for (int off = 1; off < 64; off <<= 1) {
            int u = __shfl_up(incl, off, 64);
            if (lane >= off) incl += u;
        }
        int excl = incl - c;
        int total = __shfl(incl, 63, 64);
        int tbase = lane * 64;
        unsigned int x = w2.x;
        while (x) {
            int b = __ffs(x) - 1; x &= x - 1;
            if (excl < CAP) sT[wid][excl] = tbase + b;
            ++excl;
        }
        unsigned int y = w2.y;
        while (y) {
            int b = __ffs(y) - 1; y &= y - 1;
            if (excl < CAP) sT[wid][excl] = tbase + 32 + b;
            ++excl;
        }
        d = min(total, CAP);
    }
    __syncthreads();
    int h = lane >> 3, jslot = lane & 7;
    float acc[8] = {};
    float rden = 1.f;
    if (d > 0) {
        const float* s2h = s2 + ((size_t)h << 12);
        float s1n = s1[(h << 12) + n];
        float mx = -1e30f;
        for (int jb = 0; jb < d; jb += 8) {
            int j = jb + jslot;
            int tt = (j < d) ? sT[wid][j] : 0;
            float e = (j < d) ? lrelu(s1n + s2h[tt]) : -1e30f;
            sW[wid][(j << 3) + h] = e;
            mx = fmaxf(mx, e);
        }
        mx = fmaxf(mx, __shfl_xor(mx, 1, 64));
        mx = fmaxf(mx, __shfl_xor(mx, 2, 64));
        mx = fmaxf(mx, __shfl_xor(mx, 4, 64));
        float den = 0.f;
        for (int jb = 0; jb < d; jb += 8) {
            int j = jb + jslot;
            float e = sW[wid][(j << 3) + h];
            float w = __expf(e - mx);
            sW[wid][(j << 3) + h] = w;
            den += w;
        }
        den += __shfl_xor(den, 1, 64);
        den += __shfl_xor(den, 2, 64);
        den += __shfl_xor(den, 4, 64);
        rden = 1.f / den;
        const unsigned short* Hp = Hb + lane * 8;
        int j = 0;
        for (; j + 4 <= d; j += 4) {      // 4 loads in flight (r6-verified)
            int t0 = sT[wid][j],     t1 = sT[wid][j + 1];
            int t2 = sT[wid][j + 2], t3 = sT[wid][j + 3];
            float w0 = sW[wid][(j << 3) + h];
            float w1 = sW[wid][((j + 1) << 3) + h];
            float w2 = sW[wid][((j + 2) << 3) + h];
            float w3 = sW[wid][((j + 3) << 3) + h];
            u16x8 v0 = *(const u16x8*)(Hp + ((size_t)t0 << 9));
            u16x8 v1 = *(const u16x8*)(Hp + ((size_t)t1 << 9));
            u16x8 v2 = *(const u16x8*)(Hp + ((size_t)t2 << 9));
            u16x8 v3 = *(const u16x8*)(Hp + ((size_t)t3 << 9));
#pragma unroll
            for (int i = 0; i < 8; ++i)
                acc[i] += w0 * b2f(v0[i]) + w1 * b2f(v1[i])
                        + w2 * b2f(v2[i]) + w3 * b2f(v3[i]);
        }
        for (; j < d; ++j) {
            int t0 = sT[wid][j];
            float w0 = sW[wid][(j << 3) + h];
            u16x8 v0 = *(const u16x8*)(Hp + ((size_t)t0 << 9));
#pragma unroll
            for (int i = 0; i < 8; ++i) acc[i] += w0 * b2f(v0[i]);
        }
    }
    float o[8];
    if (d == 0) {
#pragma unroll
        for (int i = 0; i < 8; ++i) o[i] = cm1[lane * 8 + i] * (1.0f / NN);
    } else {
#pragma unroll
        for (int i = 0; i < 8; ++i) o[i] = acc[i] * rden;
    }
#pragma unroll
    for (int i = 0; i < 8; ++i) {
        float v = o[i] + bh[lane * 8 + i];
        o[i] = v > 0.f ? v : __expf(v) - 1.f;     // ELU
    }
    float* xw = sW[wid];                 // reuse weight region as X row
    *(float4*)&xw[lane * 8]     = make_float4(o[0], o[1], o[2], o[3]);
    *(float4*)&xw[lane * 8 + 4] = make_float4(o[4], o[5], o[6], o[7]);
    int c = lane & 15, sub = lane >> 4;
    const float* xp = xw + sub * 128;
    const float* wp = Wo + sub * 128 * NCLASS + c;
    float a2 = 0.f;
#pragma unroll 8
    for (int kk = 0; kk < 128; ++kk) a2 += xp[kk] * wp[kk * NCLASS];
    a2 += __shfl_xor(a2, 16, 64);
    a2 += __shfl_xor(a2, 32, 64);
    if (lane < 16) out2[n * NCLASS + c] = a2;
    float r1 = a2 * ao[c], r2 = a2 * ao[NCLASS + c];
#pragma unroll
    for (int m = 8; m >= 1; m >>= 1) {
        r1 += __shfl_xor(r1, m, 16);
        r2 += __shfl_xor(r2, m, 16);
    }
    if (lane == 0) { s1o[n] = r1; s2o[n] = r2; }
    if (lane < 16) atomicAdd(&cms[c], a2);
    __syncthreads();
    if (t < NCLASS) atomicAdd(&cm2[t], cms[t]);

    gbar(gb, 1, nblk);

    // ---- attn2 from own LDS adjacency ----
    {
        float val;
        if (d == 0) {
            val = cm2[c] * (1.0f / NN);
        } else {
            float s1n = s1o[n];
            float* wvw = sW[wid];        // X row dead; reuse as weights
            int t0 = (lane < d)       ? sT[wid][lane]       : 0;
            int t1 = (lane + 64 < d)  ? sT[wid][lane + 64]  : 0;
            int t2 = (lane + 128 < d) ? sT[wid][lane + 128] : 0;
            float e0 = (lane < d)       ? lrelu(s1n + s2o[t0]) : -1e30f;
            float e1 = (lane + 64 < d)  ? lrelu(s1n + s2o[t1]) : -1e30f;
            float e2 = (lane + 128 < d) ? lrelu(s1n + s2o[t2]) : -1e30f;
            float m = waveMax(fmaxf(e0, fmaxf(e1, e2)));
            float w0 = (lane < d)       ? __expf(e0 - m) : 0.f;
            float w1 = (lane + 64 < d)  ? __expf(e1 - m) : 0.f;
            float w2 = (lane + 128 < d) ? __expf(e2 - m) : 0.f;
            float den = waveSum(w0 + w1 + w2);
            wvw[lane] = w0;
            wvw[lane + 64] = w1;
            if (lane + 128 < CAP) wvw[lane + 128] = w2;
            int g2 = lane >> 2, q = lane & 3;
            float a4[4] = {};
            for (int j = g2; j < d; j += 16) {
                float w = wvw[j];
                int tt = sT[wid][j];
                float4 v = *(const float4*)(out2 + tt * NCLASS + q * 4);
                a4[0] += w * v.x; a4[1] += w * v.y;
                a4[2] += w * v.z; a4[3] += w * v.w;
            }
#pragma unroll
            for (int m2 = 4; m2 <= 32; m2 <<= 1)
#pragma unroll
                for (int i = 0; i < 4; ++i) a4[i] += __shfl_xor(a4[i], m2, 64);
            if (lane < 4)
                *(float4*)&o2s[wid][lane * 4] = make_float4(a4[0], a4[1], a4[2], a4[3]);
            val = o2s[wid][c] / den;
        }
        val += bo[c];
        float mx = val;
#pragma unroll
        for (int m = 8; m >= 1; m >>= 1) mx = fmaxf(mx, __shfl_xor(mx, m, 16));
        float se = __expf(val - mx);
#pragma unroll
        for (int m = 8; m >= 1; m >>= 1) se += __shfl_xor(se, m, 16);
        float res = val - mx - __logf(se);
        if (lane < 16) outp[n * NCLASS + lane] = res;
    }
}

// =====================================================================
// Fallback kernels: verbatim r9 (verified 142.3 us path).
// =====================================================================
__global__ void __launch_bounds__(256)
k_prep0(const void* __restrict__ f, const void* __restrict__ Wh_,
        const void* __restrict__ ah_, const void* __restrict__ bh_,
        const void* __restrict__ Wo_, const void* __restrict__ ao_,
        const void* __restrict__ bo_,
        unsigned short* __restrict__ featb,
        unsigned short* __restrict__ Wtb,
        float* __restrict__ smallf,
        unsigned int* __restrict__ bits,
        float* __restrict__ cmz) {
    int t = threadIdx.x, bid = blockIdx.x;
    for (int i = bid * 256 + t; i < NN * NN / 32; i += gridDim.x * 256)
        bits[i] = 0u;
    if (bid == 0)
        for (int i = t; i < NHEAD * NHID + NCLASS; i += 256) cmz[i] = 0.f;
    __shared__ int sbf;
    if (t < 64) {
        unsigned int w = ((const unsigned int*)f)[t];
        unsigned int lo = w & 0xffffu, e = (lo >> 7) & 0xffu;
        unsigned long long bal = __ballot(lo == 0u || (e >= 100u && e <= 140u));
        if (t == 0) sbf = (__popcll(bal) >= 40);
    }
    __syncthreads();
    bool bf = (sbf != 0);
    if (bid < 128) {
        __shared__ float tile[64][33];
        int h = bid >> 4, k0 = (bid & 15) * 32;
        int n = t & 63, kh = t >> 6;
#pragma unroll
        for (int i = 0; i < 8; ++i) {
            int kk = kh * 8 + i;
            int si = (h << 15) + (k0 + kk) * NHID + n;
            float v = bf ? b2f(((const unsigned short*)Wh_)[si])
                         : ((const float*)Wh_)[si];
            tile[n][kk] = v;
        }
        __syncthreads();
        int n2 = t >> 2, kk0 = (t & 3) * 8;
        u16x8 o;
#pragma unroll
        for (int i = 0; i < 8; ++i) o[i] = f2b(tile[n2][kk0 + i]);
        *(u16x8*)&Wtb[(size_t)((h << 6) + n2) * NFEAT + k0 + kk0] = o;
    } else {
        const int NF8 = NN * NFEAT / 8;
        const int TOT = NF8 + NSMALL;
        int stride = (gridDim.x - 128) * 256;
        int start = bf ? NF8 : 0;
        for (int i = start + (bid - 128) * 256 + t; i < TOT; i += stride) {
            if (i < NF8) {
                float4 lo = ((const float4*)f)[i * 2];
                float4 hi = ((const float4*)f)[i * 2 + 1];
                u16x8 o;
                o[0] = f2b(lo.x); o[1] = f2b(lo.y); o[2] = f2b(lo.z); o[3] = f2b(lo.w);
                o[4] = f2b(hi.x); o[5] = f2b(hi.y); o[6] = f2b(hi.z); o[7] = f2b(hi.w);
                *(u16x8*)&featb[i * 8] = o;
            } else {
                int r = i - NF8;
                const void* sp; int off;
                if (r < SZ2)                        { sp = ah_; off = r; }
                else if (r < SZ2 + SZ3)             { sp = bh_; off = r - SZ2; }
                else if (r < SZ2 + SZ3 + SZ4)       { sp = Wo_; off = r - SZ2 - SZ3; }
                else if (r < SZ2 + SZ3 + SZ4 + SZ5) { sp = ao_; off = r - SZ2 - SZ3 - SZ4; }
                else                                { sp = bo_; off = r - SZ2 - SZ3 - SZ4 - SZ5; }
                smallf[r] = bf ? b2f(((const unsigned short*)sp)[off])
                               : ((const float*)sp)[off];
            }
        }
    }
}

__global__ void __launch_bounds__(256)
k_gemm_or(const void* __restrict__ f,
          const unsigned short* __restrict__ featb,
          const unsigned short* __restrict__ Wtb,
          const float* __restrict__ ah,
          unsigned short* __restrict__ Hb,
          float* __restrict__ s1, float* __restrict__ s2,
          float* __restrict__ cm1,
          const int* __restrict__ e32, int E,
          unsigned int* __restrict__ bits) {
    int t = threadIdx.x;
    if (blockIdx.x >= 256) {
        __shared__ int s64f;
        if (t < 64) {
            unsigned long long bal = __ballot(e32[2 * t + 1] == 0);
            if (t == 0) s64f = (__popcll(bal) >= 48);
        }
        __syncthreads();
        int i = (blockIdx.x - 256) * 256 + t;
        if (i < E) {
            int s, tt;
            if (s64f) { s = e32[2 * i]; tt = e32[2 * (E + i)]; }
            else      { s = e32[i];     tt = e32[E + i]; }
            s &= (NN - 1); tt &= (NN - 1);
            unsigned int pos = (unsigned int)s * NN + (unsigned int)tt;
            atomicOr(&bits[pos >> 5], 1u << (pos & 31u));
        }
        return;
    }
    __shared__ int sbf;
    if (t < 64) {
        unsigned int w = ((const unsigned int*)f)[t];
        unsigned int lo = w & 0xffffu, e = (lo >> 7) & 0xffu;
        unsigned long long bal = __ballot(lo == 0u || (e >= 100u && e <= 140u));
        if (t == 0) sbf = (__popcll(bal) >= 40);
    }
    __shared__ float cms[64];
    if (t < 64) cms[t] = 0.f;
    __syncthreads();
    const unsigned short* Ab = sbf ? (const unsigned short*)f : featb;
    int w = t >> 6, l = t & 63;
    int quad = l >> 4, l16 = l & 15;
    int h = blockIdx.x >> 5;
    int m0 = (blockIdx.x & 31) * 128 + w * 32;
    f32x4 acc[2][4] = {};
    const unsigned short* a0p = Ab + (size_t)(m0 + l16) * NFEAT + quad * 8;
    const unsigned short* a1p = a0p + 16 * NFEAT;
    const unsigned short* bp  = Wtb + ((size_t)h << 15) + (size_t)l16 * NFEAT + quad * 8;
#pragma unroll 4
    for (int k0 = 0; k0 < NFEAT; k0 += 32) {
        bf16x8 a0 = *(const bf16x8*)(a0p + k0);
        bf16x8 a1 = *(const bf16x8*)(a1p + k0);
#pragma unroll
        for (int nt = 0; nt < 4; ++nt) {
            bf16x8 b = *(const bf16x8*)(bp + (size_t)nt * 16 * NFEAT + k0);
            acc[0][nt] = __builtin_amdgcn_mfma_f32_16x16x32_bf16(a0, b, acc[0][nt], 0, 0, 0);
            acc[1][nt] = __builtin_amdgcn_mfma_f32_16x16x32_bf16(a1, b, acc[1][nt], 0, 0, 0);
        }
    }
    const float* av = ah + h * 2 * NHID;
    float p1[2][4] = {}, p2[2][4] = {};
#pragma unroll
    for (int rh = 0; rh < 2; ++rh) {
#pragma unroll
        for (int nt = 0; nt < 4; ++nt) {
            int col = nt * 16 + l16;
            float av1 = av[col], av2 = av[NHID + col];
            float csum = 0.f;
#pragma unroll
            for (int r = 0; r < 4; ++r) {
                float v = acc[rh][nt][r];
                int row = m0 + rh * 16 + quad * 4 + r;
                Hb[((size_t)row << 9) + (h << 6) + col] = f2b(v);
                p1[rh][r] += v * av1;
                p2[rh][r] += v * av2;
                csum += v;
            }
            atomicAdd(&cms[col], csum);
        }
    }
#pragma unroll
    for (int m = 8; m >= 1; m >>= 1)
#pragma unroll
        for (int rh = 0; rh < 2; ++rh)
#pragma unroll
            for (int r = 0; r < 4; ++r) {
                p1[rh][r] += __shfl_xor(p1[rh][r], m, 64);
                p2[rh][r] += __shfl_xor(p2[rh][r], m, 64);
            }
    if (l16 == 0) {
#pragma unroll
        for (int rh = 0; rh < 2; ++rh)
#pragma unroll
            for (int r = 0; r < 4; ++r) {
                int row = m0 + rh * 16 + quad * 4 + r;
                s1[(h << 12) + row] = p1[rh][r];
                s2[(h << 12) + row] = p2[rh][r];
            }
    }
    __syncthreads();
    if (t < 64) atomicAdd(&cm1[h * NHID + t], cms[t]);
}

__global__ void __launch_bounds__(256)
k_eattn1(const unsigned int* __restrict__ bits,
         int* __restrict__ deg, int* __restrict__ csr,
         const float* __restrict__ s1, const float* __restrict__ s2,
         const unsigned short* __restrict__ Hb,
         const float* __restrict__ bh, const float* __restrict__ cm1,
         const float* __restrict__ Wo, const float* __restrict__ ao,
         float* __restrict__ out2, float* __restrict__ s1o,
         float* __restrict__ s2o, float* __restrict__ cm2) {
    __shared__ float sW[4][CAP * 8];
    __shared__ int   sT[4][CAP];
    __shared__ float cms[NCLASS];
    int t = threadIdx.x;
    if (t < NCLASS) cms[t] = 0.f;
    int wid = t >> 6, lane = t & 63;
    int n = blockIdx.x * 4 + wid;
    int d;
    {
        uint2 w2 = *(const uint2*)&bits[n * 128 + lane * 2];
        int c = __popc(w2.x) + __popc(w2.y);
        int incl = c;
#pragma unroll
        for (int off = 1; off < 64; off <<= 1) {
            int u = __shfl_up(incl, off, 64);
            if (lane >= off) incl += u;
        }
        int excl = incl - c;
        int total = __shfl(incl, 63, 64);
        if (lane == 0) deg[n] = total;
        int tbase = lane * 64;
        unsigned int x = w2.x;
        while (x) {
            int b = __ffs(x) - 1; x &= x - 1;
            if (excl < CAP) sT[wid][excl] = tbase + b;
            ++excl;
        }
        unsigned int y = w2.y;
        while (y) {
            int b = __ffs(y) - 1; y &= y - 1;
            if (excl < CAP) sT[wid][excl] = tbase + 32 + b;
            ++excl;
        }
        d = min(total, CAP);
    }
    __syncthreads();
    for (int k = lane; k < d; k += 64) csr[(size_t)n * CAP + k] = sT[wid][k];
    int h = lane >> 3, jslot = lane & 7;
    float acc[8] = {};
    float rden = 1.f;
    if (d > 0) {
        const float* s2h = s2 + ((size_t)h << 12);
        float s1n = s1[(h << 12) + n];
        float mx = -1e30f;
        for (int jb = 0; jb < d; jb += 8) {
            int j = jb + jslot;
            int tt = (j < d) ? sT[wid][j] : 0;
            float e = (j < d) ? lrelu(s1n + s2h[tt]) : -1e30f;
            sW[wid][(j << 3) + h] = e;
            mx = fmaxf(mx, e);
        }
        mx = fmaxf(mx, __shfl_xor(mx, 1, 64));
        mx = fmaxf(mx, __shfl_xor(mx, 2, 64));
        mx = fmaxf(mx, __shfl_xor(mx, 4, 64));
        float den = 0.f;
        for (int jb = 0; jb < d; jb += 8) {
            int j = jb + jslot;
            float e = sW[wid][(j << 3) + h];
            float w = __expf(e - mx);
            sW[wid][(j << 3) + h] = w;
            den += w;
        }
        den += __shfl_xor(den, 1, 64);
        den += __shfl_xor(den, 2, 64);
        den += __shfl_xor(den, 4, 64);
        rden = 1.f / den;
        const unsigned short* Hp = Hb + lane * 8;
        int j = 0;
        for (; j + 4 <= d; j += 4) {
            int t0 = sT[wid][j],     t1 = sT[wid][j + 1];
            int t2 = sT[wid][j + 2], t3 = sT[wid][j + 3];
            float w0 = sW[wid][(j << 3) + h];
            float w1 = sW[wid][((j + 1) << 3) + h];
            float w2 = sW[wid][((j + 2) << 3) + h];
            float w3 = sW[wid][((j + 3) << 3) + h];
            u16x8 v0 = *(const u16x8*)(Hp + ((size_t)t0 << 9));
            u16x8 v1 = *(const u16x8*)(Hp + ((size_t)t1 << 9));
            u16x8 v2 = *(const u16x8*)(Hp + ((size_t)t2 << 9));
            u16x8 v3 = *(const u16x8*)(Hp + ((size_t)t3 << 9));
#pragma unroll
            for (int i = 0; i < 8; ++i)
                acc[i] += w0 * b2f(v0[i]) + w1 * b2f(v1[i])
                        + w2 * b2f(v2[i]) + w3 * b2f(v3[i]);
        }
        for (; j < d; ++j) {
            int t0 = sT[wid][j];
            float w0 = sW[wid][(j << 3) + h];
            u16x8 v0 = *(const u16x8*)(Hp + ((size_t)t0 << 9));
#pragma unroll
            for (int i = 0; i < 8; ++i) acc[i] += w0 * b2f(v0[i]);
        }
    }
    float o[8];
    if (d == 0) {
#pragma unroll
        for (int i = 0; i < 8; ++i) o[i] = cm1[lane * 8 + i] * (1.0f / NN);
    } else {
#pragma unroll
        for (int i = 0; i < 8; ++i) o[i] = acc[i] * rden;
    }
#pragma unroll
    for (int i = 0; i < 8; ++i) {
        float v = o[i] + bh[lane * 8 + i];
        o[i] = v > 0.f ? v : __expf(v) - 1.f;
    }
    float* xw = sW[wid];
    *(float4*)&xw[lane * 8]     = make_float4(o[0], o[1], o[2], o[3]);
    *(float4*)&xw[lane * 8 + 4] = make_float4(o[4], o[5], o[6], o[7]);
    int c = lane & 15, sub = lane >> 4;
    const float* xp = xw + sub * 128;
    const float* wp = Wo + sub * 128 * NCLASS + c;
    float a2 = 0.f;
#pragma unroll 8
    for (int kk = 0; kk < 128; ++kk) a2 += xp[kk] * wp[kk * NCLASS];
    a2 += __shfl_xor(a2, 16, 64);
    a2 += __shfl_xor(a2, 32, 64);
    if (lane < 16) out2[n * NCLASS + c] = a2;
    float r1 = a2 * ao[c], r2 = a2 * ao[NCLASS + c];
#pragma unroll
    for (int m = 8; m >= 1; m >>= 1) {
        r1 += __shfl_xor(r1, m, 16);
        r2 += __shfl_xor(r2, m, 16);
    }
    if (lane == 0) { s1o[n] = r1; s2o[n] = r2; }
    if (lane < 16) atomicAdd(&cms[c], a2);
    __syncthreads();
    if (t < NCLASS) atomicAdd(&cm2[t], cms[t]);
}

__global__ void __launch_bounds__(256)
k_attn2(const int* __restrict__ deg, const int* __restrict__ csr,
        const float* __restrict__ s1o, const float* __restrict__ s2o,
        const float* __restrict__ out2, const float* __restrict__ bo,
        const float* __restrict__ cm2, float* __restrict__ outp) {
    __shared__ float wv[4][CAP];
    __shared__ float o2s[4][16];
    int wid = threadIdx.x >> 6, lane = threadIdx.x & 63;
    int n = blockIdx.x * 4 + wid;
    int c = lane & 15;
    int d = min(deg[n], CAP);
    float val;
    if (d == 0) {
        val = cm2[c] * (1.0f / NN);
    } else {
        float s1n = s1o[n];
        const int* rowp = csr + (size_t)n * CAP;
        int t0 = (lane < d)       ? rowp[lane]       : 0;
        int t1 = (lane + 64 < d)  ? rowp[lane + 64]  : 0;
        int t2 = (lane + 128 < d) ? rowp[lane + 128] : 0;
        float e0 = (lane < d)       ? lrelu(s1n + s2o[t0]) : -1e30f;
        float e1 = (lane + 64 < d)  ? lrelu(s1n + s2o[t1]) : -1e30f;
        float e2 = (lane + 128 < d) ? lrelu(s1n + s2o[t2]) : -1e30f;
        float m = waveMax(fmaxf(e0, fmaxf(e1, e2)));
        float w0 = (lane < d)       ? __expf(e0 - m) : 0.f;
        float w1 = (lane + 64 < d)  ? __expf(e1 - m) : 0.f;
        float w2 = (lane + 128 < d) ? __expf(e2 - m) : 0.f;
        float den = waveSum(w0 + w1 + w2);
        wv[wid][lane] = w0;
        if (lane + 64 < CAP)  wv[wid][lane + 64]  = w1;
        if (lane + 128 < CAP) wv[wid][lane + 128] = w2;
        int g2 = lane >> 2, q = lane & 3;
        float a4[4] = {};
        for (int j = g2; j < d; j += 16) {
            float w = wv[wid][j];
            int tt = rowp[j];
            float4 v = *(const float4*)(out2 + tt * NCLASS + q * 4);
            a4[0] += w * v.x; a4[1] += w * v.y;
            a4[2] += w * v.z; a4[3] += w * v.w;
        }
#pragma unroll
        for (int m2 = 4; m2 <= 32; m2 <<= 1)
#pragma unroll
            for (int i = 0; i < 4; ++i) a4[i] += __shfl_xor(a4[i], m2, 64);
        if (lane < 4)
            *(float4*)&o2s[wid][lane * 4] = make_float4(a4[0], a4[1], a4[2], a4[3]);
        val = o2s[wid][c] / den;
    }
    val += bo[c];
    float mx = val;
#pragma unroll
    for (int m = 8; m >= 1; m >>= 1) mx = fmaxf(mx, __shfl_xor(mx, m, 16));
    float se = __expf(val - mx);
#pragma unroll
    for (int m = 8; m >= 1; m >>= 1) se += __shfl_xor(se, m, 16);
    float res = val - mx - __logf(se);
    if (lane < 16) outp[n * NCLASS + lane] = res;
}

extern "C" void kernel_launch(void* const* d_in, const int* in_sizes, int n_in,
                              void* d_out, int out_size, void* d_ws, size_t ws_size,
                              hipStream_t stream) {
    const void* features = d_in[0];
    const int*  edges    = (const int*)d_in[1];
    const void* W_heads  = d_in[2];
    const void* a_heads  = d_in[3];
    const void* b_heads  = d_in[4];
    const void* W_out    = d_in[5];
    const void* a_out    = d_in[6];
    const void* b_out    = d_in[7];
    int E = in_sizes[1] / 2;
    int csb = (E + 255) / 256;

    // ---- workspace layout (4B units): gb+cm1+cm2 first (one tiny memset) ----
    int*   gb   = (int*)d_ws;                                  // NGB
    float* cm1  = (float*)(gb + NGB);                          // NHEAD*NHID
    float* cm2  = cm1 + NHEAD * NHID;                          // NCLASS
    unsigned int* bits = (unsigned int*)(cm2 + NCLASS);        // NN*NN/32 (in-kernel zero)
    int*   deg  = (int*)(bits + (NN * NN / 32));               // NN (fallback only)
    int*   csr  = deg + NN;                                    // NN*CAP (fallback only)
    float* s1   = (float*)(csr + NN * CAP);                    // NHEAD*NN
    float* s2   = s1 + NHEAD * NN;                             // NHEAD*NN
    float* out2 = s2 + NHEAD * NN;                             // NN*NCLASS
    float* s1o  = out2 + NN * NCLASS;                          // NN
    float* s2o  = s1o + NN;                                    // NN
    float* smallf = s2o + NN;                                  // NSMALL fp32
    unsigned short* Hb    = (unsigned short*)(smallf + NSMALL);// NN*512 bf16 (node-major)
    unsigned short* featb = Hb + (size_t)NN * NHEAD * NHID;    // NN*NFEAT bf16
    unsigned short* Wtb   = featb + (size_t)NN * NFEAT;        // NHEAD*NHID*NFEAT bf16
    float* outp = (float*)d_out;
    const float* bhf = smallf + SZ2;
    const float* Wof = smallf + SZ2 + SZ3;
    const float* aof = Wof + SZ4;
    const float* bof = aof + SZ5;

    // ---- occupancy-gated barrier path ----
    static int cap01 = -2, cap23 = -2;
    if (cap01 == -2) {
        int b01 = 0, b23 = 0, ncu = 0, dev = 0;
        (void)hipGetDevice(&dev);
        if (hipDeviceGetAttribute(&ncu, hipDeviceAttributeMultiprocessorCount, dev)
                != hipSuccess) ncu = 0;
        if (hipOccupancyMaxActiveBlocksPerMultiprocessor(
                &b01, reinterpret_cast<const void*>(&k01), 256, 0) != hipSuccess) b01 = 0;
        if (hipOccupancyMaxActiveBlocksPerMultiprocessor(
                &b23, reinterpret_cast<const void*>(&k23), 256, 0) != hipSuccess) b23 = 0;
        cap01 = (b01 > 0 && ncu > 0) ? b01 * ncu : 0;
        cap23 = (b23 > 0 && ncu > 0) ? b23 * ncu : 0;
    }
    int nblk01 = cap01 > 1024 ? 1024 : cap01;

    if (nblk01 >= 128 && cap23 >= NN / 4) {
        hipMemsetAsync(d_ws, 0, (size_t)(NGB + NHEAD * NHID + NCLASS) * 4, stream);
        hipLaunchKernelGGL(k01, dim3(nblk01), dim3(256), 0, stream,
                           features, W_heads, a_heads, b_heads, W_out, a_out, b_out,
                           edges, E, csb, featb, Wtb, smallf, bits, Hb, s1, s2, cm1, gb);
        hipLaunchKernelGGL(k23, dim3(NN / 4), dim3(256), 0, stream,
                           bits, s1, s2, Hb, bhf, cm1, Wof, aof, bof,
                           out2, s1o, s2o, cm2, outp, gb);
    } else {
        hipLaunchKernelGGL(k_prep0, dim3(2048), dim3(256), 0, stream,
                           features, W_heads, a_heads, b_heads, W_out, a_out, b_out,
                           featb, Wtb, smallf, bits, cm1);
        hipLaunchKernelGGL(k_gemm_or, dim3(256 + csb), dim3(256), 0, stream,
                           features, featb, Wtb, smallf, Hb, s1, s2, cm1, edges, E, bits);
        hipLaunchKernelGGL(k_eattn1, dim3(NN / 4), dim3(256), 0, stream,
                           bits, deg, csr, s1, s2, Hb, bhf, cm1, Wof, aof,
                           out2, s1o, s2o, cm2);
        hipLaunchKernelGGL(k_attn2, dim3(NN / 4), dim3(256), 0, stream,
                           deg, csr, s1o, s2o, out2, bof, cm2, outp);
    }
}